// Round 7
// baseline (1135.624 us; speedup 1.0000x reference)
//
#include <hip/hip_runtime.h>
#include <hip/hip_bf16.h>
#include <math.h>

typedef __hip_bfloat16 bf16;
typedef unsigned short ushort_t;
typedef unsigned int uint_t;
typedef short v8s __attribute__((ext_vector_type(8)));
typedef float v4f __attribute__((ext_vector_type(4)));

#define NVTOK 9072
#define BATCH 8
#define LT 32
#define DMODEL 256
#define NHEAD 8
#define DHEAD 32
#define MVIS (BATCH*NVTOK)   /* 72576 */
#define MTEXT (BATCH*LT)     /* 256 */
#define VISSZ 18579456ull    /* MVIS*256 elements */

__device__ __forceinline__ float bf2f(ushort_t u){ return __uint_as_float(((uint_t)u)<<16); }
__device__ __forceinline__ ushort_t f2bfbits(float f){
  __hip_bfloat16 h = __float2bfloat16(f);
  union { __hip_bfloat16 h; ushort_t u; } c; c.h = h; return c.u;
}
// mode: 0 = buffers hold bf16, 1 = buffers hold fp32
__device__ __forceinline__ float ldin(const void* p, size_t i, int mode){
  return mode ? ((const float*)p)[i] : bf2f(((const ushort_t*)p)[i]);
}
__device__ __forceinline__ void stout(void* p, size_t i, int mode, float v){
  if (mode) ((float*)p)[i] = v; else ((ushort_t*)p)[i] = f2bfbits(v);
}

// async global->LDS, 16 B per lane (LDS dest = wave-uniform base + lane*16).
__device__ __forceinline__ void gload_lds16(const void* g, void* l){
  __builtin_amdgcn_global_load_lds(
      (const __attribute__((address_space(1))) unsigned int*)g,
      (__attribute__((address_space(3))) unsigned int*)l, 16, 0, 0);
}

// ---------------------------------------------------------------------------
// D0: dtype detector (unchanged)
// ---------------------------------------------------------------------------
__global__ void k_detect(const uint_t* __restrict__ buf, int n_avail, int* __restrict__ flag){
  __shared__ int zc, bc;
  if (threadIdx.x==0){ zc=0; bc=0; }
  __syncthreads();
  int stride = n_avail/2048; if (stride < 1) stride = 1;
  int nz=0, nb=0;
  for (int i=threadIdx.x; i<2048; i+=256){
    long long idx = (long long)i*stride;
    if (idx >= n_avail) break;
    uint_t d = buf[idx];
    uint_t lo = d & 0xFFFFu;
    int e = (int)((lo >> 7) & 0xFF);
    if (lo == 0) nz++;
    else if (e >= 90 && e <= 160) nb++;
  }
  atomicAdd(&zc, nz); atomicAdd(&bc, nb);
  __syncthreads();
  if (threadIdx.x==0){
    int mode;
    if (zc > 1024) mode = 1;
    else if (bc > 1228) mode = 0;
    else mode = 1;
    *flag = mode;
  }
}

// ---------------------------------------------------------------------------
// W-transpose (unchanged)
// ---------------------------------------------------------------------------
__global__ __launch_bounds__(256) void k_transpose(
    const void* W, ushort_t* __restrict__ Wt, int K, int N,
    const int* __restrict__ mf)
{
  const int mode = *mf;
  __shared__ float tile[32][33];
  const int k0 = blockIdx.x*32, n0 = blockIdx.y*32;
  const int c = threadIdx.x & 31, r8 = threadIdx.x >> 5;
  #pragma unroll
  for (int i=0;i<4;i++){
    const int kk = r8 + i*8;
    tile[kk][c] = ldin(W, (size_t)(k0+kk)*N + n0 + c, mode);
  }
  __syncthreads();
  #pragma unroll
  for (int i=0;i<4;i++){
    const int nn = r8 + i*8;
    Wt[(size_t)(n0+nn)*K + k0 + c] = f2bfbits(tile[c][nn]);
  }
}

// ---------------------------------------------------------------------------
// T1: text prep (unchanged)
// ---------------------------------------------------------------------------
__global__ __launch_bounds__(256) void k_text_prep(
    const void* text,
    const void* ref_w, const void* ref_b,
    const void* off_w, const void* off_b,
    const void* aw_w,  const void* aw_b,
    float* __restrict__ loc_out, float* __restrict__ aw_out,
    const int* __restrict__ mf)
{
  const int mode = *mf;
  const int r = blockIdx.x;
  const int t = threadIdx.x;
  __shared__ float x[256];
  __shared__ float refv[6];
  __shared__ float offv[192];
  __shared__ float logit[96];
  x[t] = ldin(text, (size_t)r*256 + t, mode);
  __syncthreads();
  if (t < 192) {
    float s = 0.f;
    for (int k=0;k<256;k++) s += x[k]*ldin(off_w, (size_t)k*192+t, mode);
    offv[t] = s + ldin(off_b, t, mode);
  } else if (t < 198) {
    int j = t-192;
    float s = 0.f;
    for (int k=0;k<256;k++) s += x[k]*ldin(ref_w, (size_t)k*6+j, mode);
    s += ldin(ref_b, j, mode);
    refv[j] = 1.f/(1.f+expf(-s));
  }
  if (t < 96) {
    float s = 0.f;
    for (int k=0;k<256;k++) s += x[k]*ldin(aw_w, (size_t)k*96+t, mode);
    logit[t] = s + ldin(aw_b, t, mode);
  }
  __syncthreads();
  if (t < 8) {
    float mx = -1e30f;
    for (int j=0;j<12;j++) mx = fmaxf(mx, logit[t*12+j]);
    float e[12]; float den = 0.f;
    for (int j=0;j<12;j++){ e[j] = expf(logit[t*12+j]-mx); den += e[j]; }
    float inv = 1.f/den;
    for (int j=0;j<12;j++) aw_out[(size_t)r*96 + t*12 + j] = e[j]*inv;
  }
  if (t < 192) {
    int rem = t % 24;
    int l = rem >> 3;
    int c = t & 1;
    const float normW[3] = {96.f,48.f,24.f};
    const float normH[3] = {72.f,36.f,18.f};
    float nrm = (c==0) ? normW[l] : normH[l];
    loc_out[(size_t)r*192 + t] = refv[l*2+c] + offv[t]/nrm;
  }
}

// ---------------------------------------------------------------------------
// T2: deformable sampling, lazy vproj (unchanged)
// ---------------------------------------------------------------------------
__global__ __launch_bounds__(64) void k_deform(
    const void* vis_value, const char* __restrict__ vmask,
    const void* vproj_w, const void* vproj_b,
    const float* __restrict__ loc, const float* __restrict__ aw,
    float* __restrict__ ctx_out, const int* __restrict__ mf)
{
  const int mode = *mf;
  const int blk = blockIdx.x;      // r*8 + h
  const int r = blk >> 3;
  const int h = blk & 7;
  const int b = r >> 5;
  const int t = threadIdx.x;
  const int Hs[3] = {72,36,18};
  const int Wsz[3] = {96,48,24};
  const int stl[3] = {0,6912,8640};
  float s0=0.f,s1=0.f,s2=0.f,s3=0.f, wsum=0.f;
  for (int l=0;l<3;l++){
    for (int p=0;p<4;p++){
      const int sIdx = blk*12 + l*4 + p;
      const float a  = aw[sIdx];
      const float X = loc[sIdx*2+0]*(float)Wsz[l] - 0.5f;
      const float Y = loc[sIdx*2+1]*(float)Hs[l] - 0.5f;
      const float x0f = floorf(X), y0f = floorf(Y);
      const int x0 = (int)x0f, y0 = (int)y0f;
      const float wx = X-x0f, wy = Y-y0f;
      const float cw[4] = {(1.f-wx)*(1.f-wy), wx*(1.f-wy), (1.f-wx)*wy, wx*wy};
      const int cx[4] = {x0,x0+1,x0,x0+1};
      const int cy[4] = {y0,y0,y0+1,y0+1};
      for (int c=0;c<4;c++){
        if (cx[c]>=0 && cx[c]<Wsz[l] && cy[c]>=0 && cy[c]<Hs[l]){
          const size_t pos = (size_t)b*NVTOK + stl[l] + cy[c]*Wsz[l] + cx[c];
          if (vmask[pos]) continue;
          const float w = a*cw[c];
          wsum += w;
          const size_t base = pos*256 + t*4;
          s0 += w*ldin(vis_value, base+0, mode);
          s1 += w*ldin(vis_value, base+1, mode);
          s2 += w*ldin(vis_value, base+2, mode);
          s3 += w*ldin(vis_value, base+3, mode);
        }
      }
    }
  }
  __shared__ float sh[256];
  sh[t*4+0]=s0; sh[t*4+1]=s1; sh[t*4+2]=s2; sh[t*4+3]=s3;
  __syncthreads();
  if (t < 32) {
    const int col = h*32 + t;
    float acc = wsum * ldin(vproj_b, col, mode);
    for (int k=0;k<256;k++) acc += sh[k]*ldin(vproj_w, (size_t)k*256+col, mode);
    ctx_out[(size_t)r*256 + col] = acc;
  }
}

__device__ __forceinline__ float block_sum(float v, float* red){
  float sm = v;
  #pragma unroll
  for (int o=32;o>0;o>>=1) sm += __shfl_down(sm,o);
  const int t = threadIdx.x;
  __syncthreads();
  if ((t&63)==0) red[t>>6] = sm;
  __syncthreads();
  return red[0]+red[1]+red[2]+red[3];
}

// ---------------------------------------------------------------------------
// MFMA GEMM (text side, unchanged — tiny M, full hi/lo precision)
// ---------------------------------------------------------------------------
__global__ __launch_bounds__(256) void k_mgemm(
    const void* A, size_t a_off, int a_kind,
    const ushort_t* __restrict__ Wt, const void* bias, float* __restrict__ C,
    int N, int K, int relu, const int* __restrict__ mf)
{
  const int mode = *mf;
  const int split = (a_kind==1) || (mode==1);
  __shared__ ushort_t Ah[128*32];
  __shared__ ushort_t Al[128*32];
  __shared__ ushort_t Bt[128*32];
  const int tid = threadIdx.x;
  const int gm0 = blockIdx.x*128, gn0 = blockIdx.y*128;
  const int wv = tid>>6, lane = tid&63;
  const int mh = (wv&1)*64, nh = (wv>>1)*64;
  const int r16 = lane&15, q8 = (lane>>4)*8;
  const int srow = tid>>1, sseg = (tid&1)*16;
  v4f acc[4][4];
  #pragma unroll
  for (int i=0;i<4;i++)
    #pragma unroll
    for (int j=0;j<4;j++) acc[i][j] = (v4f){0.f,0.f,0.f,0.f};

  for (int k0=0; k0<K; k0+=32){
    if (k0) __syncthreads();
    {
      const ushort_t* src = Wt + (size_t)(gn0+srow)*K + k0 + sseg;
      ((uint4*)&Bt[srow*32+sseg])[0]   = ((const uint4*)src)[0];
      ((uint4*)&Bt[srow*32+sseg+8])[0] = ((const uint4*)src)[1];
    }
    if (!split){
      const ushort_t* src = (const ushort_t*)A + a_off + (size_t)(gm0+srow)*K + k0 + sseg;
      ((uint4*)&Ah[srow*32+sseg])[0]   = ((const uint4*)src)[0];
      ((uint4*)&Ah[srow*32+sseg+8])[0] = ((const uint4*)src)[1];
    } else {
      const float* src = (const float*)A + a_off + (size_t)(gm0+srow)*K + k0 + sseg;
      #pragma unroll
      for (int v=0;v<4;v++){
        float4 f = ((const float4*)src)[v];
        float xs[4] = {f.x, f.y, f.z, f.w};
        #pragma unroll
        for (int e=0;e<4;e++){
          const int idx = srow*32 + sseg + v*4 + e;
          const ushort_t h = f2bfbits(xs[e]);
          Ah[idx] = h;
          Al[idx] = f2bfbits(xs[e] - bf2f(h));
        }
      }
    }
    __syncthreads();
    v8s af[4], bfr[4], al[4];
    #pragma unroll
    for (int mt=0;mt<4;mt++){
      af[mt] = *(const v8s*)&Ah[(mh + mt*16 + r16)*32 + q8];
      if (split) al[mt] = *(const v8s*)&Al[(mh + mt*16 + r16)*32 + q8];
    }
    #pragma unroll
    for (int nt=0;nt<4;nt++)
      bfr[nt] = *(const v8s*)&Bt[(nh + nt*16 + r16)*32 + q8];
    #pragma unroll
    for (int mt=0;mt<4;mt++){
      #pragma unroll
      for (int nt=0;nt<4;nt++){
        acc[mt][nt] = __builtin_amdgcn_mfma_f32_16x16x32_bf16(af[mt], bfr[nt], acc[mt][nt], 0, 0, 0);
        if (split)
          acc[mt][nt] = __builtin_amdgcn_mfma_f32_16x16x32_bf16(al[mt], bfr[nt], acc[mt][nt], 0, 0, 0);
      }
    }
  }
  const int rq = (lane>>4)*4;
  float bv[4];
  #pragma unroll
  for (int nt=0;nt<4;nt++) bv[nt] = ldin(bias, gn0 + nh + nt*16 + r16, mode);
  #pragma unroll
  for (int mt=0;mt<4;mt++){
    #pragma unroll
    for (int r=0;r<4;r++){
      const size_t ro = (size_t)(gm0 + mh + mt*16 + rq + r)*N + gn0 + nh + r16;
      #pragma unroll
      for (int nt=0;nt<4;nt++){
        float v = acc[mt][nt][r] + bv[nt];
        if (relu) v = fmaxf(v, 0.f);
        C[ro + nt*16] = v;
      }
    }
  }
}

// ---------------------------------------------------------------------------
// V3 MFMA GEMM (vis q/o proj): single-pass bf16 activations, gload_lds
// staging, XCD-bijective swizzle (unchanged from R5).
// ---------------------------------------------------------------------------
__global__ __launch_bounds__(256) void k_mgemm3(
    const void* A, size_t a_off, int a_kind,
    const ushort_t* __restrict__ Wt, const void* bias,
    float* __restrict__ Cf, ushort_t* __restrict__ Chi,
    int N, int K, int relu, const int* __restrict__ mf)
{
  const int mode = *mf;
  const int rawf32 = (a_kind==0) && (mode==1);
  __shared__ ushort_t Ah[128*32];
  __shared__ ushort_t Bt[128*32];
  const int tid = threadIdx.x;
  const int nbx = gridDim.x, nby = gridDim.y;
  const int total = nbx*nby;
  const int f = blockIdx.y*nbx + blockIdx.x;
  const int qq = total>>3, rr = total&7;
  const int xcd = f&7, pos = f>>3;
  const int wg = (xcd<rr ? xcd*(qq+1) : rr*(qq+1) + (xcd-rr)*qq) + pos;
  const int gm0 = (wg / nby)*128, gn0 = (wg % nby)*128;

  const int wv = tid>>6, lane = tid&63;
  const int mh = (wv&1)*64, nh = (wv>>1)*64;
  const int r16 = lane&15, q8 = (lane>>4)*8;
  const int grow = tid>>2;
  const int gcol = (tid&3)*8;
  const int srow = tid>>1, sseg = (tid&1)*16;
  const ushort_t* Abf = (const ushort_t*)A + a_off;
  v4f acc[4][4];
  #pragma unroll
  for (int i=0;i<4;i++)
    #pragma unroll
    for (int j=0;j<4;j++) acc[i][j] = (v4f){0.f,0.f,0.f,0.f};

  for (int k0=0; k0<K; k0+=32){
    if (k0) __syncthreads();
    gload_lds16(Wt + (size_t)(gn0+grow)*K    + k0 + gcol, &Bt[grow*32      + gcol]);
    gload_lds16(Wt + (size_t)(gn0+grow+64)*K + k0 + gcol, &Bt[(grow+64)*32 + gcol]);
    if (!rawf32){
      gload_lds16(Abf + (size_t)(gm0+grow)*K    + k0 + gcol, &Ah[grow*32      + gcol]);
      gload_lds16(Abf + (size_t)(gm0+grow+64)*K + k0 + gcol, &Ah[(grow+64)*32 + gcol]);
    } else {
      const float* src = (const float*)A + a_off + (size_t)(gm0+srow)*K + k0 + sseg;
      #pragma unroll
      for (int v=0;v<4;v++){
        float4 fq = ((const float4*)src)[v];
        float xs[4] = {fq.x, fq.y, fq.z, fq.w};
        #pragma unroll
        for (int e=0;e<4;e++)
          Ah[srow*32 + sseg + v*4 + e] = f2bfbits(xs[e]);
      }
    }
    __syncthreads();
    v8s af[4], bfr[4];
    #pragma unroll
    for (int mt=0;mt<4;mt++)
      af[mt] = *(const v8s*)&Ah[(mh + mt*16 + r16)*32 + q8];
    #pragma unroll
    for (int nt=0;nt<4;nt++)
      bfr[nt] = *(const v8s*)&Bt[(nh + nt*16 + r16)*32 + q8];
    #pragma unroll
    for (int mt=0;mt<4;mt++){
      #pragma unroll
      for (int nt=0;nt<4;nt++)
        acc[mt][nt] = __builtin_amdgcn_mfma_f32_16x16x32_bf16(af[mt], bfr[nt], acc[mt][nt], 0, 0, 0);
    }
  }
  const int rq = (lane>>4)*4;
  float bv[4];
  #pragma unroll
  for (int nt=0;nt<4;nt++) bv[nt] = ldin(bias, gn0 + nh + nt*16 + r16, mode);
  const int outf = (Cf != nullptr);
  #pragma unroll
  for (int mt=0;mt<4;mt++){
    #pragma unroll
    for (int r=0;r<4;r++){
      const size_t ro = (size_t)(gm0 + mh + mt*16 + rq + r)*N + gn0 + nh + r16;
      #pragma unroll
      for (int nt=0;nt<4;nt++){
        float v = acc[mt][nt][r] + bv[nt];
        if (relu) v = fmaxf(v, 0.f);
        if (outf) Cf[ro + nt*16] = v;
        else      Chi[ro + nt*16] = f2bfbits(v);
      }
    }
  }
}

// ---------------------------------------------------------------------------
// FUSED vis FFN: y = relu(x@W1+b1)@W2+b2, x=v1H bf16 [M][256].
// Block = 128 rows, 512 thr = 8 waves. No LDS staging for GEMM operands:
// A (x rows: L2-resident per block) and B (W1/W2: 0.5 MB each, L2-resident
// chip-wide) fragments load directly global->VGPR. Only the h_j [128][128]
// bf16 intermediate goes through LDS (32 KB, XOR-swizzled byte^=(row&7)<<4
// -> 2-way max on ds_read_b128). 2 barriers per j-slice (16 total).
// Eliminates the 148 MB hb HBM round-trip entirely.
// h-GEMM: wave = 64 rows x 32 cols (rh=(wv&1)*64, cs=(wv>>1)*32).
// y-GEMM: wave = 64 rows x 64 cols (cq=(wv>>1)*64), yacc[4][4] across j.
// ---------------------------------------------------------------------------
__global__ __launch_bounds__(512) void k_ffn(
    const ushort_t* __restrict__ X,      // [M][256] bf16
    const ushort_t* __restrict__ W1t,    // [1024][256] bf16
    const void* b1,
    const ushort_t* __restrict__ W2t,    // [256][1024] bf16
    const void* b2,
    float* __restrict__ Y,               // [M][256] fp32
    const int* __restrict__ mf)
{
  const int mode = *mf;
  __shared__ ushort_t h[128*128];
  const int tid = threadIdx.x;
  const int wv = tid>>6, lane = tid&63;
  const int r16 = lane&15, kq = lane>>4, q8 = kq*8;
  const int rh = (wv&1)*64;
  const int cs = (wv>>1)*32;
  const int cq = (wv>>1)*64;
  const int gm0 = blockIdx.x*128;
  v4f yacc[4][4];
  #pragma unroll
  for (int i=0;i<4;i++)
    #pragma unroll
    for (int j=0;j<4;j++) yacc[i][j] = (v4f){0.f,0.f,0.f,0.f};

  for (int j=0; j<8; ++j){
    // ---- h_j = relu(x @ W1[:, j*128 .. +128) + b1) ----
    v4f hacc[4][2];
    #pragma unroll
    for (int i=0;i<4;i++){ hacc[i][0]=(v4f){0.f,0.f,0.f,0.f}; hacc[i][1]=(v4f){0.f,0.f,0.f,0.f}; }
    #pragma unroll
    for (int k=0;k<8;++k){
      v8s af[4], bf[2];
      #pragma unroll
      for (int mt=0;mt<4;mt++)
        af[mt] = *(const v8s*)&X[(size_t)(gm0 + rh + mt*16 + r16)*256 + k*32 + q8];
      #pragma unroll
      for (int nt=0;nt<2;nt++)
        bf[nt] = *(const v8s*)&W1t[(size_t)(j*128 + cs + nt*16 + r16)*256 + k*32 + q8];
      #pragma unroll
      for (int mt=0;mt<4;mt++)
        #pragma unroll
        for (int nt=0;nt<2;nt++)
          hacc[mt][nt] = __builtin_amdgcn_mfma_f32_16x16x32_bf16(af[mt], bf[nt], hacc[mt][nt], 0,0,0);
    }
    if (j) __syncthreads();   // previous y-GEMM done reading h
    #pragma unroll
    for (int nt=0;nt<2;nt++){
      const int col = cs + nt*16 + r16;
      const float bb = ldin(b1, j*128 + col, mode);
      const int c2hi = (col*2) & ~15, c2lo = (col*2) & 15;
      #pragma unroll
      for (int mt=0;mt<4;mt++){
        #pragma unroll
        for (int r=0;r<4;r++){
          const int row = rh + mt*16 + kq*4 + r;
          const float v = fmaxf(hacc[mt][nt][r] + bb, 0.f);
          const int byte = row*256 + (c2hi ^ ((row&7)<<4)) + c2lo;
          h[byte>>1] = f2bfbits(v);
        }
      }
    }
    __syncthreads();
    // ---- y += h_j @ W2[j*128 .. +128, :] ----
    #pragma unroll
    for (int kk=0;kk<4;++kk){
      v8s af2[4], bf2[4];
      #pragma unroll
      for (int mt=0;mt<4;mt++){
        const int row = rh + mt*16 + r16;
        const int byte = row*256 + (((kk*32 + q8)*2) ^ ((row&7)<<4));
        af2[mt] = *(const v8s*)&h[byte>>1];
      }
      #pragma unroll
      for (int nt=0;nt<4;nt++)
        bf2[nt] = *(const v8s*)&W2t[(size_t)(cq + nt*16 + r16)*1024 + j*128 + kk*32 + q8];
      #pragma unroll
      for (int mt=0;mt<4;mt++)
        #pragma unroll
        for (int nt=0;nt<4;nt++)
          yacc[mt][nt] = __builtin_amdgcn_mfma_f32_16x16x32_bf16(af2[mt], bf2[nt], yacc[mt][nt], 0,0,0);
    }
  }
  // ---- epilogue ----
  const int rq = kq*4;
  #pragma unroll
  for (int nt=0;nt<4;nt++){
    const float bb = ldin(b2, cq + nt*16 + r16, mode);
    #pragma unroll
    for (int mt=0;mt<4;mt++){
      #pragma unroll
      for (int r=0;r<4;r++)
        Y[(size_t)(gm0 + rh + mt*16 + rq + r)*256 + cq + nt*16 + r16] = yacc[mt][nt][r] + bb;
    }
  }
}

// ---------------------------------------------------------------------------
// KV split/transpose prep (unchanged)
// ---------------------------------------------------------------------------
__global__ __launch_bounds__(256) void k_kvsplit(
    const float* __restrict__ kws, const float* __restrict__ vws,
    ushort_t* __restrict__ khi, ushort_t* __restrict__ klo,
    ushort_t* __restrict__ vthi, ushort_t* __restrict__ vtlo)
{
  const int row = blockIdx.x;        // 0..255 = b*32 + key
  const int b = row >> 5, key = row & 31;
  const int t = threadIdx.x;         // dim 0..255
  const float f = kws[(size_t)row*256 + t];
  const ushort_t fh = f2bfbits(f);
  khi[(size_t)row*256 + t] = fh;
  klo[(size_t)row*256 + t] = f2bfbits(f - bf2f(fh));
  const float g = vws[(size_t)row*256 + t];
  const ushort_t gh = f2bfbits(g);
  const size_t vt = ((size_t)b*256 + t)*32 + key;
  vthi[vt] = gh;
  vtlo[vt] = f2bfbits(g - bf2f(gh));
}

// ---------------------------------------------------------------------------
// A2: MFMA MHA (unchanged from R5)
// ---------------------------------------------------------------------------
__global__ __launch_bounds__(256) void k_attn2(
    const ushort_t* __restrict__ qcH,
    ushort_t* __restrict__ aoh,
    const ushort_t* __restrict__ khi, const ushort_t* __restrict__ klo,
    const ushort_t* __restrict__ vthi, const ushort_t* __restrict__ vtlo,
    const char* __restrict__ tmask, int r0)
{
  __shared__ float P[4][16][36];
  const int tid = threadIdx.x;
  const int wv = tid>>6, lane = tid&63;
  const int lrow0 = blockIdx.x*64 + wv*16;
  const int b = (r0 + lrow0)/NVTOK;
  const int m16 = lane&15;
  const int kq = lane>>4;
  const int q8 = kq*8;
  const int key0 = m16, key1 = m16+16;
  const bool msk0 = tmask[b*LT + key0] != 0;
  const bool msk1 = tmask[b*LT + key1] != 0;
  const float scale = 0.17677669529663687f;

  for (int h=0; h<8; ++h){
    const size_t qoff = (size_t)(lrow0 + m16)*256 + h*32 + q8;
    const v8s qh = *(const v8s*)&qcH[qoff];
    const size_t kb0 = ((size_t)(b*32+key0)*256) + h*32 + q8;
    const size_t kb1 = ((size_t)(b*32+key1)*256) + h*32 + q8;
    const v8s kh0 = *(const v8s*)&khi[kb0];
    const v8s kl0 = *(const v8s*)&klo[kb0];
    const v8s kh1 = *(const v8s*)&khi[kb1];
    const v8s kl1 = *(const v8s*)&klo[kb1];
    v4f s0 = (v4f){0.f,0.f,0.f,0.f}, s1 = (v4f){0.f,0.f,0.f,0.f};
    s0 = __builtin_amdgcn_mfma_f32_16x16x32_bf16(qh, kh0, s0, 0,0,0);
    s0 = __builtin_amdgcn_mfma_f32_16x16x32_bf16(qh, kl0, s0, 0,0,0);
    s1 = __builtin_amdgcn_mfma_f32_16x16x32_bf16(qh, kh1, s1, 0,0,0);
    s1 = __builtin_amdgcn_mfma_f32_16x16x32_bf16(qh, kl1, s1, 0,0,0);
    float e0[4], e1[4], inv[4];
    #pragma unroll
    for (int r=0;r<4;r++){
      const float a0 = msk0 ? -1e9f : s0[r]*scale;
      const float a1 = msk1 ? -1e9f : s1[r]*scale;
      float mx = fmaxf(a0,a1);
      #pragma unroll
      for (int o=1;o<16;o<<=1) mx = fmaxf(mx, __shfl_xor(mx,o));
      const float x0 = __expf(a0-mx), x1 = __expf(a1-mx);
      float dn = x0+x1;
      #pragma unroll
      for (int o=1;o<16;o<<=1) dn += __shfl_xor(dn,o);
      e0[r]=x0; e1[r]=x1; inv[r] = 1.f/dn;
    }
    #pragma unroll
    for (int r=0;r<4;r++){
      P[wv][kq*4+r][key0] = e0[r];
      P[wv][kq*4+r][key1] = e1[r];
    }
    __syncthreads();
    float pv[8];
    *(float4*)&pv[0] = *(const float4*)&P[wv][m16][q8];
    *(float4*)&pv[4] = *(const float4*)&P[wv][m16][q8+4];
    v8s ph;
    #pragma unroll
    for (int j=0;j<8;j++) ph[j] = (short)f2bfbits(pv[j]);
    const size_t vb0 = ((size_t)(b*256 + h*32 + m16)*32) + q8;
    const size_t vb1 = ((size_t)(b*256 + h*32 + 16 + m16)*32) + q8;
    const v8s vh0 = *(const v8s*)&vthi[vb0];
    const v8s vl0 = *(const v8s*)&vtlo[vb0];
    const v8s vh1 = *(const v8s*)&vthi[vb1];
    const v8s vl1 = *(const v8s*)&vtlo[vb1];
    v4f o0 = (v4f){0.f,0.f,0.f,0.f}, o1 = (v4f){0.f,0.f,0.f,0.f};
    o0 = __builtin_amdgcn_mfma_f32_16x16x32_bf16(ph, vh0, o0, 0,0,0);
    o0 = __builtin_amdgcn_mfma_f32_16x16x32_bf16(ph, vl0, o0, 0,0,0);
    o1 = __builtin_amdgcn_mfma_f32_16x16x32_bf16(ph, vh1, o1, 0,0,0);
    o1 = __builtin_amdgcn_mfma_f32_16x16x32_bf16(ph, vl1, o1, 0,0,0);
    __syncthreads();
    #pragma unroll
    for (int r=0;r<4;r++){
      const size_t ro = (size_t)(lrow0 + kq*4 + r)*256 + h*32;
      aoh[ro + m16]      = f2bfbits(o0[r]*inv[r]);
      aoh[ro + 16 + m16] = f2bfbits(o1[r]*inv[r]);
    }
  }
}

// ---------------------------------------------------------------------------
// residual + two-pass LayerNorm (text side, unchanged)
// ---------------------------------------------------------------------------
__global__ __launch_bounds__(256) void k_add_ln(
    const float* __restrict__ X, const void* R, size_t r_off, int r_f32,
    void* OUT, size_t o_off, int o_f32,
    void* OUT2, size_t o2_off,
    const void* g, const void* be, const int* __restrict__ mf)
{
  const int mode = *mf;
  const int row = blockIdx.x; const int t = threadIdx.x;
  const size_t idx = (size_t)row*256 + t;
  __shared__ float red[4];
  const float rv = r_f32 ? ((const float*)R)[r_off+idx] : ldin(R, r_off+idx, mode);
  const float v = X[idx] + rv;
  const float m = block_sum(v, red) * (1.f/256.f);
  __syncthreads();
  const float d = v - m;
  const float var = block_sum(d*d, red) * (1.f/256.f);
  const float o = d*rsqrtf(var+1e-5f)*ldin(g,t,mode) + ldin(be,t,mode);
  if (o_f32) ((float*)OUT)[o_off+idx] = o;
  else       stout(OUT, o_off+idx, mode, o);
  if (OUT2)  stout(OUT2, o2_off+idx, mode, o);
}

// ---------------------------------------------------------------------------
// LN1 (vis): v = X + residual(mode-typed) ; out = bf16 hi
// ---------------------------------------------------------------------------
__global__ __launch_bounds__(256) void k_add_ln_h(
    const float* __restrict__ X, const void* R, size_t r_off,
    ushort_t* __restrict__ OH,
    const void* g, const void* be, const int* __restrict__ mf)
{
  const int mode = *mf;
  const int row = blockIdx.x; const int t = threadIdx.x;
  const size_t idx = (size_t)row*256 + t;
  __shared__ float red[4];
  const float rv = ldin(R, r_off+idx, mode);
  const float v = X[idx] + rv;
  const float m = block_sum(v, red) * (1.f/256.f);
  __syncthreads();
  const float d = v - m;
  const float var = block_sum(d*d, red) * (1.f/256.f);
  const float o = d*rsqrtf(var+1e-5f)*ldin(g,t,mode) + ldin(be,t,mode);
  OH[idx] = f2bfbits(o);
}

// ---------------------------------------------------------------------------
// LN2 (vis): v = X + RH ; out = mode-typed at offset
// ---------------------------------------------------------------------------
__global__ __launch_bounds__(256) void k_add_ln_pres(
    const float* __restrict__ X,
    const ushort_t* __restrict__ RH,
    void* OUT, size_t o_off,
    const void* g, const void* be, const int* __restrict__ mf)
{
  const int mode = *mf;
  const int row = blockIdx.x; const int t = threadIdx.x;
  const size_t idx = (size_t)row*256 + t;
  __shared__ float red[4];
  const float rv = bf2f(RH[idx]);
  const float v = X[idx] + rv;
  const float m = block_sum(v, red) * (1.f/256.f);
  __syncthreads();
  const float d = v - m;
  const float var = block_sum(d*d, red) * (1.f/256.f);
  const float o = d*rsqrtf(var+1e-5f)*ldin(g,t,mode) + ldin(be,t,mode);
  stout(OUT, o_off+idx, mode, o);
}

// ---------------------------------------------------------------------------
extern "C" void kernel_launch(void* const* d_in, const int* in_sizes, int n_in,
                              void* d_out, int out_size, void* d_ws, size_t ws_size,
                              hipStream_t stream)
{
  (void)n_in; (void)out_size;
  const void* vis_tokens = d_in[0];
  const void* text_tokens= d_in[1];
  const void* vis_value  = d_in[2];
  const void* ref_w = d_in[3];  const void* ref_b = d_in[4];
  const void* off_w = d_in[5];  const void* off_b = d_in[6];
  const void* aw_w  = d_in[7];  const void* aw_b  = d_in[8];
  const void* vproj_w = d_in[9];  const void* vproj_b = d_in[10];
  const void* oproj_w = d_in[11]; const void* oproj_b = d_in[12];
  const void* lvi_out_w = d_in[13]; const void* lvi_out_b = d_in[14];
  const void* lvi_n1_s = d_in[15];  const void* lvi_n1_b = d_in[16];
  const void* lvi_f1_w = d_in[17];  const void* lvi_f1_b = d_in[18];
  const void* lvi_f2_w = d_in[19];  const void* lvi_f2_b = d_in[20];
  const void* lvi_n2_s = d_in[21];  const void* lvi_n2_b = d_in[22];
  const void* mha_qw = d_in[23]; const void* mha_qb = d_in[24];
  const void* mha_kw = d_in[25]; const void* mha_kb = d_in[26];
  const void* mha_vw = d_in[27]; const void* mha_vb = d_in[28];
  const void* mha_ow = d_in[29]; const void* mha_ob = d_in[30];
  const void* vli_out_w = d_in[31]; const void* vli_out_b = d_in[32];
  const void* vli_n1_s = d_in[33];  const void* vli_n1_b = d_in[34];
  const void* vli_f1_w = d_in[35];  const void* vli_f1_b = d_in[36];
  const void* vli_f2_w = d_in[37];  const void* vli_f2_b = d_in[38];
  const void* vli_n2_s = d_in[39];  const void* vli_n2_b = d_in[40];
  const char* tmask = (const char*)d_in[43];
  const char* vmask = (const char*)d_in[44];

  // ---- workspace layout ----
  char* ws = (char*)d_ws;
  int*   flag    = (int*)  (ws + 0);               // 256 B
  float* loc_ws  = (float*)(ws + 256);             // 196608
  float* aw_ws   = (float*)(ws + 196864);          //  98304
  float* ctxt_ws = (float*)(ws + 295168);          // 262144
  float* t_ws    = (float*)(ws + 557312);          // 262144
  float* tout_ws = (float*)(ws + 819456);          // 262144
  float* k_ws    = (float*)(ws + 1081600);         // 262144
  float* v_ws    = (float*)(ws + 1343744);         // 262144
  ushort_t* wtq  = (ushort_t*)(ws + 1605888ull);   // 131072 B
  ushort_t* wto  = (ushort_t*)(ws + 1736960ull);   // 131072 B
  ushort_t* wtf1 = (ushort_t*)(ws + 1868032ull);   // 524288 B
  ushort_t* wtf2 = (ushort_t*)(ws + 2392320ull);   // 524288 B
  ushort_t* wtk   = (ushort_t*)(ws + 2916608ull);  // 131072 B (mha_kw^T)
  ushort_t* wtv   = (ushort_t*)(ws + 3047680ull);  // 131072 B (mha_vw^T)
  ushort_t* wtop  = (ushort_t*)(ws + 3178752ull);  // 131072 B (oproj_w^T)
  ushort_t* wtlo  = (ushort_t*)(ws + 3309824ull);  // 131072 B (lvi_out_w^T)
  ushort_t* wtlf1 = (ushort_t*)(ws + 3440896ull);  // 524288 B (lvi_f1_w^T)
  ushort_t* wtlf2 = (ushort_t*)(ws + 3965184ull);  // 524288 B (lvi_f2_w^T)
  float* hbuf_t   = (float*)(ws + 4489472ull);     // 1048576 B (256x1024)
  float* ybuf     = (float*)(ws + 5538048ull);     // 262144 B
  float* fbuf     = (float*)(ws + 5800192ull);     // 262144 B
  ushort_t* khi   = (ushort_t*)(ws + 6062336ull);  // 131072 B
  ushort_t* klo   = (ushort_t*)(ws + 6193408ull);  // 131072 B
  ushort_t* vthi  = (ushort_t*)(ws + 6324480ull);  // 131072 B
  ushort_t* vtlo  = (ushort_t*)(ws + 6455552ull);  // 131072 B
  const size_t fe = 6586624ull;                    // chunk region start

  // per-row chunk bytes (2048 B/row), hb eliminated by fused FFN:
  //   region0 (1024 B): ubuf fp32; first 512 B alias qc bf16 (dead after attn2)
  //   region1 ( 512 B): v1 bf16
  //   region2 ( 512 B): ao bf16
  long long R_ll = 128;
  if (ws_size > fe) R_ll = (long long)((ws_size - fe) / 2048ull);
  if (R_ll > (long long)MVIS) R_ll = MVIS;
  R_ll &= ~127LL;
  if (R_ll < 128) R_ll = 128;
  const int R = (int)R_ll;
  ushort_t* qcH  = (ushort_t*)(ws + fe);                      // region0 alias
  float*    ubuf = (float*)   (ws + fe);                      // region0
  ushort_t* v1H  = (ushort_t*)(ws + fe + (size_t)R*1024ull);  // region1
  ushort_t* aoH  = (ushort_t*)(ws + fe + (size_t)R*1536ull);  // region2

  // ---- dtype detect ----
  int ndw = in_sizes[1]/2; if (ndw < 1) ndw = 1;
  k_detect<<<1,256,0,stream>>>((const uint_t*)text_tokens, ndw, flag);

  // ---- weight transposes for MFMA GEMMs ----
  k_transpose<<<dim3(8,8),  256,0,stream>>>(mha_qw,    wtq,   256, 256,  flag);
  k_transpose<<<dim3(8,8),  256,0,stream>>>(mha_ow,    wto,   256, 256,  flag);
  k_transpose<<<dim3(8,32), 256,0,stream>>>(vli_f1_w,  wtf1,  256, 1024, flag);
  k_transpose<<<dim3(32,8), 256,0,stream>>>(vli_f2_w,  wtf2,  1024, 256, flag);
  k_transpose<<<dim3(8,8),  256,0,stream>>>(mha_kw,    wtk,   256, 256,  flag);
  k_transpose<<<dim3(8,8),  256,0,stream>>>(mha_vw,    wtv,   256, 256,  flag);
  k_transpose<<<dim3(8,8),  256,0,stream>>>(oproj_w,   wtop,  256, 256,  flag);
  k_transpose<<<dim3(8,8),  256,0,stream>>>(lvi_out_w, wtlo,  256, 256,  flag);
  k_transpose<<<dim3(8,32), 256,0,stream>>>(lvi_f1_w,  wtlf1, 256, 1024, flag);
  k_transpose<<<dim3(32,8), 256,0,stream>>>(lvi_f2_w,  wtlf2, 1024, 256, flag);

  // ---- text side ----
  k_text_prep<<<MTEXT,256,0,stream>>>(text_tokens, ref_w, ref_b, off_w, off_b,
                                      aw_w, aw_b, loc_ws, aw_ws, flag);
  k_deform<<<MTEXT*NHEAD,64,0,stream>>>(vis_value, vmask, vproj_w, vproj_b,
                                        loc_ws, aw_ws, ctxt_ws, flag);

  // attn-out path: y = ctx@oproj + b ; z = y@lvi_out + b ; t = LN(text + z)
  {
    dim3 g22(2,2);
    k_mgemm<<<g22,256,0,stream>>>(ctxt_ws, 0, 1, wtop, oproj_b, ybuf, 256, 256, 0, flag);
    k_mgemm<<<g22,256,0,stream>>>(ybuf,    0, 1, wtlo, lvi_out_b, fbuf, 256, 256, 0, flag);
    k_add_ln<<<MTEXT,256,0,stream>>>(fbuf, text_tokens, 0, 0,
                                     t_ws, 0, 1, nullptr, 0, lvi_n1_s, lvi_n1_b, flag);
  }
  // ffn path: h = relu(t@f1+b1) ; f = h@f2+b2 ; tout = LN(t + f)
  {
    dim3 g28(2,8), g22(2,2);
    k_mgemm<<<g28,256,0,stream>>>(t_ws,   0, 1, wtlf1, lvi_f1_b, hbuf_t, 1024, 256, 1, flag);
    k_mgemm<<<g22,256,0,stream>>>(hbuf_t, 0, 1, wtlf2, lvi_f2_b, fbuf,   256, 1024, 0, flag);
    k_add_ln<<<MTEXT,256,0,stream>>>(fbuf, t_ws, 0, 1,
                                     tout_ws, 0, 1, d_out, VISSZ, lvi_n2_s, lvi_n2_b, flag);
  }
  // k/v projection of text_out + bf16 hi/lo split (+ V transpose)
  {
    dim3 g22(2,2);
    k_mgemm<<<g22,256,0,stream>>>(tout_ws, 0, 1, wtk, mha_kb, k_ws, 256, 256, 0, flag);
    k_mgemm<<<g22,256,0,stream>>>(tout_ws, 0, 1, wtv, mha_vb, v_ws, 256, 256, 0, flag);
    k_kvsplit<<<256,256,0,stream>>>(k_ws, v_ws, khi, klo, vthi, vtlo);
  }

  // ---- vis side, chunked by R rows ----
  for (int r0 = 0; r0 < MVIS; r0 += R){
    const int nr = (MVIS - r0 < R) ? (MVIS - r0) : R;   // multiple of 128
    dim3 g2(nr/128, 2);
    k_mgemm3<<<g2,256,0,stream>>>(vis_tokens, (size_t)r0*256, 0,
                                  wtq, mha_qb, nullptr, qcH, 256, 256, 0, flag);
    k_attn2<<<nr/64,256,0,stream>>>(qcH, aoH, khi, klo, vthi, vtlo, tmask, r0);
    k_mgemm3<<<g2,256,0,stream>>>(aoH, 0, 2,
                                  wto, mha_ob, ubuf, nullptr, 256, 256, 0, flag);
    k_add_ln_h<<<nr,256,0,stream>>>(ubuf, vis_tokens, (size_t)r0*256,
                                    v1H, vli_n1_s, vli_n1_b, flag);
    k_ffn<<<nr/128,512,0,stream>>>(v1H, wtf1, vli_f1_b, wtf2, vli_f2_b, ubuf, flag);
    k_add_ln_pres<<<nr,256,0,stream>>>(ubuf, v1H,
                                       d_out, (size_t)r0*256, vli_n2_s, vli_n2_b, flag);
  }
}

// Round 8
// 984.254 us; speedup vs baseline: 1.1538x; 1.1538x over previous
//
#include <hip/hip_runtime.h>
#include <hip/hip_bf16.h>
#include <math.h>

typedef __hip_bfloat16 bf16;
typedef unsigned short ushort_t;
typedef unsigned int uint_t;
typedef short v8s __attribute__((ext_vector_type(8)));
typedef float v4f __attribute__((ext_vector_type(4)));

#define NVTOK 9072
#define BATCH 8
#define LT 32
#define DMODEL 256
#define NHEAD 8
#define DHEAD 32
#define MVIS (BATCH*NVTOK)   /* 72576 */
#define MTEXT (BATCH*LT)     /* 256 */
#define VISSZ 18579456ull    /* MVIS*256 elements */

__device__ __forceinline__ float bf2f(ushort_t u){ return __uint_as_float(((uint_t)u)<<16); }
__device__ __forceinline__ ushort_t f2bfbits(float f){
  __hip_bfloat16 h = __float2bfloat16(f);
  union { __hip_bfloat16 h; ushort_t u; } c; c.h = h; return c.u;
}
// mode: 0 = buffers hold bf16, 1 = buffers hold fp32
__device__ __forceinline__ float ldin(const void* p, size_t i, int mode){
  return mode ? ((const float*)p)[i] : bf2f(((const ushort_t*)p)[i]);
}
__device__ __forceinline__ void stout(void* p, size_t i, int mode, float v){
  if (mode) ((float*)p)[i] = v; else ((ushort_t*)p)[i] = f2bfbits(v);
}

// async global->LDS, 16 B per lane (LDS dest = wave-uniform base + lane*16;
// global SOURCE address is per-lane, so row-clamping on the source is legal).
__device__ __forceinline__ void gload_lds16(const void* g, void* l){
  __builtin_amdgcn_global_load_lds(
      (const __attribute__((address_space(1))) unsigned int*)g,
      (__attribute__((address_space(3))) unsigned int*)l, 16, 0, 0);
}

// ---------------------------------------------------------------------------
// D0: dtype detector (unchanged)
// ---------------------------------------------------------------------------
__global__ void k_detect(const uint_t* __restrict__ buf, int n_avail, int* __restrict__ flag){
  __shared__ int zc, bc;
  if (threadIdx.x==0){ zc=0; bc=0; }
  __syncthreads();
  int stride = n_avail/2048; if (stride < 1) stride = 1;
  int nz=0, nb=0;
  for (int i=threadIdx.x; i<2048; i+=256){
    long long idx = (long long)i*stride;
    if (idx >= n_avail) break;
    uint_t d = buf[idx];
    uint_t lo = d & 0xFFFFu;
    int e = (int)((lo >> 7) & 0xFF);
    if (lo == 0) nz++;
    else if (e >= 90 && e <= 160) nb++;
  }
  atomicAdd(&zc, nz); atomicAdd(&bc, nb);
  __syncthreads();
  if (threadIdx.x==0){
    int mode;
    if (zc > 1024) mode = 1;
    else if (bc > 1228) mode = 0;
    else mode = 1;
    *flag = mode;
  }
}

// ---------------------------------------------------------------------------
// W-transpose (unchanged)
// ---------------------------------------------------------------------------
__global__ __launch_bounds__(256) void k_transpose(
    const void* W, ushort_t* __restrict__ Wt, int K, int N,
    const int* __restrict__ mf)
{
  const int mode = *mf;
  __shared__ float tile[32][33];
  const int k0 = blockIdx.x*32, n0 = blockIdx.y*32;
  const int c = threadIdx.x & 31, r8 = threadIdx.x >> 5;
  #pragma unroll
  for (int i=0;i<4;i++){
    const int kk = r8 + i*8;
    tile[kk][c] = ldin(W, (size_t)(k0+kk)*N + n0 + c, mode);
  }
  __syncthreads();
  #pragma unroll
  for (int i=0;i<4;i++){
    const int nn = r8 + i*8;
    Wt[(size_t)(n0+nn)*K + k0 + c] = f2bfbits(tile[c][nn]);
  }
}

// ---------------------------------------------------------------------------
// T1: text prep (unchanged)
// ---------------------------------------------------------------------------
__global__ __launch_bounds__(256) void k_text_prep(
    const void* text,
    const void* ref_w, const void* ref_b,
    const void* off_w, const void* off_b,
    const void* aw_w,  const void* aw_b,
    float* __restrict__ loc_out, float* __restrict__ aw_out,
    const int* __restrict__ mf)
{
  const int mode = *mf;
  const int r = blockIdx.x;
  const int t = threadIdx.x;
  __shared__ float x[256];
  __shared__ float refv[6];
  __shared__ float offv[192];
  __shared__ float logit[96];
  x[t] = ldin(text, (size_t)r*256 + t, mode);
  __syncthreads();
  if (t < 192) {
    float s = 0.f;
    for (int k=0;k<256;k++) s += x[k]*ldin(off_w, (size_t)k*192+t, mode);
    offv[t] = s + ldin(off_b, t, mode);
  } else if (t < 198) {
    int j = t-192;
    float s = 0.f;
    for (int k=0;k<256;k++) s += x[k]*ldin(ref_w, (size_t)k*6+j, mode);
    s += ldin(ref_b, j, mode);
    refv[j] = 1.f/(1.f+expf(-s));
  }
  if (t < 96) {
    float s = 0.f;
    for (int k=0;k<256;k++) s += x[k]*ldin(aw_w, (size_t)k*96+t, mode);
    logit[t] = s + ldin(aw_b, t, mode);
  }
  __syncthreads();
  if (t < 8) {
    float mx = -1e30f;
    for (int j=0;j<12;j++) mx = fmaxf(mx, logit[t*12+j]);
    float e[12]; float den = 0.f;
    for (int j=0;j<12;j++){ e[j] = expf(logit[t*12+j]-mx); den += e[j]; }
    float inv = 1.f/den;
    for (int j=0;j<12;j++) aw_out[(size_t)r*96 + t*12 + j] = e[j]*inv;
  }
  if (t < 192) {
    int rem = t % 24;
    int l = rem >> 3;
    int c = t & 1;
    const float normW[3] = {96.f,48.f,24.f};
    const float normH[3] = {72.f,36.f,18.f};
    float nrm = (c==0) ? normW[l] : normH[l];
    loc_out[(size_t)r*192 + t] = refv[l*2+c] + offv[t]/nrm;
  }
}

// ---------------------------------------------------------------------------
// T2: deformable sampling, lazy vproj (unchanged)
// ---------------------------------------------------------------------------
__global__ __launch_bounds__(64) void k_deform(
    const void* vis_value, const char* __restrict__ vmask,
    const void* vproj_w, const void* vproj_b,
    const float* __restrict__ loc, const float* __restrict__ aw,
    float* __restrict__ ctx_out, const int* __restrict__ mf)
{
  const int mode = *mf;
  const int blk = blockIdx.x;      // r*8 + h
  const int r = blk >> 3;
  const int h = blk & 7;
  const int b = r >> 5;
  const int t = threadIdx.x;
  const int Hs[3] = {72,36,18};
  const int Wsz[3] = {96,48,24};
  const int stl[3] = {0,6912,8640};
  float s0=0.f,s1=0.f,s2=0.f,s3=0.f, wsum=0.f;
  for (int l=0;l<3;l++){
    for (int p=0;p<4;p++){
      const int sIdx = blk*12 + l*4 + p;
      const float a  = aw[sIdx];
      const float X = loc[sIdx*2+0]*(float)Wsz[l] - 0.5f;
      const float Y = loc[sIdx*2+1]*(float)Hs[l] - 0.5f;
      const float x0f = floorf(X), y0f = floorf(Y);
      const int x0 = (int)x0f, y0 = (int)y0f;
      const float wx = X-x0f, wy = Y-y0f;
      const float cw[4] = {(1.f-wx)*(1.f-wy), wx*(1.f-wy), (1.f-wx)*wy, wx*wy};
      const int cx[4] = {x0,x0+1,x0,x0+1};
      const int cy[4] = {y0,y0,y0+1,y0+1};
      for (int c=0;c<4;c++){
        if (cx[c]>=0 && cx[c]<Wsz[l] && cy[c]>=0 && cy[c]<Hs[l]){
          const size_t pos = (size_t)b*NVTOK + stl[l] + cy[c]*Wsz[l] + cx[c];
          if (vmask[pos]) continue;
          const float w = a*cw[c];
          wsum += w;
          const size_t base = pos*256 + t*4;
          s0 += w*ldin(vis_value, base+0, mode);
          s1 += w*ldin(vis_value, base+1, mode);
          s2 += w*ldin(vis_value, base+2, mode);
          s3 += w*ldin(vis_value, base+3, mode);
        }
      }
    }
  }
  __shared__ float sh[256];
  sh[t*4+0]=s0; sh[t*4+1]=s1; sh[t*4+2]=s2; sh[t*4+3]=s3;
  __syncthreads();
  if (t < 32) {
    const int col = h*32 + t;
    float acc = wsum * ldin(vproj_b, col, mode);
    for (int k=0;k<256;k++) acc += sh[k]*ldin(vproj_w, (size_t)k*256+col, mode);
    ctx_out[(size_t)r*256 + col] = acc;
  }
}

__device__ __forceinline__ float block_sum(float v, float* red){
  float sm = v;
  #pragma unroll
  for (int o=32;o>0;o>>=1) sm += __shfl_down(sm,o);
  const int t = threadIdx.x;
  __syncthreads();
  if ((t&63)==0) red[t>>6] = sm;
  __syncthreads();
  return red[0]+red[1]+red[2]+red[3];
}

// ---------------------------------------------------------------------------
// MFMA GEMM (text side, unchanged — tiny M, full hi/lo precision)
// ---------------------------------------------------------------------------
__global__ __launch_bounds__(256) void k_mgemm(
    const void* A, size_t a_off, int a_kind,
    const ushort_t* __restrict__ Wt, const void* bias, float* __restrict__ C,
    int N, int K, int relu, const int* __restrict__ mf)
{
  const int mode = *mf;
  const int split = (a_kind==1) || (mode==1);
  __shared__ ushort_t Ah[128*32];
  __shared__ ushort_t Al[128*32];
  __shared__ ushort_t Bt[128*32];
  const int tid = threadIdx.x;
  const int gm0 = blockIdx.x*128, gn0 = blockIdx.y*128;
  const int wv = tid>>6, lane = tid&63;
  const int mh = (wv&1)*64, nh = (wv>>1)*64;
  const int r16 = lane&15, q8 = (lane>>4)*8;
  const int srow = tid>>1, sseg = (tid&1)*16;
  v4f acc[4][4];
  #pragma unroll
  for (int i=0;i<4;i++)
    #pragma unroll
    for (int j=0;j<4;j++) acc[i][j] = (v4f){0.f,0.f,0.f,0.f};

  for (int k0=0; k0<K; k0+=32){
    if (k0) __syncthreads();
    {
      const ushort_t* src = Wt + (size_t)(gn0+srow)*K + k0 + sseg;
      ((uint4*)&Bt[srow*32+sseg])[0]   = ((const uint4*)src)[0];
      ((uint4*)&Bt[srow*32+sseg+8])[0] = ((const uint4*)src)[1];
    }
    if (!split){
      const ushort_t* src = (const ushort_t*)A + a_off + (size_t)(gm0+srow)*K + k0 + sseg;
      ((uint4*)&Ah[srow*32+sseg])[0]   = ((const uint4*)src)[0];
      ((uint4*)&Ah[srow*32+sseg+8])[0] = ((const uint4*)src)[1];
    } else {
      const float* src = (const float*)A + a_off + (size_t)(gm0+srow)*K + k0 + sseg;
      #pragma unroll
      for (int v=0;v<4;v++){
        float4 f = ((const float4*)src)[v];
        float xs[4] = {f.x, f.y, f.z, f.w};
        #pragma unroll
        for (int e=0;e<4;e++){
          const int idx = srow*32 + sseg + v*4 + e;
          const ushort_t h = f2bfbits(xs[e]);
          Ah[idx] = h;
          Al[idx] = f2bfbits(xs[e] - bf2f(h));
        }
      }
    }
    __syncthreads();
    v8s af[4], bfr[4], al[4];
    #pragma unroll
    for (int mt=0;mt<4;mt++){
      af[mt] = *(const v8s*)&Ah[(mh + mt*16 + r16)*32 + q8];
      if (split) al[mt] = *(const v8s*)&Al[(mh + mt*16 + r16)*32 + q8];
    }
    #pragma unroll
    for (int nt=0;nt<4;nt++)
      bfr[nt] = *(const v8s*)&Bt[(nh + nt*16 + r16)*32 + q8];
    #pragma unroll
    for (int mt=0;mt<4;mt++){
      #pragma unroll
      for (int nt=0;nt<4;nt++){
        acc[mt][nt] = __builtin_amdgcn_mfma_f32_16x16x32_bf16(af[mt], bfr[nt], acc[mt][nt], 0, 0, 0);
        if (split)
          acc[mt][nt] = __builtin_amdgcn_mfma_f32_16x16x32_bf16(al[mt], bfr[nt], acc[mt][nt], 0, 0, 0);
      }
    }
  }
  const int rq = (lane>>4)*4;
  float bv[4];
  #pragma unroll
  for (int nt=0;nt<4;nt++) bv[nt] = ldin(bias, gn0 + nh + nt*16 + r16, mode);
  #pragma unroll
  for (int mt=0;mt<4;mt++){
    #pragma unroll
    for (int r=0;r<4;r++){
      const size_t ro = (size_t)(gm0 + mh + mt*16 + rq + r)*N + gn0 + nh + r16;
      #pragma unroll
      for (int nt=0;nt<4;nt++){
        float v = acc[mt][nt][r] + bv[nt];
        if (relu) v = fmaxf(v, 0.f);
        C[ro + nt*16] = v;
      }
    }
  }
}

// ---------------------------------------------------------------------------
// V4 MFMA GEMM (vis side): 256x128 tile, 512 thr = 8 waves (4 m-halves x
// 2 n-halves). Doubles MFMA work per barrier vs the 128x128 tile at the
// same barrier count — amortizes the stage+drain stall that capped R6 at
// MfmaUtil 18%. gload_lds16 staging (lane-linear LDS dest); the global
// SOURCE row is clamped per-lane to Mv-1 for the M-tail tile (legal: source
// is per-lane). Workspace rows are rounded to 256 so stores need no guard.
// Single-pass bf16 activations. XCD-bijective block swizzle, n-fastest.
// ---------------------------------------------------------------------------
__global__ __launch_bounds__(512) void k_mgemm4(
    const void* A, size_t a_off, int a_kind,
    const ushort_t* __restrict__ Wt, const void* bias,
    float* __restrict__ Cf, ushort_t* __restrict__ Chi,
    int N, int K, int relu, int Mv, const int* __restrict__ mf)
{
  const int mode = *mf;
  const int rawf32 = (a_kind==0) && (mode==1);
  __shared__ ushort_t Ah[256*32];
  __shared__ ushort_t Bt[128*32];
  const int tid = threadIdx.x;
  // ---- XCD-bijective chunked swizzle, n-fastest ----
  const int nbx = gridDim.x, nby = gridDim.y;
  const int total = nbx*nby;
  const int f = blockIdx.y*nbx + blockIdx.x;
  const int qq = total>>3, rr = total&7;
  const int xcd = f&7, pos = f>>3;
  const int wg = (xcd<rr ? xcd*(qq+1) : rr*(qq+1) + (xcd-rr)*qq) + pos;
  const int gm0 = (wg / nby)*256, gn0 = (wg % nby)*128;

  const int wv = tid>>6, lane = tid&63;
  const int mh = (wv&3)*64, nh = (wv>>2)*64;
  const int r16 = lane&15, q8 = (lane>>4)*8;
  const int grow = tid>>2, gcol = (tid&3)*8;    // 128 rows per issue
  const int srow = tid>>1, sseg = (tid&1)*16;   // rawf32: 256 rows, 16/thread
  const ushort_t* Abf = (const ushort_t*)A + a_off;
  v4f acc[4][4];
  #pragma unroll
  for (int i=0;i<4;i++)
    #pragma unroll
    for (int j=0;j<4;j++) acc[i][j] = (v4f){0.f,0.f,0.f,0.f};

  // clamped source rows (per-lane; constant across K-loop)
  int ar0 = gm0 + grow;        if (ar0 > Mv-1) ar0 = Mv-1;
  int ar1 = gm0 + 128 + grow;  if (ar1 > Mv-1) ar1 = Mv-1;
  int asr = gm0 + srow;        if (asr > Mv-1) asr = Mv-1;

  for (int k0=0; k0<K; k0+=32){
    if (k0) __syncthreads();
    gload_lds16(Wt + (size_t)(gn0+grow)*K + k0 + gcol, &Bt[grow*32 + gcol]);
    if (!rawf32){
      gload_lds16(Abf + (size_t)ar0*K + k0 + gcol, &Ah[grow*32 + gcol]);
      gload_lds16(Abf + (size_t)ar1*K + k0 + gcol, &Ah[(128+grow)*32 + gcol]);
    } else {
      const float* src = (const float*)A + a_off + (size_t)asr*K + k0 + sseg;
      #pragma unroll
      for (int v=0;v<4;v++){
        float4 fq = ((const float4*)src)[v];
        float xs[4] = {fq.x, fq.y, fq.z, fq.w};
        #pragma unroll
        for (int e=0;e<4;e++)
          Ah[srow*32 + sseg + v*4 + e] = f2bfbits(xs[e]);
      }
    }
    __syncthreads();
    v8s af[4], bfr[4];
    #pragma unroll
    for (int mt=0;mt<4;mt++)
      af[mt] = *(const v8s*)&Ah[(mh + mt*16 + r16)*32 + q8];
    #pragma unroll
    for (int nt=0;nt<4;nt++)
      bfr[nt] = *(const v8s*)&Bt[(nh + nt*16 + r16)*32 + q8];
    #pragma unroll
    for (int mt=0;mt<4;mt++){
      #pragma unroll
      for (int nt=0;nt<4;nt++)
        acc[mt][nt] = __builtin_amdgcn_mfma_f32_16x16x32_bf16(af[mt], bfr[nt], acc[mt][nt], 0, 0, 0);
    }
  }
  const int rq = (lane>>4)*4;
  float bv[4];
  #pragma unroll
  for (int nt=0;nt<4;nt++) bv[nt] = ldin(bias, gn0 + nh + nt*16 + r16, mode);
  const int outf = (Cf != nullptr);
  #pragma unroll
  for (int mt=0;mt<4;mt++){
    #pragma unroll
    for (int r=0;r<4;r++){
      const size_t ro = (size_t)(gm0 + mh + mt*16 + rq + r)*N + gn0 + nh + r16;
      #pragma unroll
      for (int nt=0;nt<4;nt++){
        float v = acc[mt][nt][r] + bv[nt];
        if (relu) v = fmaxf(v, 0.f);
        if (outf) Cf[ro + nt*16] = v;
        else      Chi[ro + nt*16] = f2bfbits(v);
      }
    }
  }
}

// ---------------------------------------------------------------------------
// KV split/transpose prep (unchanged)
// ---------------------------------------------------------------------------
__global__ __launch_bounds__(256) void k_kvsplit(
    const float* __restrict__ kws, const float* __restrict__ vws,
    ushort_t* __restrict__ khi, ushort_t* __restrict__ klo,
    ushort_t* __restrict__ vthi, ushort_t* __restrict__ vtlo)
{
  const int row = blockIdx.x;        // 0..255 = b*32 + key
  const int b = row >> 5, key = row & 31;
  const int t = threadIdx.x;         // dim 0..255
  const float f = kws[(size_t)row*256 + t];
  const ushort_t fh = f2bfbits(f);
  khi[(size_t)row*256 + t] = fh;
  klo[(size_t)row*256 + t] = f2bfbits(f - bf2f(fh));
  const float g = vws[(size_t)row*256 + t];
  const ushort_t gh = f2bfbits(g);
  const size_t vt = ((size_t)b*256 + t)*32 + key;
  vthi[vt] = gh;
  vtlo[vt] = f2bfbits(g - bf2f(gh));
}

// ---------------------------------------------------------------------------
// A2: MFMA MHA (unchanged from R6)
// ---------------------------------------------------------------------------
__global__ __launch_bounds__(256) void k_attn2(
    const ushort_t* __restrict__ qcH,
    ushort_t* __restrict__ aoh,
    const ushort_t* __restrict__ khi, const ushort_t* __restrict__ klo,
    const ushort_t* __restrict__ vthi, const ushort_t* __restrict__ vtlo,
    const char* __restrict__ tmask, int r0)
{
  __shared__ float P[4][16][36];
  const int tid = threadIdx.x;
  const int wv = tid>>6, lane = tid&63;
  const int lrow0 = blockIdx.x*64 + wv*16;
  const int b = (r0 + lrow0)/NVTOK;
  const int m16 = lane&15;
  const int kq = lane>>4;
  const int q8 = kq*8;
  const int key0 = m16, key1 = m16+16;
  const bool msk0 = tmask[b*LT + key0] != 0;
  const bool msk1 = tmask[b*LT + key1] != 0;
  const float scale = 0.17677669529663687f;

  for (int h=0; h<8; ++h){
    const size_t qoff = (size_t)(lrow0 + m16)*256 + h*32 + q8;
    const v8s qh = *(const v8s*)&qcH[qoff];
    const size_t kb0 = ((size_t)(b*32+key0)*256) + h*32 + q8;
    const size_t kb1 = ((size_t)(b*32+key1)*256) + h*32 + q8;
    const v8s kh0 = *(const v8s*)&khi[kb0];
    const v8s kl0 = *(const v8s*)&klo[kb0];
    const v8s kh1 = *(const v8s*)&khi[kb1];
    const v8s kl1 = *(const v8s*)&klo[kb1];
    v4f s0 = (v4f){0.f,0.f,0.f,0.f}, s1 = (v4f){0.f,0.f,0.f,0.f};
    s0 = __builtin_amdgcn_mfma_f32_16x16x32_bf16(qh, kh0, s0, 0,0,0);
    s0 = __builtin_amdgcn_mfma_f32_16x16x32_bf16(qh, kl0, s0, 0,0,0);
    s1 = __builtin_amdgcn_mfma_f32_16x16x32_bf16(qh, kh1, s1, 0,0,0);
    s1 = __builtin_amdgcn_mfma_f32_16x16x32_bf16(qh, kl1, s1, 0,0,0);
    float e0[4], e1[4], inv[4];
    #pragma unroll
    for (int r=0;r<4;r++){
      const float a0 = msk0 ? -1e9f : s0[r]*scale;
      const float a1 = msk1 ? -1e9f : s1[r]*scale;
      float mx = fmaxf(a0,a1);
      #pragma unroll
      for (int o=1;o<16;o<<=1) mx = fmaxf(mx, __shfl_xor(mx,o));
      const float x0 = __expf(a0-mx), x1 = __expf(a1-mx);
      float dn = x0+x1;
      #pragma unroll
      for (int o=1;o<16;o<<=1) dn += __shfl_xor(dn,o);
      e0[r]=x0; e1[r]=x1; inv[r] = 1.f/dn;
    }
    #pragma unroll
    for (int r=0;r<4;r++){
      P[wv][kq*4+r][key0] = e0[r];
      P[wv][kq*4+r][key1] = e1[r];
    }
    __syncthreads();
    float pv[8];
    *(float4*)&pv[0] = *(const float4*)&P[wv][m16][q8];
    *(float4*)&pv[4] = *(const float4*)&P[wv][m16][q8+4];
    v8s ph;
    #pragma unroll
    for (int j=0;j<8;j++) ph[j] = (short)f2bfbits(pv[j]);
    const size_t vb0 = ((size_t)(b*256 + h*32 + m16)*32) + q8;
    const size_t vb1 = ((size_t)(b*256 + h*32 + 16 + m16)*32) + q8;
    const v8s vh0 = *(const v8s*)&vthi[vb0];
    const v8s vl0 = *(const v8s*)&vtlo[vb0];
    const v8s vh1 = *(const v8s*)&vthi[vb1];
    const v8s vl1 = *(const v8s*)&vtlo[vb1];
    v4f o0 = (v4f){0.f,0.f,0.f,0.f}, o1 = (v4f){0.f,0.f,0.f,0.f};
    o0 = __builtin_amdgcn_mfma_f32_16x16x32_bf16(ph, vh0, o0, 0,0,0);
    o0 = __builtin_amdgcn_mfma_f32_16x16x32_bf16(ph, vl0, o0, 0,0,0);
    o1 = __builtin_amdgcn_mfma_f32_16x16x32_bf16(ph, vh1, o1, 0,0,0);
    o1 = __builtin_amdgcn_mfma_f32_16x16x32_bf16(ph, vl1, o1, 0,0,0);
    __syncthreads();
    #pragma unroll
    for (int r=0;r<4;r++){
      const size_t ro = (size_t)(lrow0 + kq*4 + r)*256 + h*32;
      aoh[ro + m16]      = f2bfbits(o0[r]*inv[r]);
      aoh[ro + 16 + m16] = f2bfbits(o1[r]*inv[r]);
    }
  }
}

// ---------------------------------------------------------------------------
// residual + two-pass LayerNorm (text side, unchanged)
// ---------------------------------------------------------------------------
__global__ __launch_bounds__(256) void k_add_ln(
    const float* __restrict__ X, const void* R, size_t r_off, int r_f32,
    void* OUT, size_t o_off, int o_f32,
    void* OUT2, size_t o2_off,
    const void* g, const void* be, const int* __restrict__ mf)
{
  const int mode = *mf;
  const int row = blockIdx.x; const int t = threadIdx.x;
  const size_t idx = (size_t)row*256 + t;
  __shared__ float red[4];
  const float rv = r_f32 ? ((const float*)R)[r_off+idx] : ldin(R, r_off+idx, mode);
  const float v = X[idx] + rv;
  const float m = block_sum(v, red) * (1.f/256.f);
  __syncthreads();
  const float d = v - m;
  const float var = block_sum(d*d, red) * (1.f/256.f);
  const float o = d*rsqrtf(var+1e-5f)*ldin(g,t,mode) + ldin(be,t,mode);
  if (o_f32) ((float*)OUT)[o_off+idx] = o;
  else       stout(OUT, o_off+idx, mode, o);
  if (OUT2)  stout(OUT2, o2_off+idx, mode, o);
}

// ---------------------------------------------------------------------------
// LN1 (vis): v = X + residual(mode-typed) ; out = bf16 hi
// ---------------------------------------------------------------------------
__global__ __launch_bounds__(256) void k_add_ln_h(
    const float* __restrict__ X, const void* R, size_t r_off,
    ushort_t* __restrict__ OH,
    const void* g, const void* be, const int* __restrict__ mf)
{
  const int mode = *mf;
  const int row = blockIdx.x; const int t = threadIdx.x;
  const size_t idx = (size_t)row*256 + t;
  __shared__ float red[4];
  const float rv = ldin(R, r_off+idx, mode);
  const float v = X[idx] + rv;
  const float m = block_sum(v, red) * (1.f/256.f);
  __syncthreads();
  const float d = v - m;
  const float var = block_sum(d*d, red) * (1.f/256.f);
  const float o = d*rsqrtf(var+1e-5f)*ldin(g,t,mode) + ldin(be,t,mode);
  OH[idx] = f2bfbits(o);
}

// ---------------------------------------------------------------------------
// LN2 (vis): v = X + RH ; out = mode-typed at offset
// ---------------------------------------------------------------------------
__global__ __launch_bounds__(256) void k_add_ln_pres(
    const float* __restrict__ X,
    const ushort_t* __restrict__ RH,
    void* OUT, size_t o_off,
    const void* g, const void* be, const int* __restrict__ mf)
{
  const int mode = *mf;
  const int row = blockIdx.x; const int t = threadIdx.x;
  const size_t idx = (size_t)row*256 + t;
  __shared__ float red[4];
  const float rv = bf2f(RH[idx]);
  const float v = X[idx] + rv;
  const float m = block_sum(v, red) * (1.f/256.f);
  __syncthreads();
  const float d = v - m;
  const float var = block_sum(d*d, red) * (1.f/256.f);
  const float o = d*rsqrtf(var+1e-5f)*ldin(g,t,mode) + ldin(be,t,mode);
  stout(OUT, o_off+idx, mode, o);
}

// ---------------------------------------------------------------------------
extern "C" void kernel_launch(void* const* d_in, const int* in_sizes, int n_in,
                              void* d_out, int out_size, void* d_ws, size_t ws_size,
                              hipStream_t stream)
{
  (void)n_in; (void)out_size;
  const void* vis_tokens = d_in[0];
  const void* text_tokens= d_in[1];
  const void* vis_value  = d_in[2];
  const void* ref_w = d_in[3];  const void* ref_b = d_in[4];
  const void* off_w = d_in[5];  const void* off_b = d_in[6];
  const void* aw_w  = d_in[7];  const void* aw_b  = d_in[8];
  const void* vproj_w = d_in[9];  const void* vproj_b = d_in[10];
  const void* oproj_w = d_in[11]; const void* oproj_b = d_in[12];
  const void* lvi_out_w = d_in[13]; const void* lvi_out_b = d_in[14];
  const void* lvi_n1_s = d_in[15];  const void* lvi_n1_b = d_in[16];
  const void* lvi_f1_w = d_in[17];  const void* lvi_f1_b = d_in[18];
  const void* lvi_f2_w = d_in[19];  const void* lvi_f2_b = d_in[20];
  const void* lvi_n2_s = d_in[21];  const void* lvi_n2_b = d_in[22];
  const void* mha_qw = d_in[23]; const void* mha_qb = d_in[24];
  const void* mha_kw = d_in[25]; const void* mha_kb = d_in[26];
  const void* mha_vw = d_in[27]; const void* mha_vb = d_in[28];
  const void* mha_ow = d_in[29]; const void* mha_ob = d_in[30];
  const void* vli_out_w = d_in[31]; const void* vli_out_b = d_in[32];
  const void* vli_n1_s = d_in[33];  const void* vli_n1_b = d_in[34];
  const void* vli_f1_w = d_in[35];  const void* vli_f1_b = d_in[36];
  const void* vli_f2_w = d_in[37];  const void* vli_f2_b = d_in[38];
  const void* vli_n2_s = d_in[39];  const void* vli_n2_b = d_in[40];
  const char* tmask = (const char*)d_in[43];
  const char* vmask = (const char*)d_in[44];

  // ---- workspace layout ----
  char* ws = (char*)d_ws;
  int*   flag    = (int*)  (ws + 0);               // 256 B
  float* loc_ws  = (float*)(ws + 256);             // 196608
  float* aw_ws   = (float*)(ws + 196864);          //  98304
  float* ctxt_ws = (float*)(ws + 295168);          // 262144
  float* t_ws    = (float*)(ws + 557312);          // 262144
  float* tout_ws = (float*)(ws + 819456);          // 262144
  float* k_ws    = (float*)(ws + 1081600);         // 262144
  float* v_ws    = (float*)(ws + 1343744);         // 262144
  ushort_t* wtq  = (ushort_t*)(ws + 1605888ull);   // 131072 B
  ushort_t* wto  = (ushort_t*)(ws + 1736960ull);   // 131072 B
  ushort_t* wtf1 = (ushort_t*)(ws + 1868032ull);   // 524288 B
  ushort_t* wtf2 = (ushort_t*)(ws + 2392320ull);   // 524288 B
  ushort_t* wtk   = (ushort_t*)(ws + 2916608ull);  // 131072 B (mha_kw^T)
  ushort_t* wtv   = (ushort_t*)(ws + 3047680ull);  // 131072 B (mha_vw^T)
  ushort_t* wtop  = (ushort_t*)(ws + 3178752ull);  // 131072 B (oproj_w^T)
  ushort_t* wtlo  = (ushort_t*)(ws + 3309824ull);  // 131072 B (lvi_out_w^T)
  ushort_t* wtlf1 = (ushort_t*)(ws + 3440896ull);  // 524288 B (lvi_f1_w^T)
  ushort_t* wtlf2 = (ushort_t*)(ws + 3965184ull);  // 524288 B (lvi_f2_w^T)
  float* hbuf_t   = (float*)(ws + 4489472ull);     // 1048576 B (256x1024)
  float* ybuf     = (float*)(ws + 5538048ull);     // 262144 B
  float* fbuf     = (float*)(ws + 5800192ull);     // 262144 B
  ushort_t* khi   = (ushort_t*)(ws + 6062336ull);  // 131072 B
  ushort_t* klo   = (ushort_t*)(ws + 6193408ull);  // 131072 B
  ushort_t* vthi  = (ushort_t*)(ws + 6324480ull);  // 131072 B
  ushort_t* vtlo  = (ushort_t*)(ws + 6455552ull);  // 131072 B
  const size_t fe = 6586624ull;                    // chunk region start

  // per-row chunk bytes (3584 B/row), R multiple of 256 (tile height):
  //   region0 (1024 B): ubuf fp32; first 512 B alias qc bf16 (dead after attn2)
  //   region1 ( 512 B): v1 bf16
  //   region2 (2048 B): hb bf16; first 512 B alias ao bf16 (dead pre-f1)
  long long R_ll = 256;
  if (ws_size > fe) R_ll = (long long)((ws_size - fe) / 3584ull);
  if (R_ll > (long long)MVIS) R_ll = MVIS;
  R_ll &= ~255LL;
  if (R_ll < 256) R_ll = 256;
  const int R = (int)R_ll;
  ushort_t* qcH  = (ushort_t*)(ws + fe);                      // region0 alias
  float*    ubuf = (float*)   (ws + fe);                      // region0
  ushort_t* v1H  = (ushort_t*)(ws + fe + (size_t)R*1024ull);  // region1
  ushort_t* hbH  = (ushort_t*)(ws + fe + (size_t)R*1536ull);  // region2
  ushort_t* aoH  = hbH;                                       // alias (dead pre-f1)

  // ---- dtype detect ----
  int ndw = in_sizes[1]/2; if (ndw < 1) ndw = 1;
  k_detect<<<1,256,0,stream>>>((const uint_t*)text_tokens, ndw, flag);

  // ---- weight transposes for MFMA GEMMs ----
  k_transpose<<<dim3(8,8),  256,0,stream>>>(mha_qw,    wtq,   256, 256,  flag);
  k_transpose<<<dim3(8,8),  256,0,stream>>>(mha_ow,    wto,   256, 256,  flag);
  k_transpose<<<dim3(8,32), 256,0,stream>>>(vli_f1_w,  wtf1,  256, 1024, flag);
  k_transpose<<<dim3(32,8), 256,0,stream>>>(vli_f2_w,  wtf2,  1024, 256, flag);
  k_transpose<<<dim3(8,8),  256,0,stream>>>(mha_kw,    wtk,   256, 256,  flag);
  k_transpose<<<dim3(8,8),  256,0,stream>>>(mha_vw,    wtv,   256, 256,  flag);
  k_transpose<<<dim3(8,8),  256,0,stream>>>(oproj_w,   wtop,  256, 256,  flag);
  k_transpose<<<dim3(8,8),  256,0,stream>>>(lvi_out_w, wtlo,  256, 256,  flag);
  k_transpose<<<dim3(8,32), 256,0,stream>>>(lvi_f1_w,  wtlf1, 256, 1024, flag);
  k_transpose<<<dim3(32,8), 256,0,stream>>>(lvi_f2_w,  wtlf2, 1024, 256, flag);

  // ---- text side ----
  k_text_prep<<<MTEXT,256,0,stream>>>(text_tokens, ref_w, ref_b, off_w, off_b,
                                      aw_w, aw_b, loc_ws, aw_ws, flag);
  k_deform<<<MTEXT*NHEAD,64,0,stream>>>(vis_value, vmask, vproj_w, vproj_b,
                                        loc_ws, aw_ws, ctxt_ws, flag);

  // attn-out path: y = ctx@oproj + b ; z = y@lvi_out + b ; t = LN(text + z)
  {
    dim3 g22(2,2);
    k_mgemm<<<g22,256,0,stream>>>(ctxt_ws, 0, 1, wtop, oproj_b, ybuf, 256, 256, 0, flag);
    k_mgemm<<<g22,256,0,stream>>>(ybuf,    0, 1, wtlo, lvi_out_b, fbuf, 256, 256, 0, flag);
    k_add_ln<<<MTEXT,256,0,stream>>>(fbuf, text_tokens, 0, 0,
                                     t_ws, 0, 1, nullptr, 0, lvi_n1_s, lvi_n1_b, flag);
  }
  // ffn path: h = relu(t@f1+b1) ; f = h@f2+b2 ; tout = LN(t + f)
  {
    dim3 g28(2,8), g22(2,2);
    k_mgemm<<<g28,256,0,stream>>>(t_ws,   0, 1, wtlf1, lvi_f1_b, hbuf_t, 1024, 256, 1, flag);
    k_mgemm<<<g22,256,0,stream>>>(hbuf_t, 0, 1, wtlf2, lvi_f2_b, fbuf,   256, 1024, 0, flag);
    k_add_ln<<<MTEXT,256,0,stream>>>(fbuf, t_ws, 0, 1,
                                     tout_ws, 0, 1, d_out, VISSZ, lvi_n2_s, lvi_n2_b, flag);
  }
  // k/v projection of text_out + bf16 hi/lo split (+ V transpose)
  {
    dim3 g22(2,2);
    k_mgemm<<<g22,256,0,stream>>>(tout_ws, 0, 1, wtk, mha_kb, k_ws, 256, 256, 0, flag);
    k_mgemm<<<g22,256,0,stream>>>(tout_ws, 0, 1, wtv, mha_vb, v_ws, 256, 256, 0, flag);
    k_kvsplit<<<256,256,0,stream>>>(k_ws, v_ws, khi, klo, vthi, vtlo);
  }

  // ---- vis side, chunked by R rows ----
  for (int r0 = 0; r0 < MVIS; r0 += R){
    const int nr = (MVIS - r0 < R) ? (MVIS - r0) : R;   // multiple of 128
    const int gx = (nr + 255) / 256;
    dim3 g2(gx, 2), g8(gx, 8);
    k_mgemm4<<<g2,512,0,stream>>>(vis_tokens, (size_t)r0*256, 0,
                                  wtq, mha_qb, nullptr, qcH, 256, 256, 0, nr, flag);
    k_attn2<<<nr/64,256,0,stream>>>(qcH, aoH, khi, klo, vthi, vtlo, tmask, r0);
    k_mgemm4<<<g2,512,0,stream>>>(aoH, 0, 2,
                                  wto, mha_ob, ubuf, nullptr, 256, 256, 0, nr, flag);
    k_add_ln_h<<<nr,256,0,stream>>>(ubuf, vis_tokens, (size_t)r0*256,
                                    v1H, vli_n1_s, vli_n1_b, flag);
    k_mgemm4<<<g8,512,0,stream>>>(v1H, 0, 2,
                                  wtf1, vli_f1_b, nullptr, hbH, 1024, 256, 1, nr, flag);
    k_mgemm4<<<g2,512,0,stream>>>(hbH, 0, 2,
                                  wtf2, vli_f2_b, ubuf, nullptr, 256, 1024, 0, nr, flag);
    k_add_ln_pres<<<nr,256,0,stream>>>(ubuf, v1H,
                                       d_out, (size_t)r0*256, vli_n2_s, vli_n2_b, flag);
  }
}

// Round 9
// 903.273 us; speedup vs baseline: 1.2572x; 1.0897x over previous
//
#include <hip/hip_runtime.h>
#include <hip/hip_bf16.h>
#include <math.h>

typedef __hip_bfloat16 bf16;
typedef unsigned short ushort_t;
typedef unsigned int uint_t;
typedef short v8s __attribute__((ext_vector_type(8)));
typedef float v4f __attribute__((ext_vector_type(4)));

#define NVTOK 9072
#define BATCH 8
#define LT 32
#define DMODEL 256
#define NHEAD 8
#define DHEAD 32
#define MVIS (BATCH*NVTOK)   /* 72576 */
#define MTEXT (BATCH*LT)     /* 256 */
#define VISSZ 18579456ull    /* MVIS*256 elements */

__device__ __forceinline__ float bf2f(ushort_t u){ return __uint_as_float(((uint_t)u)<<16); }
__device__ __forceinline__ ushort_t f2bfbits(float f){
  __hip_bfloat16 h = __float2bfloat16(f);
  union { __hip_bfloat16 h; ushort_t u; } c; c.h = h; return c.u;
}
// mode: 0 = buffers hold bf16, 1 = buffers hold fp32
__device__ __forceinline__ float ldin(const void* p, size_t i, int mode){
  return mode ? ((const float*)p)[i] : bf2f(((const ushort_t*)p)[i]);
}
__device__ __forceinline__ void stout(void* p, size_t i, int mode, float v){
  if (mode) ((float*)p)[i] = v; else ((ushort_t*)p)[i] = f2bfbits(v);
}

// async global->LDS, 16 B per lane (LDS dest = wave-uniform base + lane*16).
__device__ __forceinline__ void gload_lds16(const void* g, void* l){
  __builtin_amdgcn_global_load_lds(
      (const __attribute__((address_space(1))) unsigned int*)g,
      (__attribute__((address_space(3))) unsigned int*)l, 16, 0, 0);
}

// ---------------------------------------------------------------------------
// D0: dtype detector (unchanged)
// ---------------------------------------------------------------------------
__global__ void k_detect(const uint_t* __restrict__ buf, int n_avail, int* __restrict__ flag){
  __shared__ int zc, bc;
  if (threadIdx.x==0){ zc=0; bc=0; }
  __syncthreads();
  int stride = n_avail/2048; if (stride < 1) stride = 1;
  int nz=0, nb=0;
  for (int i=threadIdx.x; i<2048; i+=256){
    long long idx = (long long)i*stride;
    if (idx >= n_avail) break;
    uint_t d = buf[idx];
    uint_t lo = d & 0xFFFFu;
    int e = (int)((lo >> 7) & 0xFF);
    if (lo == 0) nz++;
    else if (e >= 90 && e <= 160) nb++;
  }
  atomicAdd(&zc, nz); atomicAdd(&bc, nb);
  __syncthreads();
  if (threadIdx.x==0){
    int mode;
    if (zc > 1024) mode = 1;
    else if (bc > 1228) mode = 0;
    else mode = 1;
    *flag = mode;
  }
}

// ---------------------------------------------------------------------------
// W-transpose (unchanged)
// ---------------------------------------------------------------------------
__global__ __launch_bounds__(256) void k_transpose(
    const void* W, ushort_t* __restrict__ Wt, int K, int N,
    const int* __restrict__ mf)
{
  const int mode = *mf;
  __shared__ float tile[32][33];
  const int k0 = blockIdx.x*32, n0 = blockIdx.y*32;
  const int c = threadIdx.x & 31, r8 = threadIdx.x >> 5;
  #pragma unroll
  for (int i=0;i<4;i++){
    const int kk = r8 + i*8;
    tile[kk][c] = ldin(W, (size_t)(k0+kk)*N + n0 + c, mode);
  }
  __syncthreads();
  #pragma unroll
  for (int i=0;i<4;i++){
    const int nn = r8 + i*8;
    Wt[(size_t)(n0+nn)*K + k0 + c] = f2bfbits(tile[c][nn]);
  }
}

// ---------------------------------------------------------------------------
// T1: text prep (unchanged)
// ---------------------------------------------------------------------------
__global__ __launch_bounds__(256) void k_text_prep(
    const void* text,
    const void* ref_w, const void* ref_b,
    const void* off_w, const void* off_b,
    const void* aw_w,  const void* aw_b,
    float* __restrict__ loc_out, float* __restrict__ aw_out,
    const int* __restrict__ mf)
{
  const int mode = *mf;
  const int r = blockIdx.x;
  const int t = threadIdx.x;
  __shared__ float x[256];
  __shared__ float refv[6];
  __shared__ float offv[192];
  __shared__ float logit[96];
  x[t] = ldin(text, (size_t)r*256 + t, mode);
  __syncthreads();
  if (t < 192) {
    float s = 0.f;
    for (int k=0;k<256;k++) s += x[k]*ldin(off_w, (size_t)k*192+t, mode);
    offv[t] = s + ldin(off_b, t, mode);
  } else if (t < 198) {
    int j = t-192;
    float s = 0.f;
    for (int k=0;k<256;k++) s += x[k]*ldin(ref_w, (size_t)k*6+j, mode);
    s += ldin(ref_b, j, mode);
    refv[j] = 1.f/(1.f+expf(-s));
  }
  if (t < 96) {
    float s = 0.f;
    for (int k=0;k<256;k++) s += x[k]*ldin(aw_w, (size_t)k*96+t, mode);
    logit[t] = s + ldin(aw_b, t, mode);
  }
  __syncthreads();
  if (t < 8) {
    float mx = -1e30f;
    for (int j=0;j<12;j++) mx = fmaxf(mx, logit[t*12+j]);
    float e[12]; float den = 0.f;
    for (int j=0;j<12;j++){ e[j] = expf(logit[t*12+j]-mx); den += e[j]; }
    float inv = 1.f/den;
    for (int j=0;j<12;j++) aw_out[(size_t)r*96 + t*12 + j] = e[j]*inv;
  }
  if (t < 192) {
    int rem = t % 24;
    int l = rem >> 3;
    int c = t & 1;
    const float normW[3] = {96.f,48.f,24.f};
    const float normH[3] = {72.f,36.f,18.f};
    float nrm = (c==0) ? normW[l] : normH[l];
    loc_out[(size_t)r*192 + t] = refv[l*2+c] + offv[t]/nrm;
  }
}

// ---------------------------------------------------------------------------
// T2: deformable sampling, lazy vproj (unchanged)
// ---------------------------------------------------------------------------
__global__ __launch_bounds__(64) void k_deform(
    const void* vis_value, const char* __restrict__ vmask,
    const void* vproj_w, const void* vproj_b,
    const float* __restrict__ loc, const float* __restrict__ aw,
    float* __restrict__ ctx_out, const int* __restrict__ mf)
{
  const int mode = *mf;
  const int blk = blockIdx.x;      // r*8 + h
  const int r = blk >> 3;
  const int h = blk & 7;
  const int b = r >> 5;
  const int t = threadIdx.x;
  const int Hs[3] = {72,36,18};
  const int Wsz[3] = {96,48,24};
  const int stl[3] = {0,6912,8640};
  float s0=0.f,s1=0.f,s2=0.f,s3=0.f, wsum=0.f;
  for (int l=0;l<3;l++){
    for (int p=0;p<4;p++){
      const int sIdx = blk*12 + l*4 + p;
      const float a  = aw[sIdx];
      const float X = loc[sIdx*2+0]*(float)Wsz[l] - 0.5f;
      const float Y = loc[sIdx*2+1]*(float)Hs[l] - 0.5f;
      const float x0f = floorf(X), y0f = floorf(Y);
      const int x0 = (int)x0f, y0 = (int)y0f;
      const float wx = X-x0f, wy = Y-y0f;
      const float cw[4] = {(1.f-wx)*(1.f-wy), wx*(1.f-wy), (1.f-wx)*wy, wx*wy};
      const int cx[4] = {x0,x0+1,x0,x0+1};
      const int cy[4] = {y0,y0,y0+1,y0+1};
      for (int c=0;c<4;c++){
        if (cx[c]>=0 && cx[c]<Wsz[l] && cy[c]>=0 && cy[c]<Hs[l]){
          const size_t pos = (size_t)b*NVTOK + stl[l] + cy[c]*Wsz[l] + cx[c];
          if (vmask[pos]) continue;
          const float w = a*cw[c];
          wsum += w;
          const size_t base = pos*256 + t*4;
          s0 += w*ldin(vis_value, base+0, mode);
          s1 += w*ldin(vis_value, base+1, mode);
          s2 += w*ldin(vis_value, base+2, mode);
          s3 += w*ldin(vis_value, base+3, mode);
        }
      }
    }
  }
  __shared__ float sh[256];
  sh[t*4+0]=s0; sh[t*4+1]=s1; sh[t*4+2]=s2; sh[t*4+3]=s3;
  __syncthreads();
  if (t < 32) {
    const int col = h*32 + t;
    float acc = wsum * ldin(vproj_b, col, mode);
    for (int k=0;k<256;k++) acc += sh[k]*ldin(vproj_w, (size_t)k*256+col, mode);
    ctx_out[(size_t)r*256 + col] = acc;
  }
}

__device__ __forceinline__ float block_sum(float v, float* red){
  float sm = v;
  #pragma unroll
  for (int o=32;o>0;o>>=1) sm += __shfl_down(sm,o);
  const int t = threadIdx.x;
  __syncthreads();
  if ((t&63)==0) red[t>>6] = sm;
  __syncthreads();
  return red[0]+red[1]+red[2]+red[3];
}

// ---------------------------------------------------------------------------
// MFMA GEMM (text side, unchanged — tiny M, full hi/lo precision)
// ---------------------------------------------------------------------------
__global__ __launch_bounds__(256) void k_mgemm(
    const void* A, size_t a_off, int a_kind,
    const ushort_t* __restrict__ Wt, const void* bias, float* __restrict__ C,
    int N, int K, int relu, const int* __restrict__ mf)
{
  const int mode = *mf;
  const int split = (a_kind==1) || (mode==1);
  __shared__ ushort_t Ah[128*32];
  __shared__ ushort_t Al[128*32];
  __shared__ ushort_t Bt[128*32];
  const int tid = threadIdx.x;
  const int gm0 = blockIdx.x*128, gn0 = blockIdx.y*128;
  const int wv = tid>>6, lane = tid&63;
  const int mh = (wv&1)*64, nh = (wv>>1)*64;
  const int r16 = lane&15, q8 = (lane>>4)*8;
  const int srow = tid>>1, sseg = (tid&1)*16;
  v4f acc[4][4];
  #pragma unroll
  for (int i=0;i<4;i++)
    #pragma unroll
    for (int j=0;j<4;j++) acc[i][j] = (v4f){0.f,0.f,0.f,0.f};

  for (int k0=0; k0<K; k0+=32){
    if (k0) __syncthreads();
    {
      const ushort_t* src = Wt + (size_t)(gn0+srow)*K + k0 + sseg;
      ((uint4*)&Bt[srow*32+sseg])[0]   = ((const uint4*)src)[0];
      ((uint4*)&Bt[srow*32+sseg+8])[0] = ((const uint4*)src)[1];
    }
    if (!split){
      const ushort_t* src = (const ushort_t*)A + a_off + (size_t)(gm0+srow)*K + k0 + sseg;
      ((uint4*)&Ah[srow*32+sseg])[0]   = ((const uint4*)src)[0];
      ((uint4*)&Ah[srow*32+sseg+8])[0] = ((const uint4*)src)[1];
    } else {
      const float* src = (const float*)A + a_off + (size_t)(gm0+srow)*K + k0 + sseg;
      #pragma unroll
      for (int v=0;v<4;v++){
        float4 f = ((const float4*)src)[v];
        float xs[4] = {f.x, f.y, f.z, f.w};
        #pragma unroll
        for (int e=0;e<4;e++){
          const int idx = srow*32 + sseg + v*4 + e;
          const ushort_t h = f2bfbits(xs[e]);
          Ah[idx] = h;
          Al[idx] = f2bfbits(xs[e] - bf2f(h));
        }
      }
    }
    __syncthreads();
    v8s af[4], bfr[4], al[4];
    #pragma unroll
    for (int mt=0;mt<4;mt++){
      af[mt] = *(const v8s*)&Ah[(mh + mt*16 + r16)*32 + q8];
      if (split) al[mt] = *(const v8s*)&Al[(mh + mt*16 + r16)*32 + q8];
    }
    #pragma unroll
    for (int nt=0;nt<4;nt++)
      bfr[nt] = *(const v8s*)&Bt[(nh + nt*16 + r16)*32 + q8];
    #pragma unroll
    for (int mt=0;mt<4;mt++){
      #pragma unroll
      for (int nt=0;nt<4;nt++){
        acc[mt][nt] = __builtin_amdgcn_mfma_f32_16x16x32_bf16(af[mt], bfr[nt], acc[mt][nt], 0, 0, 0);
        if (split)
          acc[mt][nt] = __builtin_amdgcn_mfma_f32_16x16x32_bf16(al[mt], bfr[nt], acc[mt][nt], 0, 0, 0);
      }
    }
  }
  const int rq = (lane>>4)*4;
  float bv[4];
  #pragma unroll
  for (int nt=0;nt<4;nt++) bv[nt] = ldin(bias, gn0 + nh + nt*16 + r16, mode);
  #pragma unroll
  for (int mt=0;mt<4;mt++){
    #pragma unroll
    for (int r=0;r<4;r++){
      const size_t ro = (size_t)(gm0 + mh + mt*16 + rq + r)*N + gn0 + nh + r16;
      #pragma unroll
      for (int nt=0;nt<4;nt++){
        float v = acc[mt][nt][r] + bv[nt];
        if (relu) v = fmaxf(v, 0.f);
        C[ro + nt*16] = v;
      }
    }
  }
}

// ---------------------------------------------------------------------------
// V3 MFMA GEMM (vis q-proj / f1): 128x128 tile, single-pass bf16
// activations, gload_lds16 staging, XCD-bijective swizzle (R5 structure —
// best measured). Output fp32 or bf16.
// ---------------------------------------------------------------------------
__global__ __launch_bounds__(256) void k_mgemm3(
    const void* A, size_t a_off, int a_kind,
    const ushort_t* __restrict__ Wt, const void* bias,
    float* __restrict__ Cf, ushort_t* __restrict__ Chi,
    int N, int K, int relu, const int* __restrict__ mf)
{
  const int mode = *mf;
  const int rawf32 = (a_kind==0) && (mode==1);
  __shared__ ushort_t Ah[128*32];
  __shared__ ushort_t Bt[128*32];
  const int tid = threadIdx.x;
  const int nbx = gridDim.x, nby = gridDim.y;
  const int total = nbx*nby;
  const int f = blockIdx.y*nbx + blockIdx.x;
  const int qq = total>>3, rr = total&7;
  const int xcd = f&7, pos = f>>3;
  const int wg = (xcd<rr ? xcd*(qq+1) : rr*(qq+1) + (xcd-rr)*qq) + pos;
  const int gm0 = (wg / nby)*128, gn0 = (wg % nby)*128;

  const int wv = tid>>6, lane = tid&63;
  const int mh = (wv&1)*64, nh = (wv>>1)*64;
  const int r16 = lane&15, q8 = (lane>>4)*8;
  const int grow = tid>>2;
  const int gcol = (tid&3)*8;
  const int srow = tid>>1, sseg = (tid&1)*16;
  const ushort_t* Abf = (const ushort_t*)A + a_off;
  v4f acc[4][4];
  #pragma unroll
  for (int i=0;i<4;i++)
    #pragma unroll
    for (int j=0;j<4;j++) acc[i][j] = (v4f){0.f,0.f,0.f,0.f};

  for (int k0=0; k0<K; k0+=32){
    if (k0) __syncthreads();
    gload_lds16(Wt + (size_t)(gn0+grow)*K    + k0 + gcol, &Bt[grow*32      + gcol]);
    gload_lds16(Wt + (size_t)(gn0+grow+64)*K + k0 + gcol, &Bt[(grow+64)*32 + gcol]);
    if (!rawf32){
      gload_lds16(Abf + (size_t)(gm0+grow)*K    + k0 + gcol, &Ah[grow*32      + gcol]);
      gload_lds16(Abf + (size_t)(gm0+grow+64)*K + k0 + gcol, &Ah[(grow+64)*32 + gcol]);
    } else {
      const float* src = (const float*)A + a_off + (size_t)(gm0+srow)*K + k0 + sseg;
      #pragma unroll
      for (int v=0;v<4;v++){
        float4 fq = ((const float4*)src)[v];
        float xs[4] = {fq.x, fq.y, fq.z, fq.w};
        #pragma unroll
        for (int e=0;e<4;e++)
          Ah[srow*32 + sseg + v*4 + e] = f2bfbits(xs[e]);
      }
    }
    __syncthreads();
    v8s af[4], bfr[4];
    #pragma unroll
    for (int mt=0;mt<4;mt++)
      af[mt] = *(const v8s*)&Ah[(mh + mt*16 + r16)*32 + q8];
    #pragma unroll
    for (int nt=0;nt<4;nt++)
      bfr[nt] = *(const v8s*)&Bt[(nh + nt*16 + r16)*32 + q8];
    #pragma unroll
    for (int mt=0;mt<4;mt++){
      #pragma unroll
      for (int nt=0;nt<4;nt++)
        acc[mt][nt] = __builtin_amdgcn_mfma_f32_16x16x32_bf16(af[mt], bfr[nt], acc[mt][nt], 0, 0, 0);
    }
  }
  const int rq = (lane>>4)*4;
  float bv[4];
  #pragma unroll
  for (int nt=0;nt<4;nt++) bv[nt] = ldin(bias, gn0 + nh + nt*16 + r16, mode);
  const int outf = (Cf != nullptr);
  #pragma unroll
  for (int mt=0;mt<4;mt++){
    #pragma unroll
    for (int r=0;r<4;r++){
      const size_t ro = (size_t)(gm0 + mh + mt*16 + rq + r)*N + gn0 + nh + r16;
      #pragma unroll
      for (int nt=0;nt<4;nt++){
        float v = acc[mt][nt][r] + bv[nt];
        if (relu) v = fmaxf(v, 0.f);
        if (outf) Cf[ro + nt*16] = v;
        else      Chi[ro + nt*16] = f2bfbits(v);
      }
    }
  }
}

// ---------------------------------------------------------------------------
// GEMM + residual + LayerNorm fused (vis o-proj+LN1, f2+LN2). N fixed = 256,
// tile 128 rows x 256 cols, 512 thr = 8 waves (2m x 4n) -> each block owns
// COMPLETE rows, so LN runs in the epilogue. Two-pass mean/var (matches the
// old k_add_ln rounding): 16-lane shfl_xor partials + cross-wave LDS.
// A bf16 [M][K] via gload_lds16; B = Wt [256][K] bf16 (2 issues).
// Residual: mode-typed (res_bf16=0, with res_off) or bf16 ws (res_bf16=1).
// Output: bf16 ws (out_bf16=1) or mode-typed d_out (out_bf16=0, out_off).
// Eliminates ubuf + 2 standalone LN kernels per chunk.
// ---------------------------------------------------------------------------
__global__ __launch_bounds__(512) void k_mgemm_ln(
    const ushort_t* __restrict__ A,
    const ushort_t* __restrict__ Wt, const void* bias,
    const void* RES, size_t res_off, int res_bf16,
    void* OUT, size_t out_off, int out_bf16,
    const void* g, const void* be,
    int K, const int* __restrict__ mf)
{
  const int mode = *mf;
  __shared__ ushort_t Ah[128*32];
  __shared__ ushort_t Bt[256*32];
  __shared__ float rsum[4][128];
  __shared__ float rsq[4][128];
  const int tid = threadIdx.x;
  const int gm0 = blockIdx.x*128;
  const int wv = tid>>6, lane = tid&63;
  const int wm = wv&1, wn = wv>>1;
  const int mh = wm*64, nh = wn*64;
  const int r16 = lane&15, kq = lane>>4, q8 = kq*8;
  const int grow = tid>>2, gcol = (tid&3)*8;    // 128 rows per issue
  v4f acc[4][4];
  #pragma unroll
  for (int i=0;i<4;i++)
    #pragma unroll
    for (int j=0;j<4;j++) acc[i][j] = (v4f){0.f,0.f,0.f,0.f};

  for (int k0=0; k0<K; k0+=32){
    if (k0) __syncthreads();
    gload_lds16(A  + (size_t)(gm0+grow)*K + k0 + gcol, &Ah[grow*32 + gcol]);
    gload_lds16(Wt + (size_t)grow*K       + k0 + gcol, &Bt[grow*32 + gcol]);
    gload_lds16(Wt + (size_t)(128+grow)*K + k0 + gcol, &Bt[(128+grow)*32 + gcol]);
    __syncthreads();
    v8s af[4], bfr[4];
    #pragma unroll
    for (int mt=0;mt<4;mt++)
      af[mt] = *(const v8s*)&Ah[(mh + mt*16 + r16)*32 + q8];
    #pragma unroll
    for (int nt=0;nt<4;nt++)
      bfr[nt] = *(const v8s*)&Bt[(nh + nt*16 + r16)*32 + q8];
    #pragma unroll
    for (int mt=0;mt<4;mt++){
      #pragma unroll
      for (int nt=0;nt<4;nt++)
        acc[mt][nt] = __builtin_amdgcn_mfma_f32_16x16x32_bf16(af[mt], bfr[nt], acc[mt][nt], 0, 0, 0);
    }
  }
  // ---- z = acc + bias + residual (in place) ----
  float bv[4];
  #pragma unroll
  for (int nt=0;nt<4;nt++) bv[nt] = ldin(bias, nh + nt*16 + r16, mode);
  #pragma unroll
  for (int mt=0;mt<4;mt++){
    #pragma unroll
    for (int r=0;r<4;r++){
      const int row_l = mh + mt*16 + kq*4 + r;
      const size_t rbase = (size_t)(gm0 + row_l)*256;
      #pragma unroll
      for (int nt=0;nt<4;nt++){
        const int col = nh + nt*16 + r16;
        const float rv = res_bf16 ? bf2f(((const ushort_t*)RES)[res_off + rbase + col])
                                  : ldin(RES, res_off + rbase + col, mode);
        acc[mt][nt][r] = acc[mt][nt][r] + bv[nt] + rv;
      }
    }
  }
  // ---- pass 1: row sums -> mean ----
  #pragma unroll
  for (int mt=0;mt<4;mt++){
    #pragma unroll
    for (int r=0;r<4;r++){
      float s = acc[mt][0][r] + acc[mt][1][r] + acc[mt][2][r] + acc[mt][3][r];
      #pragma unroll
      for (int o=1;o<16;o<<=1) s += __shfl_xor(s, o);
      if (r16==0) rsum[wn][mh + mt*16 + kq*4 + r] = s;
    }
  }
  __syncthreads();
  float mean[4][4];
  #pragma unroll
  for (int mt=0;mt<4;mt++){
    #pragma unroll
    for (int r=0;r<4;r++){
      const int row_l = mh + mt*16 + kq*4 + r;
      mean[mt][r] = (rsum[0][row_l]+rsum[1][row_l]+rsum[2][row_l]+rsum[3][row_l]) * (1.f/256.f);
    }
  }
  // ---- pass 2: row sumsq of (z-mean) -> var ----
  #pragma unroll
  for (int mt=0;mt<4;mt++){
    #pragma unroll
    for (int r=0;r<4;r++){
      const float m = mean[mt][r];
      float s2 = 0.f;
      #pragma unroll
      for (int nt=0;nt<4;nt++){ const float d = acc[mt][nt][r]-m; s2 += d*d; }
      #pragma unroll
      for (int o=1;o<16;o<<=1) s2 += __shfl_xor(s2, o);
      if (r16==0) rsq[wn][mh + mt*16 + kq*4 + r] = s2;
    }
  }
  __syncthreads();
  // ---- normalize + affine + write ----
  float gv[4], bev[4];
  #pragma unroll
  for (int nt=0;nt<4;nt++){
    gv[nt]  = ldin(g,  nh + nt*16 + r16, mode);
    bev[nt] = ldin(be, nh + nt*16 + r16, mode);
  }
  #pragma unroll
  for (int mt=0;mt<4;mt++){
    #pragma unroll
    for (int r=0;r<4;r++){
      const int row_l = mh + mt*16 + kq*4 + r;
      const float var = (rsq[0][row_l]+rsq[1][row_l]+rsq[2][row_l]+rsq[3][row_l]) * (1.f/256.f);
      const float inv = rsqrtf(var + 1e-5f);
      const float m = mean[mt][r];
      const size_t obase = (size_t)(gm0 + row_l)*256;
      #pragma unroll
      for (int nt=0;nt<4;nt++){
        const int col = nh + nt*16 + r16;
        const float o = (acc[mt][nt][r]-m)*inv*gv[nt] + bev[nt];
        if (out_bf16) ((ushort_t*)OUT)[obase + col] = f2bfbits(o);
        else          stout(OUT, out_off + obase + col, mode, o);
      }
    }
  }
}

// ---------------------------------------------------------------------------
// KV split/transpose prep (unchanged)
// ---------------------------------------------------------------------------
__global__ __launch_bounds__(256) void k_kvsplit(
    const float* __restrict__ kws, const float* __restrict__ vws,
    ushort_t* __restrict__ khi, ushort_t* __restrict__ klo,
    ushort_t* __restrict__ vthi, ushort_t* __restrict__ vtlo)
{
  const int row = blockIdx.x;        // 0..255 = b*32 + key
  const int b = row >> 5, key = row & 31;
  const int t = threadIdx.x;         // dim 0..255
  const float f = kws[(size_t)row*256 + t];
  const ushort_t fh = f2bfbits(f);
  khi[(size_t)row*256 + t] = fh;
  klo[(size_t)row*256 + t] = f2bfbits(f - bf2f(fh));
  const float g = vws[(size_t)row*256 + t];
  const ushort_t gh = f2bfbits(g);
  const size_t vt = ((size_t)b*256 + t)*32 + key;
  vthi[vt] = gh;
  vtlo[vt] = f2bfbits(g - bf2f(gh));
}

// ---------------------------------------------------------------------------
// A2: MFMA MHA (unchanged from R5)
// ---------------------------------------------------------------------------
__global__ __launch_bounds__(256) void k_attn2(
    const ushort_t* __restrict__ qcH,
    ushort_t* __restrict__ aoh,
    const ushort_t* __restrict__ khi, const ushort_t* __restrict__ klo,
    const ushort_t* __restrict__ vthi, const ushort_t* __restrict__ vtlo,
    const char* __restrict__ tmask, int r0)
{
  __shared__ float P[4][16][36];
  const int tid = threadIdx.x;
  const int wv = tid>>6, lane = tid&63;
  const int lrow0 = blockIdx.x*64 + wv*16;
  const int b = (r0 + lrow0)/NVTOK;
  const int m16 = lane&15;
  const int kq = lane>>4;
  const int q8 = kq*8;
  const int key0 = m16, key1 = m16+16;
  const bool msk0 = tmask[b*LT + key0] != 0;
  const bool msk1 = tmask[b*LT + key1] != 0;
  const float scale = 0.17677669529663687f;

  for (int h=0; h<8; ++h){
    const size_t qoff = (size_t)(lrow0 + m16)*256 + h*32 + q8;
    const v8s qh = *(const v8s*)&qcH[qoff];
    const size_t kb0 = ((size_t)(b*32+key0)*256) + h*32 + q8;
    const size_t kb1 = ((size_t)(b*32+key1)*256) + h*32 + q8;
    const v8s kh0 = *(const v8s*)&khi[kb0];
    const v8s kl0 = *(const v8s*)&klo[kb0];
    const v8s kh1 = *(const v8s*)&khi[kb1];
    const v8s kl1 = *(const v8s*)&klo[kb1];
    v4f s0 = (v4f){0.f,0.f,0.f,0.f}, s1 = (v4f){0.f,0.f,0.f,0.f};
    s0 = __builtin_amdgcn_mfma_f32_16x16x32_bf16(qh, kh0, s0, 0,0,0);
    s0 = __builtin_amdgcn_mfma_f32_16x16x32_bf16(qh, kl0, s0, 0,0,0);
    s1 = __builtin_amdgcn_mfma_f32_16x16x32_bf16(qh, kh1, s1, 0,0,0);
    s1 = __builtin_amdgcn_mfma_f32_16x16x32_bf16(qh, kl1, s1, 0,0,0);
    float e0[4], e1[4], inv[4];
    #pragma unroll
    for (int r=0;r<4;r++){
      const float a0 = msk0 ? -1e9f : s0[r]*scale;
      const float a1 = msk1 ? -1e9f : s1[r]*scale;
      float mx = fmaxf(a0,a1);
      #pragma unroll
      for (int o=1;o<16;o<<=1) mx = fmaxf(mx, __shfl_xor(mx,o));
      const float x0 = __expf(a0-mx), x1 = __expf(a1-mx);
      float dn = x0+x1;
      #pragma unroll
      for (int o=1;o<16;o<<=1) dn += __shfl_xor(dn,o);
      e0[r]=x0; e1[r]=x1; inv[r] = 1.f/dn;
    }
    #pragma unroll
    for (int r=0;r<4;r++){
      P[wv][kq*4+r][key0] = e0[r];
      P[wv][kq*4+r][key1] = e1[r];
    }
    __syncthreads();
    float pv[8];
    *(float4*)&pv[0] = *(const float4*)&P[wv][m16][q8];
    *(float4*)&pv[4] = *(const float4*)&P[wv][m16][q8+4];
    v8s ph;
    #pragma unroll
    for (int j=0;j<8;j++) ph[j] = (short)f2bfbits(pv[j]);
    const size_t vb0 = ((size_t)(b*256 + h*32 + m16)*32) + q8;
    const size_t vb1 = ((size_t)(b*256 + h*32 + 16 + m16)*32) + q8;
    const v8s vh0 = *(const v8s*)&vthi[vb0];
    const v8s vl0 = *(const v8s*)&vtlo[vb0];
    const v8s vh1 = *(const v8s*)&vthi[vb1];
    const v8s vl1 = *(const v8s*)&vtlo[vb1];
    v4f o0 = (v4f){0.f,0.f,0.f,0.f}, o1 = (v4f){0.f,0.f,0.f,0.f};
    o0 = __builtin_amdgcn_mfma_f32_16x16x32_bf16(ph, vh0, o0, 0,0,0);
    o0 = __builtin_amdgcn_mfma_f32_16x16x32_bf16(ph, vl0, o0, 0,0,0);
    o1 = __builtin_amdgcn_mfma_f32_16x16x32_bf16(ph, vh1, o1, 0,0,0);
    o1 = __builtin_amdgcn_mfma_f32_16x16x32_bf16(ph, vl1, o1, 0,0,0);
    __syncthreads();
    #pragma unroll
    for (int r=0;r<4;r++){
      const size_t ro = (size_t)(lrow0 + kq*4 + r)*256 + h*32;
      aoh[ro + m16]      = f2bfbits(o0[r]*inv[r]);
      aoh[ro + 16 + m16] = f2bfbits(o1[r]*inv[r]);
    }
  }
}

// ---------------------------------------------------------------------------
// residual + two-pass LayerNorm (text side, unchanged)
// ---------------------------------------------------------------------------
__global__ __launch_bounds__(256) void k_add_ln(
    const float* __restrict__ X, const void* R, size_t r_off, int r_f32,
    void* OUT, size_t o_off, int o_f32,
    void* OUT2, size_t o2_off,
    const void* g, const void* be, const int* __restrict__ mf)
{
  const int mode = *mf;
  const int row = blockIdx.x; const int t = threadIdx.x;
  const size_t idx = (size_t)row*256 + t;
  __shared__ float red[4];
  const float rv = r_f32 ? ((const float*)R)[r_off+idx] : ldin(R, r_off+idx, mode);
  const float v = X[idx] + rv;
  const float m = block_sum(v, red) * (1.f/256.f);
  __syncthreads();
  const float d = v - m;
  const float var = block_sum(d*d, red) * (1.f/256.f);
  const float o = d*rsqrtf(var+1e-5f)*ldin(g,t,mode) + ldin(be,t,mode);
  if (o_f32) ((float*)OUT)[o_off+idx] = o;
  else       stout(OUT, o_off+idx, mode, o);
  if (OUT2)  stout(OUT2, o2_off+idx, mode, o);
}

// ---------------------------------------------------------------------------
extern "C" void kernel_launch(void* const* d_in, const int* in_sizes, int n_in,
                              void* d_out, int out_size, void* d_ws, size_t ws_size,
                              hipStream_t stream)
{
  (void)n_in; (void)out_size;
  const void* vis_tokens = d_in[0];
  const void* text_tokens= d_in[1];
  const void* vis_value  = d_in[2];
  const void* ref_w = d_in[3];  const void* ref_b = d_in[4];
  const void* off_w = d_in[5];  const void* off_b = d_in[6];
  const void* aw_w  = d_in[7];  const void* aw_b  = d_in[8];
  const void* vproj_w = d_in[9];  const void* vproj_b = d_in[10];
  const void* oproj_w = d_in[11]; const void* oproj_b = d_in[12];
  const void* lvi_out_w = d_in[13]; const void* lvi_out_b = d_in[14];
  const void* lvi_n1_s = d_in[15];  const void* lvi_n1_b = d_in[16];
  const void* lvi_f1_w = d_in[17];  const void* lvi_f1_b = d_in[18];
  const void* lvi_f2_w = d_in[19];  const void* lvi_f2_b = d_in[20];
  const void* lvi_n2_s = d_in[21];  const void* lvi_n2_b = d_in[22];
  const void* mha_qw = d_in[23]; const void* mha_qb = d_in[24];
  const void* mha_kw = d_in[25]; const void* mha_kb = d_in[26];
  const void* mha_vw = d_in[27]; const void* mha_vb = d_in[28];
  const void* mha_ow = d_in[29]; const void* mha_ob = d_in[30];
  const void* vli_out_w = d_in[31]; const void* vli_out_b = d_in[32];
  const void* vli_n1_s = d_in[33];  const void* vli_n1_b = d_in[34];
  const void* vli_f1_w = d_in[35];  const void* vli_f1_b = d_in[36];
  const void* vli_f2_w = d_in[37];  const void* vli_f2_b = d_in[38];
  const void* vli_n2_s = d_in[39];  const void* vli_n2_b = d_in[40];
  const char* tmask = (const char*)d_in[43];
  const char* vmask = (const char*)d_in[44];

  // ---- workspace layout ----
  char* ws = (char*)d_ws;
  int*   flag    = (int*)  (ws + 0);               // 256 B
  float* loc_ws  = (float*)(ws + 256);             // 196608
  float* aw_ws   = (float*)(ws + 196864);          //  98304
  float* ctxt_ws = (float*)(ws + 295168);          // 262144
  float* t_ws    = (float*)(ws + 557312);          // 262144
  float* tout_ws = (float*)(ws + 819456);          // 262144
  float* k_ws    = (float*)(ws + 1081600);         // 262144
  float* v_ws    = (float*)(ws + 1343744);         // 262144
  ushort_t* wtq  = (ushort_t*)(ws + 1605888ull);   // 131072 B
  ushort_t* wto  = (ushort_t*)(ws + 1736960ull);   // 131072 B
  ushort_t* wtf1 = (ushort_t*)(ws + 1868032ull);   // 524288 B
  ushort_t* wtf2 = (ushort_t*)(ws + 2392320ull);   // 524288 B
  ushort_t* wtk   = (ushort_t*)(ws + 2916608ull);  // 131072 B (mha_kw^T)
  ushort_t* wtv   = (ushort_t*)(ws + 3047680ull);  // 131072 B (mha_vw^T)
  ushort_t* wtop  = (ushort_t*)(ws + 3178752ull);  // 131072 B (oproj_w^T)
  ushort_t* wtlo  = (ushort_t*)(ws + 3309824ull);  // 131072 B (lvi_out_w^T)
  ushort_t* wtlf1 = (ushort_t*)(ws + 3440896ull);  // 524288 B (lvi_f1_w^T)
  ushort_t* wtlf2 = (ushort_t*)(ws + 3965184ull);  // 524288 B (lvi_f2_w^T)
  float* hbuf_t   = (float*)(ws + 4489472ull);     // 1048576 B (256x1024)
  float* ybuf     = (float*)(ws + 5538048ull);     // 262144 B
  float* fbuf     = (float*)(ws + 5800192ull);     // 262144 B
  ushort_t* khi   = (ushort_t*)(ws + 6062336ull);  // 131072 B
  ushort_t* klo   = (ushort_t*)(ws + 6193408ull);  // 131072 B
  ushort_t* vthi  = (ushort_t*)(ws + 6324480ull);  // 131072 B
  ushort_t* vtlo  = (ushort_t*)(ws + 6455552ull);  // 131072 B
  const size_t fe = 6586624ull;                    // chunk region start

  // per-row chunk bytes (3072 B/row), ubuf + standalone vis-LNs eliminated:
  //   region0 ( 512 B): qc bf16 (dead after attn2)
  //   region1 ( 512 B): v1 bf16
  //   region2 (2048 B): hb bf16; first 512 B alias ao bf16 (dead pre-f1)
  long long R_ll = 128;
  if (ws_size > fe) R_ll = (long long)((ws_size - fe) / 3072ull);
  if (R_ll > (long long)MVIS) R_ll = MVIS;
  R_ll &= ~127LL;
  if (R_ll < 128) R_ll = 128;
  const int R = (int)R_ll;
  ushort_t* qcH  = (ushort_t*)(ws + fe);                      // region0
  ushort_t* v1H  = (ushort_t*)(ws + fe + (size_t)R*512ull);   // region1
  ushort_t* hbH  = (ushort_t*)(ws + fe + (size_t)R*1024ull);  // region2
  ushort_t* aoH  = hbH;                                       // alias (dead pre-f1)

  // ---- dtype detect ----
  int ndw = in_sizes[1]/2; if (ndw < 1) ndw = 1;
  k_detect<<<1,256,0,stream>>>((const uint_t*)text_tokens, ndw, flag);

  // ---- weight transposes for MFMA GEMMs ----
  k_transpose<<<dim3(8,8),  256,0,stream>>>(mha_qw,    wtq,   256, 256,  flag);
  k_transpose<<<dim3(8,8),  256,0,stream>>>(mha_ow,    wto,   256, 256,  flag);
  k_transpose<<<dim3(8,32), 256,0,stream>>>(vli_f1_w,  wtf1,  256, 1024, flag);
  k_transpose<<<dim3(32,8), 256,0,stream>>>(vli_f2_w,  wtf2,  1024, 256, flag);
  k_transpose<<<dim3(8,8),  256,0,stream>>>(mha_kw,    wtk,   256, 256,  flag);
  k_transpose<<<dim3(8,8),  256,0,stream>>>(mha_vw,    wtv,   256, 256,  flag);
  k_transpose<<<dim3(8,8),  256,0,stream>>>(oproj_w,   wtop,  256, 256,  flag);
  k_transpose<<<dim3(8,8),  256,0,stream>>>(lvi_out_w, wtlo,  256, 256,  flag);
  k_transpose<<<dim3(8,32), 256,0,stream>>>(lvi_f1_w,  wtlf1, 256, 1024, flag);
  k_transpose<<<dim3(32,8), 256,0,stream>>>(lvi_f2_w,  wtlf2, 1024, 256, flag);

  // ---- text side ----
  k_text_prep<<<MTEXT,256,0,stream>>>(text_tokens, ref_w, ref_b, off_w, off_b,
                                      aw_w, aw_b, loc_ws, aw_ws, flag);
  k_deform<<<MTEXT*NHEAD,64,0,stream>>>(vis_value, vmask, vproj_w, vproj_b,
                                        loc_ws, aw_ws, ctxt_ws, flag);

  // attn-out path: y = ctx@oproj + b ; z = y@lvi_out + b ; t = LN(text + z)
  {
    dim3 g22(2,2);
    k_mgemm<<<g22,256,0,stream>>>(ctxt_ws, 0, 1, wtop, oproj_b, ybuf, 256, 256, 0, flag);
    k_mgemm<<<g22,256,0,stream>>>(ybuf,    0, 1, wtlo, lvi_out_b, fbuf, 256, 256, 0, flag);
    k_add_ln<<<MTEXT,256,0,stream>>>(fbuf, text_tokens, 0, 0,
                                     t_ws, 0, 1, nullptr, 0, lvi_n1_s, lvi_n1_b, flag);
  }
  // ffn path: h = relu(t@f1+b1) ; f = h@f2+b2 ; tout = LN(t + f)
  {
    dim3 g28(2,8), g22(2,2);
    k_mgemm<<<g28,256,0,stream>>>(t_ws,   0, 1, wtlf1, lvi_f1_b, hbuf_t, 1024, 256, 1, flag);
    k_mgemm<<<g22,256,0,stream>>>(hbuf_t, 0, 1, wtlf2, lvi_f2_b, fbuf,   256, 1024, 0, flag);
    k_add_ln<<<MTEXT,256,0,stream>>>(fbuf, t_ws, 0, 1,
                                     tout_ws, 0, 1, d_out, VISSZ, lvi_n2_s, lvi_n2_b, flag);
  }
  // k/v projection of text_out + bf16 hi/lo split (+ V transpose)
  {
    dim3 g22(2,2);
    k_mgemm<<<g22,256,0,stream>>>(tout_ws, 0, 1, wtk, mha_kb, k_ws, 256, 256, 0, flag);
    k_mgemm<<<g22,256,0,stream>>>(tout_ws, 0, 1, wtv, mha_vb, v_ws, 256, 256, 0, flag);
    k_kvsplit<<<256,256,0,stream>>>(k_ws, v_ws, khi, klo, vthi, vtlo);
  }

  // ---- vis side, chunked by R rows ----
  for (int r0 = 0; r0 < MVIS; r0 += R){
    const int nr = (MVIS - r0 < R) ? (MVIS - r0) : R;   // multiple of 128
    dim3 g2(nr/128, 2), g8(nr/128, 8);
    k_mgemm3<<<g2,256,0,stream>>>(vis_tokens, (size_t)r0*256, 0,
                                  wtq, mha_qb, nullptr, qcH, 256, 256, 0, flag);
    k_attn2<<<nr/64,256,0,stream>>>(qcH, aoH, khi, klo, vthi, vtlo, tmask, r0);
    // o-proj + residual(vis_tokens) + LN1 -> v1H (bf16)
    k_mgemm_ln<<<nr/128,512,0,stream>>>(aoH, wto, mha_ob,
                                        vis_tokens, (size_t)r0*256, 0,
                                        v1H, 0, 1,
                                        vli_n1_s, vli_n1_b, 256, flag);
    k_mgemm3<<<g8,256,0,stream>>>(v1H, 0, 2,
                                  wtf1, vli_f1_b, nullptr, hbH, 1024, 256, 1, flag);
    // f2 + residual(v1H) + LN2 -> d_out (mode-typed)
    k_mgemm_ln<<<nr/128,512,0,stream>>>(hbH, wtf2, vli_f2_b,
                                        v1H, 0, 1,
                                        d_out, (size_t)r0*256, 0,
                                        vli_n2_s, vli_n2_b, 1024, flag);
  }
}

// Round 10
// 883.750 us; speedup vs baseline: 1.2850x; 1.0221x over previous
//
#include <hip/hip_runtime.h>
#include <hip/hip_bf16.h>
#include <math.h>

typedef __hip_bfloat16 bf16;
typedef unsigned short ushort_t;
typedef unsigned int uint_t;
typedef short v8s __attribute__((ext_vector_type(8)));
typedef float v4f __attribute__((ext_vector_type(4)));

#define NVTOK 9072
#define BATCH 8
#define LT 32
#define DMODEL 256
#define NHEAD 8
#define DHEAD 32
#define MVIS (BATCH*NVTOK)   /* 72576 */
#define MTEXT (BATCH*LT)     /* 256 */
#define VISSZ 18579456ull    /* MVIS*256 elements */

__device__ __forceinline__ float bf2f(ushort_t u){ return __uint_as_float(((uint_t)u)<<16); }
__device__ __forceinline__ ushort_t f2bfbits(float f){
  __hip_bfloat16 h = __float2bfloat16(f);
  union { __hip_bfloat16 h; ushort_t u; } c; c.h = h; return c.u;
}
// mode: 0 = buffers hold bf16, 1 = buffers hold fp32
__device__ __forceinline__ float ldin(const void* p, size_t i, int mode){
  return mode ? ((const float*)p)[i] : bf2f(((const ushort_t*)p)[i]);
}
__device__ __forceinline__ void stout(void* p, size_t i, int mode, float v){
  if (mode) ((float*)p)[i] = v; else ((ushort_t*)p)[i] = f2bfbits(v);
}

// async global->LDS, 16 B per lane (LDS dest = wave-uniform base + lane*16).
__device__ __forceinline__ void gload_lds16(const void* g, void* l){
  __builtin_amdgcn_global_load_lds(
      (const __attribute__((address_space(1))) unsigned int*)g,
      (__attribute__((address_space(3))) unsigned int*)l, 16, 0, 0);
}

// ---------------------------------------------------------------------------
// D0: dtype detector (unchanged)
// ---------------------------------------------------------------------------
__global__ void k_detect(const uint_t* __restrict__ buf, int n_avail, int* __restrict__ flag){
  __shared__ int zc, bc;
  if (threadIdx.x==0){ zc=0; bc=0; }
  __syncthreads();
  int stride = n_avail/2048; if (stride < 1) stride = 1;
  int nz=0, nb=0;
  for (int i=threadIdx.x; i<2048; i+=256){
    long long idx = (long long)i*stride;
    if (idx >= n_avail) break;
    uint_t d = buf[idx];
    uint_t lo = d & 0xFFFFu;
    int e = (int)((lo >> 7) & 0xFF);
    if (lo == 0) nz++;
    else if (e >= 90 && e <= 160) nb++;
  }
  atomicAdd(&zc, nz); atomicAdd(&bc, nb);
  __syncthreads();
  if (threadIdx.x==0){
    int mode;
    if (zc > 1024) mode = 1;
    else if (bc > 1228) mode = 0;
    else mode = 1;
    *flag = mode;
  }
}

// ---------------------------------------------------------------------------
// W-transpose (unchanged)
// ---------------------------------------------------------------------------
__global__ __launch_bounds__(256) void k_transpose(
    const void* W, ushort_t* __restrict__ Wt, int K, int N,
    const int* __restrict__ mf)
{
  const int mode = *mf;
  __shared__ float tile[32][33];
  const int k0 = blockIdx.x*32, n0 = blockIdx.y*32;
  const int c = threadIdx.x & 31, r8 = threadIdx.x >> 5;
  #pragma unroll
  for (int i=0;i<4;i++){
    const int kk = r8 + i*8;
    tile[kk][c] = ldin(W, (size_t)(k0+kk)*N + n0 + c, mode);
  }
  __syncthreads();
  #pragma unroll
  for (int i=0;i<4;i++){
    const int nn = r8 + i*8;
    Wt[(size_t)(n0+nn)*K + k0 + c] = f2bfbits(tile[c][nn]);
  }
}

// ---------------------------------------------------------------------------
// T1: text prep (unchanged)
// ---------------------------------------------------------------------------
__global__ __launch_bounds__(256) void k_text_prep(
    const void* text,
    const void* ref_w, const void* ref_b,
    const void* off_w, const void* off_b,
    const void* aw_w,  const void* aw_b,
    float* __restrict__ loc_out, float* __restrict__ aw_out,
    const int* __restrict__ mf)
{
  const int mode = *mf;
  const int r = blockIdx.x;
  const int t = threadIdx.x;
  __shared__ float x[256];
  __shared__ float refv[6];
  __shared__ float offv[192];
  __shared__ float logit[96];
  x[t] = ldin(text, (size_t)r*256 + t, mode);
  __syncthreads();
  if (t < 192) {
    float s = 0.f;
    for (int k=0;k<256;k++) s += x[k]*ldin(off_w, (size_t)k*192+t, mode);
    offv[t] = s + ldin(off_b, t, mode);
  } else if (t < 198) {
    int j = t-192;
    float s = 0.f;
    for (int k=0;k<256;k++) s += x[k]*ldin(ref_w, (size_t)k*6+j, mode);
    s += ldin(ref_b, j, mode);
    refv[j] = 1.f/(1.f+expf(-s));
  }
  if (t < 96) {
    float s = 0.f;
    for (int k=0;k<256;k++) s += x[k]*ldin(aw_w, (size_t)k*96+t, mode);
    logit[t] = s + ldin(aw_b, t, mode);
  }
  __syncthreads();
  if (t < 8) {
    float mx = -1e30f;
    for (int j=0;j<12;j++) mx = fmaxf(mx, logit[t*12+j]);
    float e[12]; float den = 0.f;
    for (int j=0;j<12;j++){ e[j] = expf(logit[t*12+j]-mx); den += e[j]; }
    float inv = 1.f/den;
    for (int j=0;j<12;j++) aw_out[(size_t)r*96 + t*12 + j] = e[j]*inv;
  }
  if (t < 192) {
    int rem = t % 24;
    int l = rem >> 3;
    int c = t & 1;
    const float normW[3] = {96.f,48.f,24.f};
    const float normH[3] = {72.f,36.f,18.f};
    float nrm = (c==0) ? normW[l] : normH[l];
    loc_out[(size_t)r*192 + t] = refv[l*2+c] + offv[t]/nrm;
  }
}

// ---------------------------------------------------------------------------
// T2: deformable sampling, lazy vproj (unchanged)
// ---------------------------------------------------------------------------
__global__ __launch_bounds__(64) void k_deform(
    const void* vis_value, const char* __restrict__ vmask,
    const void* vproj_w, const void* vproj_b,
    const float* __restrict__ loc, const float* __restrict__ aw,
    float* __restrict__ ctx_out, const int* __restrict__ mf)
{
  const int mode = *mf;
  const int blk = blockIdx.x;      // r*8 + h
  const int r = blk >> 3;
  const int h = blk & 7;
  const int b = r >> 5;
  const int t = threadIdx.x;
  const int Hs[3] = {72,36,18};
  const int Wsz[3] = {96,48,24};
  const int stl[3] = {0,6912,8640};
  float s0=0.f,s1=0.f,s2=0.f,s3=0.f, wsum=0.f;
  for (int l=0;l<3;l++){
    for (int p=0;p<4;p++){
      const int sIdx = blk*12 + l*4 + p;
      const float a  = aw[sIdx];
      const float X = loc[sIdx*2+0]*(float)Wsz[l] - 0.5f;
      const float Y = loc[sIdx*2+1]*(float)Hs[l] - 0.5f;
      const float x0f = floorf(X), y0f = floorf(Y);
      const int x0 = (int)x0f, y0 = (int)y0f;
      const float wx = X-x0f, wy = Y-y0f;
      const float cw[4] = {(1.f-wx)*(1.f-wy), wx*(1.f-wy), (1.f-wx)*wy, wx*wy};
      const int cx[4] = {x0,x0+1,x0,x0+1};
      const int cy[4] = {y0,y0,y0+1,y0+1};
      for (int c=0;c<4;c++){
        if (cx[c]>=0 && cx[c]<Wsz[l] && cy[c]>=0 && cy[c]<Hs[l]){
          const size_t pos = (size_t)b*NVTOK + stl[l] + cy[c]*Wsz[l] + cx[c];
          if (vmask[pos]) continue;
          const float w = a*cw[c];
          wsum += w;
          const size_t base = pos*256 + t*4;
          s0 += w*ldin(vis_value, base+0, mode);
          s1 += w*ldin(vis_value, base+1, mode);
          s2 += w*ldin(vis_value, base+2, mode);
          s3 += w*ldin(vis_value, base+3, mode);
        }
      }
    }
  }
  __shared__ float sh[256];
  sh[t*4+0]=s0; sh[t*4+1]=s1; sh[t*4+2]=s2; sh[t*4+3]=s3;
  __syncthreads();
  if (t < 32) {
    const int col = h*32 + t;
    float acc = wsum * ldin(vproj_b, col, mode);
    for (int k=0;k<256;k++) acc += sh[k]*ldin(vproj_w, (size_t)k*256+col, mode);
    ctx_out[(size_t)r*256 + col] = acc;
  }
}

__device__ __forceinline__ float block_sum(float v, float* red){
  float sm = v;
  #pragma unroll
  for (int o=32;o>0;o>>=1) sm += __shfl_down(sm,o);
  const int t = threadIdx.x;
  __syncthreads();
  if ((t&63)==0) red[t>>6] = sm;
  __syncthreads();
  return red[0]+red[1]+red[2]+red[3];
}

// ---------------------------------------------------------------------------
// MFMA GEMM (text side, unchanged — tiny M, full hi/lo precision)
// ---------------------------------------------------------------------------
__global__ __launch_bounds__(256) void k_mgemm(
    const void* A, size_t a_off, int a_kind,
    const ushort_t* __restrict__ Wt, const void* bias, float* __restrict__ C,
    int N, int K, int relu, const int* __restrict__ mf)
{
  const int mode = *mf;
  const int split = (a_kind==1) || (mode==1);
  __shared__ ushort_t Ah[128*32];
  __shared__ ushort_t Al[128*32];
  __shared__ ushort_t Bt[128*32];
  const int tid = threadIdx.x;
  const int gm0 = blockIdx.x*128, gn0 = blockIdx.y*128;
  const int wv = tid>>6, lane = tid&63;
  const int mh = (wv&1)*64, nh = (wv>>1)*64;
  const int r16 = lane&15, q8 = (lane>>4)*8;
  const int srow = tid>>1, sseg = (tid&1)*16;
  v4f acc[4][4];
  #pragma unroll
  for (int i=0;i<4;i++)
    #pragma unroll
    for (int j=0;j<4;j++) acc[i][j] = (v4f){0.f,0.f,0.f,0.f};

  for (int k0=0; k0<K; k0+=32){
    if (k0) __syncthreads();
    {
      const ushort_t* src = Wt + (size_t)(gn0+srow)*K + k0 + sseg;
      ((uint4*)&Bt[srow*32+sseg])[0]   = ((const uint4*)src)[0];
      ((uint4*)&Bt[srow*32+sseg+8])[0] = ((const uint4*)src)[1];
    }
    if (!split){
      const ushort_t* src = (const ushort_t*)A + a_off + (size_t)(gm0+srow)*K + k0 + sseg;
      ((uint4*)&Ah[srow*32+sseg])[0]   = ((const uint4*)src)[0];
      ((uint4*)&Ah[srow*32+sseg+8])[0] = ((const uint4*)src)[1];
    } else {
      const float* src = (const float*)A + a_off + (size_t)(gm0+srow)*K + k0 + sseg;
      #pragma unroll
      for (int v=0;v<4;v++){
        float4 f = ((const float4*)src)[v];
        float xs[4] = {f.x, f.y, f.z, f.w};
        #pragma unroll
        for (int e=0;e<4;e++){
          const int idx = srow*32 + sseg + v*4 + e;
          const ushort_t h = f2bfbits(xs[e]);
          Ah[idx] = h;
          Al[idx] = f2bfbits(xs[e] - bf2f(h));
        }
      }
    }
    __syncthreads();
    v8s af[4], bfr[4], al[4];
    #pragma unroll
    for (int mt=0;mt<4;mt++){
      af[mt] = *(const v8s*)&Ah[(mh + mt*16 + r16)*32 + q8];
      if (split) al[mt] = *(const v8s*)&Al[(mh + mt*16 + r16)*32 + q8];
    }
    #pragma unroll
    for (int nt=0;nt<4;nt++)
      bfr[nt] = *(const v8s*)&Bt[(nh + nt*16 + r16)*32 + q8];
    #pragma unroll
    for (int mt=0;mt<4;mt++){
      #pragma unroll
      for (int nt=0;nt<4;nt++){
        acc[mt][nt] = __builtin_amdgcn_mfma_f32_16x16x32_bf16(af[mt], bfr[nt], acc[mt][nt], 0, 0, 0);
        if (split)
          acc[mt][nt] = __builtin_amdgcn_mfma_f32_16x16x32_bf16(al[mt], bfr[nt], acc[mt][nt], 0, 0, 0);
      }
    }
  }
  const int rq = (lane>>4)*4;
  float bv[4];
  #pragma unroll
  for (int nt=0;nt<4;nt++) bv[nt] = ldin(bias, gn0 + nh + nt*16 + r16, mode);
  #pragma unroll
  for (int mt=0;mt<4;mt++){
    #pragma unroll
    for (int r=0;r<4;r++){
      const size_t ro = (size_t)(gm0 + mh + mt*16 + rq + r)*N + gn0 + nh + r16;
      #pragma unroll
      for (int nt=0;nt<4;nt++){
        float v = acc[mt][nt][r] + bv[nt];
        if (relu) v = fmaxf(v, 0.f);
        C[ro + nt*16] = v;
      }
    }
  }
}

// ---------------------------------------------------------------------------
// V3 MFMA GEMM (vis q-proj / f1): 128x128 tile, single-pass bf16
// activations, gload_lds16 staging, XCD-bijective swizzle (R5 structure —
// best measured). Output fp32 or bf16.
// ---------------------------------------------------------------------------
__global__ __launch_bounds__(256) void k_mgemm3(
    const void* A, size_t a_off, int a_kind,
    const ushort_t* __restrict__ Wt, const void* bias,
    float* __restrict__ Cf, ushort_t* __restrict__ Chi,
    int N, int K, int relu, const int* __restrict__ mf)
{
  const int mode = *mf;
  const int rawf32 = (a_kind==0) && (mode==1);
  __shared__ ushort_t Ah[128*32];
  __shared__ ushort_t Bt[128*32];
  const int tid = threadIdx.x;
  const int nbx = gridDim.x, nby = gridDim.y;
  const int total = nbx*nby;
  const int f = blockIdx.y*nbx + blockIdx.x;
  const int qq = total>>3, rr = total&7;
  const int xcd = f&7, pos = f>>3;
  const int wg = (xcd<rr ? xcd*(qq+1) : rr*(qq+1) + (xcd-rr)*qq) + pos;
  const int gm0 = (wg / nby)*128, gn0 = (wg % nby)*128;

  const int wv = tid>>6, lane = tid&63;
  const int mh = (wv&1)*64, nh = (wv>>1)*64;
  const int r16 = lane&15, q8 = (lane>>4)*8;
  const int grow = tid>>2;
  const int gcol = (tid&3)*8;
  const int srow = tid>>1, sseg = (tid&1)*16;
  const ushort_t* Abf = (const ushort_t*)A + a_off;
  v4f acc[4][4];
  #pragma unroll
  for (int i=0;i<4;i++)
    #pragma unroll
    for (int j=0;j<4;j++) acc[i][j] = (v4f){0.f,0.f,0.f,0.f};

  for (int k0=0; k0<K; k0+=32){
    if (k0) __syncthreads();
    gload_lds16(Wt + (size_t)(gn0+grow)*K    + k0 + gcol, &Bt[grow*32      + gcol]);
    gload_lds16(Wt + (size_t)(gn0+grow+64)*K + k0 + gcol, &Bt[(grow+64)*32 + gcol]);
    if (!rawf32){
      gload_lds16(Abf + (size_t)(gm0+grow)*K    + k0 + gcol, &Ah[grow*32      + gcol]);
      gload_lds16(Abf + (size_t)(gm0+grow+64)*K + k0 + gcol, &Ah[(grow+64)*32 + gcol]);
    } else {
      const float* src = (const float*)A + a_off + (size_t)(gm0+srow)*K + k0 + sseg;
      #pragma unroll
      for (int v=0;v<4;v++){
        float4 fq = ((const float4*)src)[v];
        float xs[4] = {fq.x, fq.y, fq.z, fq.w};
        #pragma unroll
        for (int e=0;e<4;e++)
          Ah[srow*32 + sseg + v*4 + e] = f2bfbits(xs[e]);
      }
    }
    __syncthreads();
    v8s af[4], bfr[4];
    #pragma unroll
    for (int mt=0;mt<4;mt++)
      af[mt] = *(const v8s*)&Ah[(mh + mt*16 + r16)*32 + q8];
    #pragma unroll
    for (int nt=0;nt<4;nt++)
      bfr[nt] = *(const v8s*)&Bt[(nh + nt*16 + r16)*32 + q8];
    #pragma unroll
    for (int mt=0;mt<4;mt++){
      #pragma unroll
      for (int nt=0;nt<4;nt++)
        acc[mt][nt] = __builtin_amdgcn_mfma_f32_16x16x32_bf16(af[mt], bfr[nt], acc[mt][nt], 0, 0, 0);
    }
  }
  const int rq = (lane>>4)*4;
  float bv[4];
  #pragma unroll
  for (int nt=0;nt<4;nt++) bv[nt] = ldin(bias, gn0 + nh + nt*16 + r16, mode);
  const int outf = (Cf != nullptr);
  #pragma unroll
  for (int mt=0;mt<4;mt++){
    #pragma unroll
    for (int r=0;r<4;r++){
      const size_t ro = (size_t)(gm0 + mh + mt*16 + rq + r)*N + gn0 + nh + r16;
      #pragma unroll
      for (int nt=0;nt<4;nt++){
        float v = acc[mt][nt][r] + bv[nt];
        if (relu) v = fmaxf(v, 0.f);
        if (outf) Cf[ro + nt*16] = v;
        else      Chi[ro + nt*16] = f2bfbits(v);
      }
    }
  }
}

// ---------------------------------------------------------------------------
// GEMM + residual + LayerNorm fused, v2 geometry: 64 rows x 256 cols,
// 256 thr = 4 waves (1m x 4n). Grid = M/64 (~2x blocks of the v1 128-row
// tile -> full CU coverage); LDS 22 KB (Ah 4K + Bt 16K + red 2K) -> higher
// occupancy. Each block owns complete rows so LN runs in the epilogue
// (two-pass mean/var, 16-lane shfl_xor + cross-wave LDS partials).
// A bf16 [M][K] (1 gload issue); B = Wt [256][K] bf16 (4 issues).
// ---------------------------------------------------------------------------
__global__ __launch_bounds__(256) void k_mgemm_ln(
    const ushort_t* __restrict__ A,
    const ushort_t* __restrict__ Wt, const void* bias,
    const void* RES, size_t res_off, int res_bf16,
    void* OUT, size_t out_off, int out_bf16,
    const void* g, const void* be,
    int K, const int* __restrict__ mf)
{
  const int mode = *mf;
  __shared__ ushort_t Ah[64*32];
  __shared__ ushort_t Bt[256*32];
  __shared__ float rsum[4][64];
  __shared__ float rsq[4][64];
  const int tid = threadIdx.x;
  const int gm0 = blockIdx.x*64;
  const int wv = tid>>6, lane = tid&63;
  const int nh = wv*64;
  const int r16 = lane&15, kq = lane>>4, q8 = kq*8;
  const int grow = tid>>2, gcol = (tid&3)*8;    // 64 rows (A) / 64-row slabs (B)
  v4f acc[4][4];
  #pragma unroll
  for (int i=0;i<4;i++)
    #pragma unroll
    for (int j=0;j<4;j++) acc[i][j] = (v4f){0.f,0.f,0.f,0.f};

  for (int k0=0; k0<K; k0+=32){
    if (k0) __syncthreads();
    gload_lds16(A  + (size_t)(gm0+grow)*K  + k0 + gcol, &Ah[grow*32 + gcol]);
    gload_lds16(Wt + (size_t)grow*K        + k0 + gcol, &Bt[grow*32 + gcol]);
    gload_lds16(Wt + (size_t)(64+grow)*K   + k0 + gcol, &Bt[(64+grow)*32 + gcol]);
    gload_lds16(Wt + (size_t)(128+grow)*K  + k0 + gcol, &Bt[(128+grow)*32 + gcol]);
    gload_lds16(Wt + (size_t)(192+grow)*K  + k0 + gcol, &Bt[(192+grow)*32 + gcol]);
    __syncthreads();
    v8s af[4], bfr[4];
    #pragma unroll
    for (int mt=0;mt<4;mt++)
      af[mt] = *(const v8s*)&Ah[(mt*16 + r16)*32 + q8];
    #pragma unroll
    for (int nt=0;nt<4;nt++)
      bfr[nt] = *(const v8s*)&Bt[(nh + nt*16 + r16)*32 + q8];
    #pragma unroll
    for (int mt=0;mt<4;mt++){
      #pragma unroll
      for (int nt=0;nt<4;nt++)
        acc[mt][nt] = __builtin_amdgcn_mfma_f32_16x16x32_bf16(af[mt], bfr[nt], acc[mt][nt], 0, 0, 0);
    }
  }
  // ---- z = acc + bias + residual (in place) ----
  float bv[4];
  #pragma unroll
  for (int nt=0;nt<4;nt++) bv[nt] = ldin(bias, nh + nt*16 + r16, mode);
  #pragma unroll
  for (int mt=0;mt<4;mt++){
    #pragma unroll
    for (int r=0;r<4;r++){
      const int row_l = mt*16 + kq*4 + r;
      const size_t rbase = (size_t)(gm0 + row_l)*256;
      #pragma unroll
      for (int nt=0;nt<4;nt++){
        const int col = nh + nt*16 + r16;
        const float rv = res_bf16 ? bf2f(((const ushort_t*)RES)[res_off + rbase + col])
                                  : ldin(RES, res_off + rbase + col, mode);
        acc[mt][nt][r] = acc[mt][nt][r] + bv[nt] + rv;
      }
    }
  }
  // ---- pass 1: row sums -> mean ----
  #pragma unroll
  for (int mt=0;mt<4;mt++){
    #pragma unroll
    for (int r=0;r<4;r++){
      float s = acc[mt][0][r] + acc[mt][1][r] + acc[mt][2][r] + acc[mt][3][r];
      #pragma unroll
      for (int o=1;o<16;o<<=1) s += __shfl_xor(s, o);
      if (r16==0) rsum[wv][mt*16 + kq*4 + r] = s;
    }
  }
  __syncthreads();
  float mean[4][4];
  #pragma unroll
  for (int mt=0;mt<4;mt++){
    #pragma unroll
    for (int r=0;r<4;r++){
      const int row_l = mt*16 + kq*4 + r;
      mean[mt][r] = (rsum[0][row_l]+rsum[1][row_l]+rsum[2][row_l]+rsum[3][row_l]) * (1.f/256.f);
    }
  }
  // ---- pass 2: row sumsq of (z-mean) -> var ----
  #pragma unroll
  for (int mt=0;mt<4;mt++){
    #pragma unroll
    for (int r=0;r<4;r++){
      const float m = mean[mt][r];
      float s2 = 0.f;
      #pragma unroll
      for (int nt=0;nt<4;nt++){ const float d = acc[mt][nt][r]-m; s2 += d*d; }
      #pragma unroll
      for (int o=1;o<16;o<<=1) s2 += __shfl_xor(s2, o);
      if (r16==0) rsq[wv][mt*16 + kq*4 + r] = s2;
    }
  }
  __syncthreads();
  // ---- normalize + affine + write ----
  float gv[4], bev[4];
  #pragma unroll
  for (int nt=0;nt<4;nt++){
    gv[nt]  = ldin(g,  nh + nt*16 + r16, mode);
    bev[nt] = ldin(be, nh + nt*16 + r16, mode);
  }
  #pragma unroll
  for (int mt=0;mt<4;mt++){
    #pragma unroll
    for (int r=0;r<4;r++){
      const int row_l = mt*16 + kq*4 + r;
      const float var = (rsq[0][row_l]+rsq[1][row_l]+rsq[2][row_l]+rsq[3][row_l]) * (1.f/256.f);
      const float inv = rsqrtf(var + 1e-5f);
      const float m = mean[mt][r];
      const size_t obase = (size_t)(gm0 + row_l)*256;
      #pragma unroll
      for (int nt=0;nt<4;nt++){
        const int col = nh + nt*16 + r16;
        const float o = (acc[mt][nt][r]-m)*inv*gv[nt] + bev[nt];
        if (out_bf16) ((ushort_t*)OUT)[obase + col] = f2bfbits(o);
        else          stout(OUT, out_off + obase + col, mode, o);
      }
    }
  }
}

// ---------------------------------------------------------------------------
// KV split/transpose prep (unchanged)
// ---------------------------------------------------------------------------
__global__ __launch_bounds__(256) void k_kvsplit(
    const float* __restrict__ kws, const float* __restrict__ vws,
    ushort_t* __restrict__ khi, ushort_t* __restrict__ klo,
    ushort_t* __restrict__ vthi, ushort_t* __restrict__ vtlo)
{
  const int row = blockIdx.x;        // 0..255 = b*32 + key
  const int b = row >> 5, key = row & 31;
  const int t = threadIdx.x;         // dim 0..255
  const float f = kws[(size_t)row*256 + t];
  const ushort_t fh = f2bfbits(f);
  khi[(size_t)row*256 + t] = fh;
  klo[(size_t)row*256 + t] = f2bfbits(f - bf2f(fh));
  const float g = vws[(size_t)row*256 + t];
  const ushort_t gh = f2bfbits(g);
  const size_t vt = ((size_t)b*256 + t)*32 + key;
  vthi[vt] = gh;
  vtlo[vt] = f2bfbits(g - bf2f(gh));
}

// ---------------------------------------------------------------------------
// A2: MFMA MHA (unchanged from R5)
// ---------------------------------------------------------------------------
__global__ __launch_bounds__(256) void k_attn2(
    const ushort_t* __restrict__ qcH,
    ushort_t* __restrict__ aoh,
    const ushort_t* __restrict__ khi, const ushort_t* __restrict__ klo,
    const ushort_t* __restrict__ vthi, const ushort_t* __restrict__ vtlo,
    const char* __restrict__ tmask, int r0)
{
  __shared__ float P[4][16][36];
  const int tid = threadIdx.x;
  const int wv = tid>>6, lane = tid&63;
  const int lrow0 = blockIdx.x*64 + wv*16;
  const int b = (r0 + lrow0)/NVTOK;
  const int m16 = lane&15;
  const int kq = lane>>4;
  const int q8 = kq*8;
  const int key0 = m16, key1 = m16+16;
  const bool msk0 = tmask[b*LT + key0] != 0;
  const bool msk1 = tmask[b*LT + key1] != 0;
  const float scale = 0.17677669529663687f;

  for (int h=0; h<8; ++h){
    const size_t qoff = (size_t)(lrow0 + m16)*256 + h*32 + q8;
    const v8s qh = *(const v8s*)&qcH[qoff];
    const size_t kb0 = ((size_t)(b*32+key0)*256) + h*32 + q8;
    const size_t kb1 = ((size_t)(b*32+key1)*256) + h*32 + q8;
    const v8s kh0 = *(const v8s*)&khi[kb0];
    const v8s kl0 = *(const v8s*)&klo[kb0];
    const v8s kh1 = *(const v8s*)&khi[kb1];
    const v8s kl1 = *(const v8s*)&klo[kb1];
    v4f s0 = (v4f){0.f,0.f,0.f,0.f}, s1 = (v4f){0.f,0.f,0.f,0.f};
    s0 = __builtin_amdgcn_mfma_f32_16x16x32_bf16(qh, kh0, s0, 0,0,0);
    s0 = __builtin_amdgcn_mfma_f32_16x16x32_bf16(qh, kl0, s0, 0,0,0);
    s1 = __builtin_amdgcn_mfma_f32_16x16x32_bf16(qh, kh1, s1, 0,0,0);
    s1 = __builtin_amdgcn_mfma_f32_16x16x32_bf16(qh, kl1, s1, 0,0,0);
    float e0[4], e1[4], inv[4];
    #pragma unroll
    for (int r=0;r<4;r++){
      const float a0 = msk0 ? -1e9f : s0[r]*scale;
      const float a1 = msk1 ? -1e9f : s1[r]*scale;
      float mx = fmaxf(a0,a1);
      #pragma unroll
      for (int o=1;o<16;o<<=1) mx = fmaxf(mx, __shfl_xor(mx,o));
      const float x0 = __expf(a0-mx), x1 = __expf(a1-mx);
      float dn = x0+x1;
      #pragma unroll
      for (int o=1;o<16;o<<=1) dn += __shfl_xor(dn,o);
      e0[r]=x0; e1[r]=x1; inv[r] = 1.f/dn;
    }
    #pragma unroll
    for (int r=0;r<4;r++){
      P[wv][kq*4+r][key0] = e0[r];
      P[wv][kq*4+r][key1] = e1[r];
    }
    __syncthreads();
    float pv[8];
    *(float4*)&pv[0] = *(const float4*)&P[wv][m16][q8];
    *(float4*)&pv[4] = *(const float4*)&P[wv][m16][q8+4];
    v8s ph;
    #pragma unroll
    for (int j=0;j<8;j++) ph[j] = (short)f2bfbits(pv[j]);
    const size_t vb0 = ((size_t)(b*256 + h*32 + m16)*32) + q8;
    const size_t vb1 = ((size_t)(b*256 + h*32 + 16 + m16)*32) + q8;
    const v8s vh0 = *(const v8s*)&vthi[vb0];
    const v8s vl0 = *(const v8s*)&vtlo[vb0];
    const v8s vh1 = *(const v8s*)&vthi[vb1];
    const v8s vl1 = *(const v8s*)&vtlo[vb1];
    v4f o0 = (v4f){0.f,0.f,0.f,0.f}, o1 = (v4f){0.f,0.f,0.f,0.f};
    o0 = __builtin_amdgcn_mfma_f32_16x16x32_bf16(ph, vh0, o0, 0,0,0);
    o0 = __builtin_amdgcn_mfma_f32_16x16x32_bf16(ph, vl0, o0, 0,0,0);
    o1 = __builtin_amdgcn_mfma_f32_16x16x32_bf16(ph, vh1, o1, 0,0,0);
    o1 = __builtin_amdgcn_mfma_f32_16x16x32_bf16(ph, vl1, o1, 0,0,0);
    __syncthreads();
    #pragma unroll
    for (int r=0;r<4;r++){
      const size_t ro = (size_t)(lrow0 + kq*4 + r)*256 + h*32;
      aoh[ro + m16]      = f2bfbits(o0[r]*inv[r]);
      aoh[ro + 16 + m16] = f2bfbits(o1[r]*inv[r]);
    }
  }
}

// ---------------------------------------------------------------------------
// residual + two-pass LayerNorm (text side, unchanged)
// ---------------------------------------------------------------------------
__global__ __launch_bounds__(256) void k_add_ln(
    const float* __restrict__ X, const void* R, size_t r_off, int r_f32,
    void* OUT, size_t o_off, int o_f32,
    void* OUT2, size_t o2_off,
    const void* g, const void* be, const int* __restrict__ mf)
{
  const int mode = *mf;
  const int row = blockIdx.x; const int t = threadIdx.x;
  const size_t idx = (size_t)row*256 + t;
  __shared__ float red[4];
  const float rv = r_f32 ? ((const float*)R)[r_off+idx] : ldin(R, r_off+idx, mode);
  const float v = X[idx] + rv;
  const float m = block_sum(v, red) * (1.f/256.f);
  __syncthreads();
  const float d = v - m;
  const float var = block_sum(d*d, red) * (1.f/256.f);
  const float o = d*rsqrtf(var+1e-5f)*ldin(g,t,mode) + ldin(be,t,mode);
  if (o_f32) ((float*)OUT)[o_off+idx] = o;
  else       stout(OUT, o_off+idx, mode, o);
  if (OUT2)  stout(OUT2, o2_off+idx, mode, o);
}

// ---------------------------------------------------------------------------
extern "C" void kernel_launch(void* const* d_in, const int* in_sizes, int n_in,
                              void* d_out, int out_size, void* d_ws, size_t ws_size,
                              hipStream_t stream)
{
  (void)n_in; (void)out_size;
  const void* vis_tokens = d_in[0];
  const void* text_tokens= d_in[1];
  const void* vis_value  = d_in[2];
  const void* ref_w = d_in[3];  const void* ref_b = d_in[4];
  const void* off_w = d_in[5];  const void* off_b = d_in[6];
  const void* aw_w  = d_in[7];  const void* aw_b  = d_in[8];
  const void* vproj_w = d_in[9];  const void* vproj_b = d_in[10];
  const void* oproj_w = d_in[11]; const void* oproj_b = d_in[12];
  const void* lvi_out_w = d_in[13]; const void* lvi_out_b = d_in[14];
  const void* lvi_n1_s = d_in[15];  const void* lvi_n1_b = d_in[16];
  const void* lvi_f1_w = d_in[17];  const void* lvi_f1_b = d_in[18];
  const void* lvi_f2_w = d_in[19];  const void* lvi_f2_b = d_in[20];
  const void* lvi_n2_s = d_in[21];  const void* lvi_n2_b = d_in[22];
  const void* mha_qw = d_in[23]; const void* mha_qb = d_in[24];
  const void* mha_kw = d_in[25]; const void* mha_kb = d_in[26];
  const void* mha_vw = d_in[27]; const void* mha_vb = d_in[28];
  const void* mha_ow = d_in[29]; const void* mha_ob = d_in[30];
  const void* vli_out_w = d_in[31]; const void* vli_out_b = d_in[32];
  const void* vli_n1_s = d_in[33];  const void* vli_n1_b = d_in[34];
  const void* vli_f1_w = d_in[35];  const void* vli_f1_b = d_in[36];
  const void* vli_f2_w = d_in[37];  const void* vli_f2_b = d_in[38];
  const void* vli_n2_s = d_in[39];  const void* vli_n2_b = d_in[40];
  const char* tmask = (const char*)d_in[43];
  const char* vmask = (const char*)d_in[44];

  // ---- workspace layout ----
  char* ws = (char*)d_ws;
  int*   flag    = (int*)  (ws + 0);               // 256 B
  float* loc_ws  = (float*)(ws + 256);             // 196608
  float* aw_ws   = (float*)(ws + 196864);          //  98304
  float* ctxt_ws = (float*)(ws + 295168);          // 262144
  float* t_ws    = (float*)(ws + 557312);          // 262144
  float* tout_ws = (float*)(ws + 819456);          // 262144
  float* k_ws    = (float*)(ws + 1081600);         // 262144
  float* v_ws    = (float*)(ws + 1343744);         // 262144
  ushort_t* wtq  = (ushort_t*)(ws + 1605888ull);   // 131072 B
  ushort_t* wto  = (ushort_t*)(ws + 1736960ull);   // 131072 B
  ushort_t* wtf1 = (ushort_t*)(ws + 1868032ull);   // 524288 B
  ushort_t* wtf2 = (ushort_t*)(ws + 2392320ull);   // 524288 B
  ushort_t* wtk   = (ushort_t*)(ws + 2916608ull);  // 131072 B (mha_kw^T)
  ushort_t* wtv   = (ushort_t*)(ws + 3047680ull);  // 131072 B (mha_vw^T)
  ushort_t* wtop  = (ushort_t*)(ws + 3178752ull);  // 131072 B (oproj_w^T)
  ushort_t* wtlo  = (ushort_t*)(ws + 3309824ull);  // 131072 B (lvi_out_w^T)
  ushort_t* wtlf1 = (ushort_t*)(ws + 3440896ull);  // 524288 B (lvi_f1_w^T)
  ushort_t* wtlf2 = (ushort_t*)(ws + 3965184ull);  // 524288 B (lvi_f2_w^T)
  float* hbuf_t   = (float*)(ws + 4489472ull);     // 1048576 B (256x1024)
  float* ybuf     = (float*)(ws + 5538048ull);     // 262144 B
  float* fbuf     = (float*)(ws + 5800192ull);     // 262144 B
  ushort_t* khi   = (ushort_t*)(ws + 6062336ull);  // 131072 B
  ushort_t* klo   = (ushort_t*)(ws + 6193408ull);  // 131072 B
  ushort_t* vthi  = (ushort_t*)(ws + 6324480ull);  // 131072 B
  ushort_t* vtlo  = (ushort_t*)(ws + 6455552ull);  // 131072 B
  const size_t fe = 6586624ull;                    // chunk region start

  // per-row chunk bytes (3072 B/row):
  //   region0 ( 512 B): qc bf16 (dead after attn2)
  //   region1 ( 512 B): v1 bf16
  //   region2 (2048 B): hb bf16; first 512 B alias ao bf16 (dead pre-f1)
  long long R_ll = 128;
  if (ws_size > fe) R_ll = (long long)((ws_size - fe) / 3072ull);
  if (R_ll > (long long)MVIS) R_ll = MVIS;
  R_ll &= ~127LL;
  if (R_ll < 128) R_ll = 128;
  const int R = (int)R_ll;
  ushort_t* qcH  = (ushort_t*)(ws + fe);                      // region0
  ushort_t* v1H  = (ushort_t*)(ws + fe + (size_t)R*512ull);   // region1
  ushort_t* hbH  = (ushort_t*)(ws + fe + (size_t)R*1024ull);  // region2
  ushort_t* aoH  = hbH;                                       // alias (dead pre-f1)

  // ---- dtype detect ----
  int ndw = in_sizes[1]/2; if (ndw < 1) ndw = 1;
  k_detect<<<1,256,0,stream>>>((const uint_t*)text_tokens, ndw, flag);

  // ---- weight transposes for MFMA GEMMs ----
  k_transpose<<<dim3(8,8),  256,0,stream>>>(mha_qw,    wtq,   256, 256,  flag);
  k_transpose<<<dim3(8,8),  256,0,stream>>>(mha_ow,    wto,   256, 256,  flag);
  k_transpose<<<dim3(8,32), 256,0,stream>>>(vli_f1_w,  wtf1,  256, 1024, flag);
  k_transpose<<<dim3(32,8), 256,0,stream>>>(vli_f2_w,  wtf2,  1024, 256, flag);
  k_transpose<<<dim3(8,8),  256,0,stream>>>(mha_kw,    wtk,   256, 256,  flag);
  k_transpose<<<dim3(8,8),  256,0,stream>>>(mha_vw,    wtv,   256, 256,  flag);
  k_transpose<<<dim3(8,8),  256,0,stream>>>(oproj_w,   wtop,  256, 256,  flag);
  k_transpose<<<dim3(8,8),  256,0,stream>>>(lvi_out_w, wtlo,  256, 256,  flag);
  k_transpose<<<dim3(8,32), 256,0,stream>>>(lvi_f1_w,  wtlf1, 256, 1024, flag);
  k_transpose<<<dim3(32,8), 256,0,stream>>>(lvi_f2_w,  wtlf2, 1024, 256, flag);

  // ---- text side ----
  k_text_prep<<<MTEXT,256,0,stream>>>(text_tokens, ref_w, ref_b, off_w, off_b,
                                      aw_w, aw_b, loc_ws, aw_ws, flag);
  k_deform<<<MTEXT*NHEAD,64,0,stream>>>(vis_value, vmask, vproj_w, vproj_b,
                                        loc_ws, aw_ws, ctxt_ws, flag);

  // attn-out path: y = ctx@oproj + b ; z = y@lvi_out + b ; t = LN(text + z)
  {
    dim3 g22(2,2);
    k_mgemm<<<g22,256,0,stream>>>(ctxt_ws, 0, 1, wtop, oproj_b, ybuf, 256, 256, 0, flag);
    k_mgemm<<<g22,256,0,stream>>>(ybuf,    0, 1, wtlo, lvi_out_b, fbuf, 256, 256, 0, flag);
    k_add_ln<<<MTEXT,256,0,stream>>>(fbuf, text_tokens, 0, 0,
                                     t_ws, 0, 1, nullptr, 0, lvi_n1_s, lvi_n1_b, flag);
  }
  // ffn path: h = relu(t@f1+b1) ; f = h@f2+b2 ; tout = LN(t + f)
  {
    dim3 g28(2,8), g22(2,2);
    k_mgemm<<<g28,256,0,stream>>>(t_ws,   0, 1, wtlf1, lvi_f1_b, hbuf_t, 1024, 256, 1, flag);
    k_mgemm<<<g22,256,0,stream>>>(hbuf_t, 0, 1, wtlf2, lvi_f2_b, fbuf,   256, 1024, 0, flag);
    k_add_ln<<<MTEXT,256,0,stream>>>(fbuf, t_ws, 0, 1,
                                     tout_ws, 0, 1, d_out, VISSZ, lvi_n2_s, lvi_n2_b, flag);
  }
  // k/v projection of text_out + bf16 hi/lo split (+ V transpose)
  {
    dim3 g22(2,2);
    k_mgemm<<<g22,256,0,stream>>>(tout_ws, 0, 1, wtk, mha_kb, k_ws, 256, 256, 0, flag);
    k_mgemm<<<g22,256,0,stream>>>(tout_ws, 0, 1, wtv, mha_vb, v_ws, 256, 256, 0, flag);
    k_kvsplit<<<256,256,0,stream>>>(k_ws, v_ws, khi, klo, vthi, vtlo);
  }

  // ---- vis side, chunked by R rows ----
  for (int r0 = 0; r0 < MVIS; r0 += R){
    const int nr = (MVIS - r0 < R) ? (MVIS - r0) : R;   // multiple of 128
    dim3 g2(nr/128, 2), g8(nr/128, 8);
    k_mgemm3<<<g2,256,0,stream>>>(vis_tokens, (size_t)r0*256, 0,
                                  wtq, mha_qb, nullptr, qcH, 256, 256, 0, flag);
    k_attn2<<<nr/64,256,0,stream>>>(qcH, aoH, khi, klo, vthi, vtlo, tmask, r0);
    // o-proj + residual(vis_tokens) + LN1 -> v1H (bf16)
    k_mgemm_ln<<<nr/64,256,0,stream>>>(aoH, wto, mha_ob,
                                       vis_tokens, (size_t)r0*256, 0,
                                       v1H, 0, 1,
                                       vli_n1_s, vli_n1_b, 256, flag);
    k_mgemm3<<<g8,256,0,stream>>>(v1H, 0, 2,
                                  wtf1, vli_f1_b, nullptr, hbH, 1024, 256, 1, flag);
    // f2 + residual(v1H) + LN2 -> d_out (mode-typed)
    k_mgemm_ln<<<nr/64,256,0,stream>>>(hbH, wtf2, vli_f2_b,
                                       v1H, 0, 1,
                                       d_out, (size_t)r0*256, 0,
                                       vli_n2_s, vli_n2_b, 1024, flag);
  }
}

// Round 12
// 881.210 us; speedup vs baseline: 1.2887x; 1.0029x over previous
//
#include <hip/hip_runtime.h>
#include <hip/hip_bf16.h>
#include <math.h>

typedef __hip_bfloat16 bf16;
typedef unsigned short ushort_t;
typedef unsigned int uint_t;
typedef short v8s __attribute__((ext_vector_type(8)));
typedef float v4f __attribute__((ext_vector_type(4)));

#define NVTOK 9072
#define BATCH 8
#define LT 32
#define DMODEL 256
#define NHEAD 8
#define DHEAD 32
#define MVIS (BATCH*NVTOK)   /* 72576 */
#define MTEXT (BATCH*LT)     /* 256 */
#define VISSZ 18579456ull    /* MVIS*256 elements */

__device__ __forceinline__ float bf2f(ushort_t u){ return __uint_as_float(((uint_t)u)<<16); }
__device__ __forceinline__ ushort_t f2bfbits(float f){
  __hip_bfloat16 h = __float2bfloat16(f);
  union { __hip_bfloat16 h; ushort_t u; } c; c.h = h; return c.u;
}
// mode: 0 = buffers hold bf16, 1 = buffers hold fp32
__device__ __forceinline__ float ldin(const void* p, size_t i, int mode){
  return mode ? ((const float*)p)[i] : bf2f(((const ushort_t*)p)[i]);
}
__device__ __forceinline__ void stout(void* p, size_t i, int mode, float v){
  if (mode) ((float*)p)[i] = v; else ((ushort_t*)p)[i] = f2bfbits(v);
}

// async global->LDS, 16 B per lane (LDS dest = wave-uniform base + lane*16).
__device__ __forceinline__ void gload_lds16(const void* g, void* l){
  __builtin_amdgcn_global_load_lds(
      (const __attribute__((address_space(1))) unsigned int*)g,
      (__attribute__((address_space(3))) unsigned int*)l, 16, 0, 0);
}

// ---------------------------------------------------------------------------
// D0: dtype detector (unchanged)
// ---------------------------------------------------------------------------
__global__ void k_detect(const uint_t* __restrict__ buf, int n_avail, int* __restrict__ flag){
  __shared__ int zc, bc;
  if (threadIdx.x==0){ zc=0; bc=0; }
  __syncthreads();
  int stride = n_avail/2048; if (stride < 1) stride = 1;
  int nz=0, nb=0;
  for (int i=threadIdx.x; i<2048; i+=256){
    long long idx = (long long)i*stride;
    if (idx >= n_avail) break;
    uint_t d = buf[idx];
    uint_t lo = d & 0xFFFFu;
    int e = (int)((lo >> 7) & 0xFF);
    if (lo == 0) nz++;
    else if (e >= 90 && e <= 160) nb++;
  }
  atomicAdd(&zc, nz); atomicAdd(&bc, nb);
  __syncthreads();
  if (threadIdx.x==0){
    int mode;
    if (zc > 1024) mode = 1;
    else if (bc > 1228) mode = 0;
    else mode = 1;
    *flag = mode;
  }
}

// ---------------------------------------------------------------------------
// W-transpose (unchanged)
// ---------------------------------------------------------------------------
__global__ __launch_bounds__(256) void k_transpose(
    const void* W, ushort_t* __restrict__ Wt, int K, int N,
    const int* __restrict__ mf)
{
  const int mode = *mf;
  __shared__ float tile[32][33];
  const int k0 = blockIdx.x*32, n0 = blockIdx.y*32;
  const int c = threadIdx.x & 31, r8 = threadIdx.x >> 5;
  #pragma unroll
  for (int i=0;i<4;i++){
    const int kk = r8 + i*8;
    tile[kk][c] = ldin(W, (size_t)(k0+kk)*N + n0 + c, mode);
  }
  __syncthreads();
  #pragma unroll
  for (int i=0;i<4;i++){
    const int nn = r8 + i*8;
    Wt[(size_t)(n0+nn)*K + k0 + c] = f2bfbits(tile[c][nn]);
  }
}

// ---------------------------------------------------------------------------
// T1: text prep (unchanged)
// ---------------------------------------------------------------------------
__global__ __launch_bounds__(256) void k_text_prep(
    const void* text,
    const void* ref_w, const void* ref_b,
    const void* off_w, const void* off_b,
    const void* aw_w,  const void* aw_b,
    float* __restrict__ loc_out, float* __restrict__ aw_out,
    const int* __restrict__ mf)
{
  const int mode = *mf;
  const int r = blockIdx.x;
  const int t = threadIdx.x;
  __shared__ float x[256];
  __shared__ float refv[6];
  __shared__ float offv[192];
  __shared__ float logit[96];
  x[t] = ldin(text, (size_t)r*256 + t, mode);
  __syncthreads();
  if (t < 192) {
    float s = 0.f;
    for (int k=0;k<256;k++) s += x[k]*ldin(off_w, (size_t)k*192+t, mode);
    offv[t] = s + ldin(off_b, t, mode);
  } else if (t < 198) {
    int j = t-192;
    float s = 0.f;
    for (int k=0;k<256;k++) s += x[k]*ldin(ref_w, (size_t)k*6+j, mode);
    s += ldin(ref_b, j, mode);
    refv[j] = 1.f/(1.f+expf(-s));
  }
  if (t < 96) {
    float s = 0.f;
    for (int k=0;k<256;k++) s += x[k]*ldin(aw_w, (size_t)k*96+t, mode);
    logit[t] = s + ldin(aw_b, t, mode);
  }
  __syncthreads();
  if (t < 8) {
    float mx = -1e30f;
    for (int j=0;j<12;j++) mx = fmaxf(mx, logit[t*12+j]);
    float e[12]; float den = 0.f;
    for (int j=0;j<12;j++){ e[j] = expf(logit[t*12+j]-mx); den += e[j]; }
    float inv = 1.f/den;
    for (int j=0;j<12;j++) aw_out[(size_t)r*96 + t*12 + j] = e[j]*inv;
  }
  if (t < 192) {
    int rem = t % 24;
    int l = rem >> 3;
    int c = t & 1;
    const float normW[3] = {96.f,48.f,24.f};
    const float normH[3] = {72.f,36.f,18.f};
    float nrm = (c==0) ? normW[l] : normH[l];
    loc_out[(size_t)r*192 + t] = refv[l*2+c] + offv[t]/nrm;
  }
}

// ---------------------------------------------------------------------------
// T2: deformable sampling, lazy vproj (unchanged)
// ---------------------------------------------------------------------------
__global__ __launch_bounds__(64) void k_deform(
    const void* vis_value, const char* __restrict__ vmask,
    const void* vproj_w, const void* vproj_b,
    const float* __restrict__ loc, const float* __restrict__ aw,
    float* __restrict__ ctx_out, const int* __restrict__ mf)
{
  const int mode = *mf;
  const int blk = blockIdx.x;      // r*8 + h
  const int r = blk >> 3;
  const int h = blk & 7;
  const int b = r >> 5;
  const int t = threadIdx.x;
  const int Hs[3] = {72,36,18};
  const int Wsz[3] = {96,48,24};
  const int stl[3] = {0,6912,8640};
  float s0=0.f,s1=0.f,s2=0.f,s3=0.f, wsum=0.f;
  for (int l=0;l<3;l++){
    for (int p=0;p<4;p++){
      const int sIdx = blk*12 + l*4 + p;
      const float a  = aw[sIdx];
      const float X = loc[sIdx*2+0]*(float)Wsz[l] - 0.5f;
      const float Y = loc[sIdx*2+1]*(float)Hs[l] - 0.5f;
      const float x0f = floorf(X), y0f = floorf(Y);
      const int x0 = (int)x0f, y0 = (int)y0f;
      const float wx = X-x0f, wy = Y-y0f;
      const float cw[4] = {(1.f-wx)*(1.f-wy), wx*(1.f-wy), (1.f-wx)*wy, wx*wy};
      const int cx[4] = {x0,x0+1,x0,x0+1};
      const int cy[4] = {y0,y0,y0+1,y0+1};
      for (int c=0;c<4;c++){
        if (cx[c]>=0 && cx[c]<Wsz[l] && cy[c]>=0 && cy[c]<Hs[l]){
          const size_t pos = (size_t)b*NVTOK + stl[l] + cy[c]*Wsz[l] + cx[c];
          if (vmask[pos]) continue;
          const float w = a*cw[c];
          wsum += w;
          const size_t base = pos*256 + t*4;
          s0 += w*ldin(vis_value, base+0, mode);
          s1 += w*ldin(vis_value, base+1, mode);
          s2 += w*ldin(vis_value, base+2, mode);
          s3 += w*ldin(vis_value, base+3, mode);
        }
      }
    }
  }
  __shared__ float sh[256];
  sh[t*4+0]=s0; sh[t*4+1]=s1; sh[t*4+2]=s2; sh[t*4+3]=s3;
  __syncthreads();
  if (t < 32) {
    const int col = h*32 + t;
    float acc = wsum * ldin(vproj_b, col, mode);
    for (int k=0;k<256;k++) acc += sh[k]*ldin(vproj_w, (size_t)k*256+col, mode);
    ctx_out[(size_t)r*256 + col] = acc;
  }
}

__device__ __forceinline__ float block_sum(float v, float* red){
  float sm = v;
  #pragma unroll
  for (int o=32;o>0;o>>=1) sm += __shfl_down(sm,o);
  const int t = threadIdx.x;
  __syncthreads();
  if ((t&63)==0) red[t>>6] = sm;
  __syncthreads();
  return red[0]+red[1]+red[2]+red[3];
}

// ---------------------------------------------------------------------------
// MFMA GEMM (text side, unchanged — tiny M, full hi/lo precision)
// ---------------------------------------------------------------------------
__global__ __launch_bounds__(256) void k_mgemm(
    const void* A, size_t a_off, int a_kind,
    const ushort_t* __restrict__ Wt, const void* bias, float* __restrict__ C,
    int N, int K, int relu, const int* __restrict__ mf)
{
  const int mode = *mf;
  const int split = (a_kind==1) || (mode==1);
  __shared__ ushort_t Ah[128*32];
  __shared__ ushort_t Al[128*32];
  __shared__ ushort_t Bt[128*32];
  const int tid = threadIdx.x;
  const int gm0 = blockIdx.x*128, gn0 = blockIdx.y*128;
  const int wv = tid>>6, lane = tid&63;
  const int mh = (wv&1)*64, nh = (wv>>1)*64;
  const int r16 = lane&15, q8 = (lane>>4)*8;
  const int srow = tid>>1, sseg = (tid&1)*16;
  v4f acc[4][4];
  #pragma unroll
  for (int i=0;i<4;i++)
    #pragma unroll
    for (int j=0;j<4;j++) acc[i][j] = (v4f){0.f,0.f,0.f,0.f};

  for (int k0=0; k0<K; k0+=32){
    if (k0) __syncthreads();
    {
      const ushort_t* src = Wt + (size_t)(gn0+srow)*K + k0 + sseg;
      ((uint4*)&Bt[srow*32+sseg])[0]   = ((const uint4*)src)[0];
      ((uint4*)&Bt[srow*32+sseg+8])[0] = ((const uint4*)src)[1];
    }
    if (!split){
      const ushort_t* src = (const ushort_t*)A + a_off + (size_t)(gm0+srow)*K + k0 + sseg;
      ((uint4*)&Ah[srow*32+sseg])[0]   = ((const uint4*)src)[0];
      ((uint4*)&Ah[srow*32+sseg+8])[0] = ((const uint4*)src)[1];
    } else {
      const float* src = (const float*)A + a_off + (size_t)(gm0+srow)*K + k0 + sseg;
      #pragma unroll
      for (int v=0;v<4;v++){
        float4 f = ((const float4*)src)[v];
        float xs[4] = {f.x, f.y, f.z, f.w};
        #pragma unroll
        for (int e=0;e<4;e++){
          const int idx = srow*32 + sseg + v*4 + e;
          const ushort_t h = f2bfbits(xs[e]);
          Ah[idx] = h;
          Al[idx] = f2bfbits(xs[e] - bf2f(h));
        }
      }
    }
    __syncthreads();
    v8s af[4], bfr[4], al[4];
    #pragma unroll
    for (int mt=0;mt<4;mt++){
      af[mt] = *(const v8s*)&Ah[(mh + mt*16 + r16)*32 + q8];
      if (split) al[mt] = *(const v8s*)&Al[(mh + mt*16 + r16)*32 + q8];
    }
    #pragma unroll
    for (int nt=0;nt<4;nt++)
      bfr[nt] = *(const v8s*)&Bt[(nh + nt*16 + r16)*32 + q8];
    #pragma unroll
    for (int mt=0;mt<4;mt++){
      #pragma unroll
      for (int nt=0;nt<4;nt++){
        acc[mt][nt] = __builtin_amdgcn_mfma_f32_16x16x32_bf16(af[mt], bfr[nt], acc[mt][nt], 0, 0, 0);
        if (split)
          acc[mt][nt] = __builtin_amdgcn_mfma_f32_16x16x32_bf16(al[mt], bfr[nt], acc[mt][nt], 0, 0, 0);
      }
    }
  }
  const int rq = (lane>>4)*4;
  float bv[4];
  #pragma unroll
  for (int nt=0;nt<4;nt++) bv[nt] = ldin(bias, gn0 + nh + nt*16 + r16, mode);
  #pragma unroll
  for (int mt=0;mt<4;mt++){
    #pragma unroll
    for (int r=0;r<4;r++){
      const size_t ro = (size_t)(gm0 + mh + mt*16 + rq + r)*N + gn0 + nh + r16;
      #pragma unroll
      for (int nt=0;nt<4;nt++){
        float v = acc[mt][nt][r] + bv[nt];
        if (relu) v = fmaxf(v, 0.f);
        C[ro + nt*16] = v;
      }
    }
  }
}

// ---------------------------------------------------------------------------
// V3 MFMA GEMM (vis q-proj / f1 / f2): 128x128 tile, single-pass bf16
// activations, gload_lds16 staging, XCD-bijective swizzle (best measured:
// f1/f2 ~85 us at MfmaUtil 18%). Output fp32 or bf16.
// ---------------------------------------------------------------------------
__global__ __launch_bounds__(256) void k_mgemm3(
    const void* A, size_t a_off, int a_kind,
    const ushort_t* __restrict__ Wt, const void* bias,
    float* __restrict__ Cf, ushort_t* __restrict__ Chi,
    int N, int K, int relu, const int* __restrict__ mf)
{
  const int mode = *mf;
  const int rawf32 = (a_kind==0) && (mode==1);
  __shared__ ushort_t Ah[128*32];
  __shared__ ushort_t Bt[128*32];
  const int tid = threadIdx.x;
  const int nbx = gridDim.x, nby = gridDim.y;
  const int total = nbx*nby;
  const int f = blockIdx.y*nbx + blockIdx.x;
  const int qq = total>>3, rr = total&7;
  const int xcd = f&7, pos = f>>3;
  const int wg = (xcd<rr ? xcd*(qq+1) : rr*(qq+1) + (xcd-rr)*qq) + pos;
  const int gm0 = (wg / nby)*128, gn0 = (wg % nby)*128;

  const int wv = tid>>6, lane = tid&63;
  const int mh = (wv&1)*64, nh = (wv>>1)*64;
  const int r16 = lane&15, q8 = (lane>>4)*8;
  const int grow = tid>>2;
  const int gcol = (tid&3)*8;
  const int srow = tid>>1, sseg = (tid&1)*16;
  const ushort_t* Abf = (const ushort_t*)A + a_off;
  v4f acc[4][4];
  #pragma unroll
  for (int i=0;i<4;i++)
    #pragma unroll
    for (int j=0;j<4;j++) acc[i][j] = (v4f){0.f,0.f,0.f,0.f};

  for (int k0=0; k0<K; k0+=32){
    if (k0) __syncthreads();
    gload_lds16(Wt + (size_t)(gn0+grow)*K    + k0 + gcol, &Bt[grow*32      + gcol]);
    gload_lds16(Wt + (size_t)(gn0+grow+64)*K + k0 + gcol, &Bt[(grow+64)*32 + gcol]);
    if (!rawf32){
      gload_lds16(Abf + (size_t)(gm0+grow)*K    + k0 + gcol, &Ah[grow*32      + gcol]);
      gload_lds16(Abf + (size_t)(gm0+grow+64)*K + k0 + gcol, &Ah[(grow+64)*32 + gcol]);
    } else {
      const float* src = (const float*)A + a_off + (size_t)(gm0+srow)*K + k0 + sseg;
      #pragma unroll
      for (int v=0;v<4;v++){
        float4 fq = ((const float4*)src)[v];
        float xs[4] = {fq.x, fq.y, fq.z, fq.w};
        #pragma unroll
        for (int e=0;e<4;e++)
          Ah[srow*32 + sseg + v*4 + e] = f2bfbits(xs[e]);
      }
    }
    __syncthreads();
    v8s af[4], bfr[4];
    #pragma unroll
    for (int mt=0;mt<4;mt++)
      af[mt] = *(const v8s*)&Ah[(mh + mt*16 + r16)*32 + q8];
    #pragma unroll
    for (int nt=0;nt<4;nt++)
      bfr[nt] = *(const v8s*)&Bt[(nh + nt*16 + r16)*32 + q8];
    #pragma unroll
    for (int mt=0;mt<4;mt++){
      #pragma unroll
      for (int nt=0;nt<4;nt++)
        acc[mt][nt] = __builtin_amdgcn_mfma_f32_16x16x32_bf16(af[mt], bfr[nt], acc[mt][nt], 0, 0, 0);
    }
  }
  const int rq = (lane>>4)*4;
  float bv[4];
  #pragma unroll
  for (int nt=0;nt<4;nt++) bv[nt] = ldin(bias, gn0 + nh + nt*16 + r16, mode);
  const int outf = (Cf != nullptr);
  #pragma unroll
  for (int mt=0;mt<4;mt++){
    #pragma unroll
    for (int r=0;r<4;r++){
      const size_t ro = (size_t)(gm0 + mh + mt*16 + rq + r)*N + gn0 + nh + r16;
      #pragma unroll
      for (int nt=0;nt<4;nt++){
        float v = acc[mt][nt][r] + bv[nt];
        if (relu) v = fmaxf(v, 0.f);
        if (outf) Cf[ro + nt*16] = v;
        else      Chi[ro + nt*16] = f2bfbits(v);
      }
    }
  }
}

// ---------------------------------------------------------------------------
// GEMM + residual + LayerNorm fused — kept ONLY for o-proj (K=256; 8
// K-steps so the per-step vmcnt drain is amortizable). 64 rows x 256 cols,
// 256 thr = 4 waves. f2 (K=1024) measured 182-204 us in this structure —
// latency-bound (32 serial drain phases) — so f2 stays unfused.
// ---------------------------------------------------------------------------
__global__ __launch_bounds__(256) void k_mgemm_ln(
    const ushort_t* __restrict__ A,
    const ushort_t* __restrict__ Wt, const void* bias,
    const void* RES, size_t res_off, int res_bf16,
    void* OUT, size_t out_off, int out_bf16,
    const void* g, const void* be,
    int K, const int* __restrict__ mf)
{
  const int mode = *mf;
  __shared__ ushort_t Ah[64*32];
  __shared__ ushort_t Bt[256*32];
  __shared__ float rsum[4][64];
  __shared__ float rsq[4][64];
  const int tid = threadIdx.x;
  const int gm0 = blockIdx.x*64;
  const int wv = tid>>6, lane = tid&63;
  const int nh = wv*64;
  const int r16 = lane&15, kq = lane>>4, q8 = kq*8;
  const int grow = tid>>2, gcol = (tid&3)*8;
  v4f acc[4][4];
  #pragma unroll
  for (int i=0;i<4;i++)
    #pragma unroll
    for (int j=0;j<4;j++) acc[i][j] = (v4f){0.f,0.f,0.f,0.f};

  for (int k0=0; k0<K; k0+=32){
    if (k0) __syncthreads();
    gload_lds16(A  + (size_t)(gm0+grow)*K  + k0 + gcol, &Ah[grow*32 + gcol]);
    gload_lds16(Wt + (size_t)grow*K        + k0 + gcol, &Bt[grow*32 + gcol]);
    gload_lds16(Wt + (size_t)(64+grow)*K   + k0 + gcol, &Bt[(64+grow)*32 + gcol]);
    gload_lds16(Wt + (size_t)(128+grow)*K  + k0 + gcol, &Bt[(128+grow)*32 + gcol]);
    gload_lds16(Wt + (size_t)(192+grow)*K  + k0 + gcol, &Bt[(192+grow)*32 + gcol]);
    __syncthreads();
    v8s af[4], bfr[4];
    #pragma unroll
    for (int mt=0;mt<4;mt++)
      af[mt] = *(const v8s*)&Ah[(mt*16 + r16)*32 + q8];
    #pragma unroll
    for (int nt=0;nt<4;nt++)
      bfr[nt] = *(const v8s*)&Bt[(nh + nt*16 + r16)*32 + q8];
    #pragma unroll
    for (int mt=0;mt<4;mt++){
      #pragma unroll
      for (int nt=0;nt<4;nt++)
        acc[mt][nt] = __builtin_amdgcn_mfma_f32_16x16x32_bf16(af[mt], bfr[nt], acc[mt][nt], 0, 0, 0);
    }
  }
  // ---- z = acc + bias + residual (in place) ----
  float bv[4];
  #pragma unroll
  for (int nt=0;nt<4;nt++) bv[nt] = ldin(bias, nh + nt*16 + r16, mode);
  #pragma unroll
  for (int mt=0;mt<4;mt++){
    #pragma unroll
    for (int r=0;r<4;r++){
      const int row_l = mt*16 + kq*4 + r;
      const size_t rbase = (size_t)(gm0 + row_l)*256;
      #pragma unroll
      for (int nt=0;nt<4;nt++){
        const int col = nh + nt*16 + r16;
        const float rv = res_bf16 ? bf2f(((const ushort_t*)RES)[res_off + rbase + col])
                                  : ldin(RES, res_off + rbase + col, mode);
        acc[mt][nt][r] = acc[mt][nt][r] + bv[nt] + rv;
      }
    }
  }
  // ---- pass 1: row sums -> mean ----
  #pragma unroll
  for (int mt=0;mt<4;mt++){
    #pragma unroll
    for (int r=0;r<4;r++){
      float s = acc[mt][0][r] + acc[mt][1][r] + acc[mt][2][r] + acc[mt][3][r];
      #pragma unroll
      for (int o=1;o<16;o<<=1) s += __shfl_xor(s, o);
      if (r16==0) rsum[wv][mt*16 + kq*4 + r] = s;
    }
  }
  __syncthreads();
  float mean[4][4];
  #pragma unroll
  for (int mt=0;mt<4;mt++){
    #pragma unroll
    for (int r=0;r<4;r++){
      const int row_l = mt*16 + kq*4 + r;
      mean[mt][r] = (rsum[0][row_l]+rsum[1][row_l]+rsum[2][row_l]+rsum[3][row_l]) * (1.f/256.f);
    }
  }
  // ---- pass 2: row sumsq of (z-mean) -> var ----
  #pragma unroll
  for (int mt=0;mt<4;mt++){
    #pragma unroll
    for (int r=0;r<4;r++){
      const float m = mean[mt][r];
      float s2 = 0.f;
      #pragma unroll
      for (int nt=0;nt<4;nt++){ const float d = acc[mt][nt][r]-m; s2 += d*d; }
      #pragma unroll
      for (int o=1;o<16;o<<=1) s2 += __shfl_xor(s2, o);
      if (r16==0) rsq[wv][mt*16 + kq*4 + r] = s2;
    }
  }
  __syncthreads();
  // ---- normalize + affine + write ----
  float gv[4], bev[4];
  #pragma unroll
  for (int nt=0;nt<4;nt++){
    gv[nt]  = ldin(g,  nh + nt*16 + r16, mode);
    bev[nt] = ldin(be, nh + nt*16 + r16, mode);
  }
  #pragma unroll
  for (int mt=0;mt<4;mt++){
    #pragma unroll
    for (int r=0;r<4;r++){
      const int row_l = mt*16 + kq*4 + r;
      const float var = (rsq[0][row_l]+rsq[1][row_l]+rsq[2][row_l]+rsq[3][row_l]) * (1.f/256.f);
      const float inv = rsqrtf(var + 1e-5f);
      const float m = mean[mt][r];
      const size_t obase = (size_t)(gm0 + row_l)*256;
      #pragma unroll
      for (int nt=0;nt<4;nt++){
        const int col = nh + nt*16 + r16;
        const float o = (acc[mt][nt][r]-m)*inv*gv[nt] + bev[nt];
        if (out_bf16) ((ushort_t*)OUT)[obase + col] = f2bfbits(o);
        else          stout(OUT, out_off + obase + col, mode, o);
      }
    }
  }
}

// ---------------------------------------------------------------------------
// KV split/transpose prep (unchanged)
// ---------------------------------------------------------------------------
__global__ __launch_bounds__(256) void k_kvsplit(
    const float* __restrict__ kws, const float* __restrict__ vws,
    ushort_t* __restrict__ khi, ushort_t* __restrict__ klo,
    ushort_t* __restrict__ vthi, ushort_t* __restrict__ vtlo)
{
  const int row = blockIdx.x;        // 0..255 = b*32 + key
  const int b = row >> 5, key = row & 31;
  const int t = threadIdx.x;         // dim 0..255
  const float f = kws[(size_t)row*256 + t];
  const ushort_t fh = f2bfbits(f);
  khi[(size_t)row*256 + t] = fh;
  klo[(size_t)row*256 + t] = f2bfbits(f - bf2f(fh));
  const float g = vws[(size_t)row*256 + t];
  const ushort_t gh = f2bfbits(g);
  const size_t vt = ((size_t)b*256 + t)*32 + key;
  vthi[vt] = gh;
  vtlo[vt] = f2bfbits(g - bf2f(gh));
}

// ---------------------------------------------------------------------------
// A2: MFMA MHA (unchanged)
// ---------------------------------------------------------------------------
__global__ __launch_bounds__(256) void k_attn2(
    const ushort_t* __restrict__ qcH,
    ushort_t* __restrict__ aoh,
    const ushort_t* __restrict__ khi, const ushort_t* __restrict__ klo,
    const ushort_t* __restrict__ vthi, const ushort_t* __restrict__ vtlo,
    const char* __restrict__ tmask, int r0)
{
  __shared__ float P[4][16][36];
  const int tid = threadIdx.x;
  const int wv = tid>>6, lane = tid&63;
  const int lrow0 = blockIdx.x*64 + wv*16;
  const int b = (r0 + lrow0)/NVTOK;
  const int m16 = lane&15;
  const int kq = lane>>4;
  const int q8 = kq*8;
  const int key0 = m16, key1 = m16+16;
  const bool msk0 = tmask[b*LT + key0] != 0;
  const bool msk1 = tmask[b*LT + key1] != 0;
  const float scale = 0.17677669529663687f;

  for (int h=0; h<8; ++h){
    const size_t qoff = (size_t)(lrow0 + m16)*256 + h*32 + q8;
    const v8s qh = *(const v8s*)&qcH[qoff];
    const size_t kb0 = ((size_t)(b*32+key0)*256) + h*32 + q8;
    const size_t kb1 = ((size_t)(b*32+key1)*256) + h*32 + q8;
    const v8s kh0 = *(const v8s*)&khi[kb0];
    const v8s kl0 = *(const v8s*)&klo[kb0];
    const v8s kh1 = *(const v8s*)&khi[kb1];
    const v8s kl1 = *(const v8s*)&klo[kb1];
    v4f s0 = (v4f){0.f,0.f,0.f,0.f}, s1 = (v4f){0.f,0.f,0.f,0.f};
    s0 = __builtin_amdgcn_mfma_f32_16x16x32_bf16(qh, kh0, s0, 0,0,0);
    s0 = __builtin_amdgcn_mfma_f32_16x16x32_bf16(qh, kl0, s0, 0,0,0);
    s1 = __builtin_amdgcn_mfma_f32_16x16x32_bf16(qh, kh1, s1, 0,0,0);
    s1 = __builtin_amdgcn_mfma_f32_16x16x32_bf16(qh, kl1, s1, 0,0,0);
    float e0[4], e1[4], inv[4];
    #pragma unroll
    for (int r=0;r<4;r++){
      const float a0 = msk0 ? -1e9f : s0[r]*scale;
      const float a1 = msk1 ? -1e9f : s1[r]*scale;
      float mx = fmaxf(a0,a1);
      #pragma unroll
      for (int o=1;o<16;o<<=1) mx = fmaxf(mx, __shfl_xor(mx,o));
      const float x0 = __expf(a0-mx), x1 = __expf(a1-mx);
      float dn = x0+x1;
      #pragma unroll
      for (int o=1;o<16;o<<=1) dn += __shfl_xor(dn,o);
      e0[r]=x0; e1[r]=x1; inv[r] = 1.f/dn;
    }
    #pragma unroll
    for (int r=0;r<4;r++){
      P[wv][kq*4+r][key0] = e0[r];
      P[wv][kq*4+r][key1] = e1[r];
    }
    __syncthreads();
    float pv[8];
    *(float4*)&pv[0] = *(const float4*)&P[wv][m16][q8];
    *(float4*)&pv[4] = *(const float4*)&P[wv][m16][q8+4];
    v8s ph;
    #pragma unroll
    for (int j=0;j<8;j++) ph[j] = (short)f2bfbits(pv[j]);
    const size_t vb0 = ((size_t)(b*256 + h*32 + m16)*32) + q8;
    const size_t vb1 = ((size_t)(b*256 + h*32 + 16 + m16)*32) + q8;
    const v8s vh0 = *(const v8s*)&vthi[vb0];
    const v8s vl0 = *(const v8s*)&vtlo[vb0];
    const v8s vh1 = *(const v8s*)&vthi[vb1];
    const v8s vl1 = *(const v8s*)&vtlo[vb1];
    v4f o0 = (v4f){0.f,0.f,0.f,0.f}, o1 = (v4f){0.f,0.f,0.f,0.f};
    o0 = __builtin_amdgcn_mfma_f32_16x16x32_bf16(ph, vh0, o0, 0,0,0);
    o0 = __builtin_amdgcn_mfma_f32_16x16x32_bf16(ph, vl0, o0, 0,0,0);
    o1 = __builtin_amdgcn_mfma_f32_16x16x32_bf16(ph, vh1, o1, 0,0,0);
    o1 = __builtin_amdgcn_mfma_f32_16x16x32_bf16(ph, vl1, o1, 0,0,0);
    __syncthreads();
    #pragma unroll
    for (int r=0;r<4;r++){
      const size_t ro = (size_t)(lrow0 + kq*4 + r)*256 + h*32;
      aoh[ro + m16]      = f2bfbits(o0[r]*inv[r]);
      aoh[ro + 16 + m16] = f2bfbits(o1[r]*inv[r]);
    }
  }
}

// ---------------------------------------------------------------------------
// residual + two-pass LayerNorm (text side, unchanged)
// ---------------------------------------------------------------------------
__global__ __launch_bounds__(256) void k_add_ln(
    const float* __restrict__ X, const void* R, size_t r_off, int r_f32,
    void* OUT, size_t o_off, int o_f32,
    void* OUT2, size_t o2_off,
    const void* g, const void* be, const int* __restrict__ mf)
{
  const int mode = *mf;
  const int row = blockIdx.x; const int t = threadIdx.x;
  const size_t idx = (size_t)row*256 + t;
  __shared__ float red[4];
  const float rv = r_f32 ? ((const float*)R)[r_off+idx] : ldin(R, r_off+idx, mode);
  const float v = X[idx] + rv;
  const float m = block_sum(v, red) * (1.f/256.f);
  __syncthreads();
  const float d = v - m;
  const float var = block_sum(d*d, red) * (1.f/256.f);
  const float o = d*rsqrtf(var+1e-5f)*ldin(g,t,mode) + ldin(be,t,mode);
  if (o_f32) ((float*)OUT)[o_off+idx] = o;
  else       stout(OUT, o_off+idx, mode, o);
  if (OUT2)  stout(OUT2, o2_off+idx, mode, o);
}

// ---------------------------------------------------------------------------
// LN2 (vis): v = X + RH ; out = mode-typed at offset
// ---------------------------------------------------------------------------
__global__ __launch_bounds__(256) void k_add_ln_pres(
    const float* __restrict__ X,
    const ushort_t* __restrict__ RH,
    void* OUT, size_t o_off,
    const void* g, const void* be, const int* __restrict__ mf)
{
  const int mode = *mf;
  const int row = blockIdx.x; const int t = threadIdx.x;
  const size_t idx = (size_t)row*256 + t;
  __shared__ float red[4];
  const float rv = bf2f(RH[idx]);
  const float v = X[idx] + rv;
  const float m = block_sum(v, red) * (1.f/256.f);
  __syncthreads();
  const float d = v - m;
  const float var = block_sum(d*d, red) * (1.f/256.f);
  const float o = d*rsqrtf(var+1e-5f)*ldin(g,t,mode) + ldin(be,t,mode);
  stout(OUT, o_off+idx, mode, o);
}

// ---------------------------------------------------------------------------
extern "C" void kernel_launch(void* const* d_in, const int* in_sizes, int n_in,
                              void* d_out, int out_size, void* d_ws, size_t ws_size,
                              hipStream_t stream)
{
  (void)n_in; (void)out_size;
  const void* vis_tokens = d_in[0];
  const void* text_tokens= d_in[1];
  const void* vis_value  = d_in[2];
  const void* ref_w = d_in[3];  const void* ref_b = d_in[4];
  const void* off_w = d_in[5];  const void* off_b = d_in[6];
  const void* aw_w  = d_in[7];  const void* aw_b  = d_in[8];
  const void* vproj_w = d_in[9];  const void* vproj_b = d_in[10];
  const void* oproj_w = d_in[11]; const void* oproj_b = d_in[12];
  const void* lvi_out_w = d_in[13]; const void* lvi_out_b = d_in[14];
  const void* lvi_n1_s = d_in[15];  const void* lvi_n1_b = d_in[16];
  const void* lvi_f1_w = d_in[17];  const void* lvi_f1_b = d_in[18];
  const void* lvi_f2_w = d_in[19];  const void* lvi_f2_b = d_in[20];
  const void* lvi_n2_s = d_in[21];  const void* lvi_n2_b = d_in[22];
  const void* mha_qw = d_in[23]; const void* mha_qb = d_in[24];
  const void* mha_kw = d_in[25]; const void* mha_kb = d_in[26];
  const void* mha_vw = d_in[27]; const void* mha_vb = d_in[28];
  const void* mha_ow = d_in[29]; const void* mha_ob = d_in[30];
  const void* vli_out_w = d_in[31]; const void* vli_out_b = d_in[32];
  const void* vli_n1_s = d_in[33];  const void* vli_n1_b = d_in[34];
  const void* vli_f1_w = d_in[35];  const void* vli_f1_b = d_in[36];
  const void* vli_f2_w = d_in[37];  const void* vli_f2_b = d_in[38];
  const void* vli_n2_s = d_in[39];  const void* vli_n2_b = d_in[40];
  const char* tmask = (const char*)d_in[43];
  const char* vmask = (const char*)d_in[44];

  // ---- workspace layout ----
  char* ws = (char*)d_ws;
  int*   flag    = (int*)  (ws + 0);               // 256 B
  float* loc_ws  = (float*)(ws + 256);             // 196608
  float* aw_ws   = (float*)(ws + 196864);          //  98304
  float* ctxt_ws = (float*)(ws + 295168);          // 262144
  float* t_ws    = (float*)(ws + 557312);          // 262144
  float* tout_ws = (float*)(ws + 819456);          // 262144
  float* k_ws    = (float*)(ws + 1081600);         // 262144
  float* v_ws    = (float*)(ws + 1343744);         // 262144
  ushort_t* wtq  = (ushort_t*)(ws + 1605888ull);   // 131072 B
  ushort_t* wto  = (ushort_t*)(ws + 1736960ull);   // 131072 B
  ushort_t* wtf1 = (ushort_t*)(ws + 1868032ull);   // 524288 B
  ushort_t* wtf2 = (ushort_t*)(ws + 2392320ull);   // 524288 B
  ushort_t* wtk   = (ushort_t*)(ws + 2916608ull);  // 131072 B (mha_kw^T)
  ushort_t* wtv   = (ushort_t*)(ws + 3047680ull);  // 131072 B (mha_vw^T)
  ushort_t* wtop  = (ushort_t*)(ws + 3178752ull);  // 131072 B (oproj_w^T)
  ushort_t* wtlo  = (ushort_t*)(ws + 3309824ull);  // 131072 B (lvi_out_w^T)
  ushort_t* wtlf1 = (ushort_t*)(ws + 3440896ull);  // 524288 B (lvi_f1_w^T)
  ushort_t* wtlf2 = (ushort_t*)(ws + 3965184ull);  // 524288 B (lvi_f2_w^T)
  float* hbuf_t   = (float*)(ws + 4489472ull);     // 1048576 B (256x1024)
  float* ybuf     = (float*)(ws + 5538048ull);     // 262144 B
  float* fbuf     = (float*)(ws + 5800192ull);     // 262144 B
  ushort_t* khi   = (ushort_t*)(ws + 6062336ull);  // 131072 B
  ushort_t* klo   = (ushort_t*)(ws + 6193408ull);  // 131072 B
  ushort_t* vthi  = (ushort_t*)(ws + 6324480ull);  // 131072 B
  ushort_t* vtlo  = (ushort_t*)(ws + 6455552ull);  // 131072 B
  const size_t fe = 6586624ull;                    // chunk region start

  // per-row chunk bytes (3584 B/row):
  //   region0 (1024 B): ubuf fp32 (f2 out); first 512 B alias qc bf16
  //   region1 ( 512 B): v1 bf16
  //   region2 (2048 B): hb bf16; first 512 B alias ao bf16 (dead pre-f1)
  long long R_ll = 128;
  if (ws_size > fe) R_ll = (long long)((ws_size - fe) / 3584ull);
  if (R_ll > (long long)MVIS) R_ll = MVIS;
  R_ll &= ~127LL;
  if (R_ll < 128) R_ll = 128;
  const int R = (int)R_ll;
  ushort_t* qcH  = (ushort_t*)(ws + fe);                      // region0 alias
  float*    ubuf = (float*)   (ws + fe);                      // region0
  ushort_t* v1H  = (ushort_t*)(ws + fe + (size_t)R*1024ull);  // region1
  ushort_t* hbH  = (ushort_t*)(ws + fe + (size_t)R*1536ull);  // region2
  ushort_t* aoH  = hbH;                                       // alias (dead pre-f1)

  // ---- dtype detect ----
  int ndw = in_sizes[1]/2; if (ndw < 1) ndw = 1;
  k_detect<<<1,256,0,stream>>>((const uint_t*)text_tokens, ndw, flag);

  // ---- weight transposes for MFMA GEMMs ----
  k_transpose<<<dim3(8,8),  256,0,stream>>>(mha_qw,    wtq,   256, 256,  flag);
  k_transpose<<<dim3(8,8),  256,0,stream>>>(mha_ow,    wto,   256, 256,  flag);
  k_transpose<<<dim3(8,32), 256,0,stream>>>(vli_f1_w,  wtf1,  256, 1024, flag);
  k_transpose<<<dim3(32,8), 256,0,stream>>>(vli_f2_w,  wtf2,  1024, 256, flag);
  k_transpose<<<dim3(8,8),  256,0,stream>>>(mha_kw,    wtk,   256, 256,  flag);
  k_transpose<<<dim3(8,8),  256,0,stream>>>(mha_vw,    wtv,   256, 256,  flag);
  k_transpose<<<dim3(8,8),  256,0,stream>>>(oproj_w,   wtop,  256, 256,  flag);
  k_transpose<<<dim3(8,8),  256,0,stream>>>(lvi_out_w, wtlo,  256, 256,  flag);
  k_transpose<<<dim3(8,32), 256,0,stream>>>(lvi_f1_w,  wtlf1, 256, 1024, flag);
  k_transpose<<<dim3(32,8), 256,0,stream>>>(lvi_f2_w,  wtlf2, 1024, 256, flag);

  // ---- text side ----
  k_text_prep<<<MTEXT,256,0,stream>>>(text_tokens, ref_w, ref_b, off_w, off_b,
                                      aw_w, aw_b, loc_ws, aw_ws, flag);
  k_deform<<<MTEXT*NHEAD,64,0,stream>>>(vis_value, vmask, vproj_w, vproj_b,
                                        loc_ws, aw_ws, ctxt_ws, flag);

  // attn-out path: y = ctx@oproj + b ; z = y@lvi_out + b ; t = LN(text + z)
  {
    dim3 g22(2,2);
    k_mgemm<<<g22,256,0,stream>>>(ctxt_ws, 0, 1, wtop, oproj_b, ybuf, 256, 256, 0, flag);
    k_mgemm<<<g22,256,0,stream>>>(ybuf,    0, 1, wtlo, lvi_out_b, fbuf, 256, 256, 0, flag);
    k_add_ln<<<MTEXT,256,0,stream>>>(fbuf, text_tokens, 0, 0,
                                     t_ws, 0, 1, nullptr, 0, lvi_n1_s, lvi_n1_b, flag);
  }
  // ffn path: h = relu(t@f1+b1) ; f = h@f2+b2 ; tout = LN(t + f)
  {
    dim3 g28(2,8), g22(2,2);
    k_mgemm<<<g28,256,0,stream>>>(t_ws,   0, 1, wtlf1, lvi_f1_b, hbuf_t, 1024, 256, 1, flag);
    k_mgemm<<<g22,256,0,stream>>>(hbuf_t, 0, 1, wtlf2, lvi_f2_b, fbuf,   256, 1024, 0, flag);
    k_add_ln<<<MTEXT,256,0,stream>>>(fbuf, t_ws, 0, 1,
                                     tout_ws, 0, 1, d_out, VISSZ, lvi_n2_s, lvi_n2_b, flag);
  }
  // k/v projection of text_out + bf16 hi/lo split (+ V transpose)
  {
    dim3 g22(2,2);
    k_mgemm<<<g22,256,0,stream>>>(tout_ws, 0, 1, wtk, mha_kb, k_ws, 256, 256, 0, flag);
    k_mgemm<<<g22,256,0,stream>>>(tout_ws, 0, 1, wtv, mha_vb, v_ws, 256, 256, 0, flag);
    k_kvsplit<<<256,256,0,stream>>>(k_ws, v_ws, khi, klo, vthi, vtlo);
  }

  // ---- vis side, chunked by R rows ----
  for (int r0 = 0; r0 < MVIS; r0 += R){
    const int nr = (MVIS - r0 < R) ? (MVIS - r0) : R;   // multiple of 128
    dim3 g2(nr/128, 2), g8(nr/128, 8);
    k_mgemm3<<<g2,256,0,stream>>>(vis_tokens, (size_t)r0*256, 0,
                                  wtq, mha_qb, nullptr, qcH, 256, 256, 0, flag);
    k_attn2<<<nr/64,256,0,stream>>>(qcH, aoH, khi, klo, vthi, vtlo, tmask, r0);
    // o-proj + residual(vis_tokens) + LN1 -> v1H (bf16)  [K=256: fused OK]
    k_mgemm_ln<<<nr/64,256,0,stream>>>(aoH, wto, mha_ob,
                                       vis_tokens, (size_t)r0*256, 0,
                                       v1H, 0, 1,
                                       vli_n1_s, vli_n1_b, 256, flag);
    k_mgemm3<<<g8,256,0,stream>>>(v1H, 0, 2,
                                  wtf1, vli_f1_b, nullptr, hbH, 1024, 256, 1, flag);
    // f2 unfused (proven 128x128 N-split path) -> ubuf fp32
    k_mgemm3<<<g2,256,0,stream>>>(hbH, 0, 2,
                                  wtf2, vli_f2_b, ubuf, nullptr, 256, 1024, 0, flag);
    // LN2: ubuf + v1H -> d_out
    k_add_ln_pres<<<nr,256,0,stream>>>(ubuf, v1H,
                                       d_out, (size_t)r0*256, vli_n2_s, vli_n2_b, flag);
  }
}

// Round 13
// 868.355 us; speedup vs baseline: 1.3078x; 1.0148x over previous
//
#include <hip/hip_runtime.h>
#include <hip/hip_bf16.h>
#include <math.h>

typedef __hip_bfloat16 bf16;
typedef unsigned short ushort_t;
typedef unsigned int uint_t;
typedef short v8s __attribute__((ext_vector_type(8)));
typedef float v4f __attribute__((ext_vector_type(4)));

#define NVTOK 9072
#define BATCH 8
#define LT 32
#define DMODEL 256
#define NHEAD 8
#define DHEAD 32
#define MVIS (BATCH*NVTOK)   /* 72576 */
#define MTEXT (BATCH*LT)     /* 256 */
#define VISSZ 18579456ull    /* MVIS*256 elements */

__device__ __forceinline__ float bf2f(ushort_t u){ return __uint_as_float(((uint_t)u)<<16); }
__device__ __forceinline__ ushort_t f2bfbits(float f){
  __hip_bfloat16 h = __float2bfloat16(f);
  union { __hip_bfloat16 h; ushort_t u; } c; c.h = h; return c.u;
}
// mode: 0 = buffers hold bf16, 1 = buffers hold fp32
__device__ __forceinline__ float ldin(const void* p, size_t i, int mode){
  return mode ? ((const float*)p)[i] : bf2f(((const ushort_t*)p)[i]);
}
__device__ __forceinline__ void stout(void* p, size_t i, int mode, float v){
  if (mode) ((float*)p)[i] = v; else ((ushort_t*)p)[i] = f2bfbits(v);
}

// async global->LDS, 16 B per lane (LDS dest = wave-uniform base + lane*16).
__device__ __forceinline__ void gload_lds16(const void* g, void* l){
  __builtin_amdgcn_global_load_lds(
      (const __attribute__((address_space(1))) unsigned int*)g,
      (__attribute__((address_space(3))) unsigned int*)l, 16, 0, 0);
}

// ---------------------------------------------------------------------------
// D0: dtype detector (unchanged)
// ---------------------------------------------------------------------------
__global__ void k_detect(const uint_t* __restrict__ buf, int n_avail, int* __restrict__ flag){
  __shared__ int zc, bc;
  if (threadIdx.x==0){ zc=0; bc=0; }
  __syncthreads();
  int stride = n_avail/2048; if (stride < 1) stride = 1;
  int nz=0, nb=0;
  for (int i=threadIdx.x; i<2048; i+=256){
    long long idx = (long long)i*stride;
    if (idx >= n_avail) break;
    uint_t d = buf[idx];
    uint_t lo = d & 0xFFFFu;
    int e = (int)((lo >> 7) & 0xFF);
    if (lo == 0) nz++;
    else if (e >= 90 && e <= 160) nb++;
  }
  atomicAdd(&zc, nz); atomicAdd(&bc, nb);
  __syncthreads();
  if (threadIdx.x==0){
    int mode;
    if (zc > 1024) mode = 1;
    else if (bc > 1228) mode = 0;
    else mode = 1;
    *flag = mode;
  }
}

// ---------------------------------------------------------------------------
// W-transpose (unchanged)
// ---------------------------------------------------------------------------
__global__ __launch_bounds__(256) void k_transpose(
    const void* W, ushort_t* __restrict__ Wt, int K, int N,
    const int* __restrict__ mf)
{
  const int mode = *mf;
  __shared__ float tile[32][33];
  const int k0 = blockIdx.x*32, n0 = blockIdx.y*32;
  const int c = threadIdx.x & 31, r8 = threadIdx.x >> 5;
  #pragma unroll
  for (int i=0;i<4;i++){
    const int kk = r8 + i*8;
    tile[kk][c] = ldin(W, (size_t)(k0+kk)*N + n0 + c, mode);
  }
  __syncthreads();
  #pragma unroll
  for (int i=0;i<4;i++){
    const int nn = r8 + i*8;
    Wt[(size_t)(n0+nn)*K + k0 + c] = f2bfbits(tile[c][nn]);
  }
}

// ---------------------------------------------------------------------------
// T1: text prep (unchanged)
// ---------------------------------------------------------------------------
__global__ __launch_bounds__(256) void k_text_prep(
    const void* text,
    const void* ref_w, const void* ref_b,
    const void* off_w, const void* off_b,
    const void* aw_w,  const void* aw_b,
    float* __restrict__ loc_out, float* __restrict__ aw_out,
    const int* __restrict__ mf)
{
  const int mode = *mf;
  const int r = blockIdx.x;
  const int t = threadIdx.x;
  __shared__ float x[256];
  __shared__ float refv[6];
  __shared__ float offv[192];
  __shared__ float logit[96];
  x[t] = ldin(text, (size_t)r*256 + t, mode);
  __syncthreads();
  if (t < 192) {
    float s = 0.f;
    for (int k=0;k<256;k++) s += x[k]*ldin(off_w, (size_t)k*192+t, mode);
    offv[t] = s + ldin(off_b, t, mode);
  } else if (t < 198) {
    int j = t-192;
    float s = 0.f;
    for (int k=0;k<256;k++) s += x[k]*ldin(ref_w, (size_t)k*6+j, mode);
    s += ldin(ref_b, j, mode);
    refv[j] = 1.f/(1.f+expf(-s));
  }
  if (t < 96) {
    float s = 0.f;
    for (int k=0;k<256;k++) s += x[k]*ldin(aw_w, (size_t)k*96+t, mode);
    logit[t] = s + ldin(aw_b, t, mode);
  }
  __syncthreads();
  if (t < 8) {
    float mx = -1e30f;
    for (int j=0;j<12;j++) mx = fmaxf(mx, logit[t*12+j]);
    float e[12]; float den = 0.f;
    for (int j=0;j<12;j++){ e[j] = expf(logit[t*12+j]-mx); den += e[j]; }
    float inv = 1.f/den;
    for (int j=0;j<12;j++) aw_out[(size_t)r*96 + t*12 + j] = e[j]*inv;
  }
  if (t < 192) {
    int rem = t % 24;
    int l = rem >> 3;
    int c = t & 1;
    const float normW[3] = {96.f,48.f,24.f};
    const float normH[3] = {72.f,36.f,18.f};
    float nrm = (c==0) ? normW[l] : normH[l];
    loc_out[(size_t)r*192 + t] = refv[l*2+c] + offv[t]/nrm;
  }
}

// ---------------------------------------------------------------------------
// T2: deformable sampling, lazy vproj (unchanged)
// ---------------------------------------------------------------------------
__global__ __launch_bounds__(64) void k_deform(
    const void* vis_value, const char* __restrict__ vmask,
    const void* vproj_w, const void* vproj_b,
    const float* __restrict__ loc, const float* __restrict__ aw,
    float* __restrict__ ctx_out, const int* __restrict__ mf)
{
  const int mode = *mf;
  const int blk = blockIdx.x;      // r*8 + h
  const int r = blk >> 3;
  const int h = blk & 7;
  const int b = r >> 5;
  const int t = threadIdx.x;
  const int Hs[3] = {72,36,18};
  const int Wsz[3] = {96,48,24};
  const int stl[3] = {0,6912,8640};
  float s0=0.f,s1=0.f,s2=0.f,s3=0.f, wsum=0.f;
  for (int l=0;l<3;l++){
    for (int p=0;p<4;p++){
      const int sIdx = blk*12 + l*4 + p;
      const float a  = aw[sIdx];
      const float X = loc[sIdx*2+0]*(float)Wsz[l] - 0.5f;
      const float Y = loc[sIdx*2+1]*(float)Hs[l] - 0.5f;
      const float x0f = floorf(X), y0f = floorf(Y);
      const int x0 = (int)x0f, y0 = (int)y0f;
      const float wx = X-x0f, wy = Y-y0f;
      const float cw[4] = {(1.f-wx)*(1.f-wy), wx*(1.f-wy), (1.f-wx)*wy, wx*wy};
      const int cx[4] = {x0,x0+1,x0,x0+1};
      const int cy[4] = {y0,y0,y0+1,y0+1};
      for (int c=0;c<4;c++){
        if (cx[c]>=0 && cx[c]<Wsz[l] && cy[c]>=0 && cy[c]<Hs[l]){
          const size_t pos = (size_t)b*NVTOK + stl[l] + cy[c]*Wsz[l] + cx[c];
          if (vmask[pos]) continue;
          const float w = a*cw[c];
          wsum += w;
          const size_t base = pos*256 + t*4;
          s0 += w*ldin(vis_value, base+0, mode);
          s1 += w*ldin(vis_value, base+1, mode);
          s2 += w*ldin(vis_value, base+2, mode);
          s3 += w*ldin(vis_value, base+3, mode);
        }
      }
    }
  }
  __shared__ float sh[256];
  sh[t*4+0]=s0; sh[t*4+1]=s1; sh[t*4+2]=s2; sh[t*4+3]=s3;
  __syncthreads();
  if (t < 32) {
    const int col = h*32 + t;
    float acc = wsum * ldin(vproj_b, col, mode);
    for (int k=0;k<256;k++) acc += sh[k]*ldin(vproj_w, (size_t)k*256+col, mode);
    ctx_out[(size_t)r*256 + col] = acc;
  }
}

__device__ __forceinline__ float block_sum(float v, float* red){
  float sm = v;
  #pragma unroll
  for (int o=32;o>0;o>>=1) sm += __shfl_down(sm,o);
  const int t = threadIdx.x;
  __syncthreads();
  if ((t&63)==0) red[t>>6] = sm;
  __syncthreads();
  return red[0]+red[1]+red[2]+red[3];
}

// ---------------------------------------------------------------------------
// MFMA GEMM (text side, unchanged — tiny M, full hi/lo precision)
// ---------------------------------------------------------------------------
__global__ __launch_bounds__(256) void k_mgemm(
    const void* A, size_t a_off, int a_kind,
    const ushort_t* __restrict__ Wt, const void* bias, float* __restrict__ C,
    int N, int K, int relu, const int* __restrict__ mf)
{
  const int mode = *mf;
  const int split = (a_kind==1) || (mode==1);
  __shared__ ushort_t Ah[128*32];
  __shared__ ushort_t Al[128*32];
  __shared__ ushort_t Bt[128*32];
  const int tid = threadIdx.x;
  const int gm0 = blockIdx.x*128, gn0 = blockIdx.y*128;
  const int wv = tid>>6, lane = tid&63;
  const int mh = (wv&1)*64, nh = (wv>>1)*64;
  const int r16 = lane&15, q8 = (lane>>4)*8;
  const int srow = tid>>1, sseg = (tid&1)*16;
  v4f acc[4][4];
  #pragma unroll
  for (int i=0;i<4;i++)
    #pragma unroll
    for (int j=0;j<4;j++) acc[i][j] = (v4f){0.f,0.f,0.f,0.f};

  for (int k0=0; k0<K; k0+=32){
    if (k0) __syncthreads();
    {
      const ushort_t* src = Wt + (size_t)(gn0+srow)*K + k0 + sseg;
      ((uint4*)&Bt[srow*32+sseg])[0]   = ((const uint4*)src)[0];
      ((uint4*)&Bt[srow*32+sseg+8])[0] = ((const uint4*)src)[1];
    }
    if (!split){
      const ushort_t* src = (const ushort_t*)A + a_off + (size_t)(gm0+srow)*K + k0 + sseg;
      ((uint4*)&Ah[srow*32+sseg])[0]   = ((const uint4*)src)[0];
      ((uint4*)&Ah[srow*32+sseg+8])[0] = ((const uint4*)src)[1];
    } else {
      const float* src = (const float*)A + a_off + (size_t)(gm0+srow)*K + k0 + sseg;
      #pragma unroll
      for (int v=0;v<4;v++){
        float4 f = ((const float4*)src)[v];
        float xs[4] = {f.x, f.y, f.z, f.w};
        #pragma unroll
        for (int e=0;e<4;e++){
          const int idx = srow*32 + sseg + v*4 + e;
          const ushort_t h = f2bfbits(xs[e]);
          Ah[idx] = h;
          Al[idx] = f2bfbits(xs[e] - bf2f(h));
        }
      }
    }
    __syncthreads();
    v8s af[4], bfr[4], al[4];
    #pragma unroll
    for (int mt=0;mt<4;mt++){
      af[mt] = *(const v8s*)&Ah[(mh + mt*16 + r16)*32 + q8];
      if (split) al[mt] = *(const v8s*)&Al[(mh + mt*16 + r16)*32 + q8];
    }
    #pragma unroll
    for (int nt=0;nt<4;nt++)
      bfr[nt] = *(const v8s*)&Bt[(nh + nt*16 + r16)*32 + q8];
    #pragma unroll
    for (int mt=0;mt<4;mt++){
      #pragma unroll
      for (int nt=0;nt<4;nt++){
        acc[mt][nt] = __builtin_amdgcn_mfma_f32_16x16x32_bf16(af[mt], bfr[nt], acc[mt][nt], 0, 0, 0);
        if (split)
          acc[mt][nt] = __builtin_amdgcn_mfma_f32_16x16x32_bf16(al[mt], bfr[nt], acc[mt][nt], 0, 0, 0);
      }
    }
  }
  const int rq = (lane>>4)*4;
  float bv[4];
  #pragma unroll
  for (int nt=0;nt<4;nt++) bv[nt] = ldin(bias, gn0 + nh + nt*16 + r16, mode);
  #pragma unroll
  for (int mt=0;mt<4;mt++){
    #pragma unroll
    for (int r=0;r<4;r++){
      const size_t ro = (size_t)(gm0 + mh + mt*16 + rq + r)*N + gn0 + nh + r16;
      #pragma unroll
      for (int nt=0;nt<4;nt++){
        float v = acc[mt][nt][r] + bv[nt];
        if (relu) v = fmaxf(v, 0.f);
        C[ro + nt*16] = v;
      }
    }
  }
}

// ---------------------------------------------------------------------------
// V5 MFMA GEMM (vis q-proj / f1 / f2): 128x128 tile, BK=64 (half the
// barrier/drain phases of BK=32), seg-XOR LDS swizzle to kill bank
// conflicts:
//   LDS layout linear [128][64] ushort; segment s (8 ushorts = 16 B) of
//   row r holds GLOBAL segment s^(r&7)  (rule #21: linear gload_lds dest +
//   inverse-swizzled per-lane SOURCE + same involution on ds_read).
//   Read addr: row*64 + ((seg ^ (row&7))<<3) -> quad lanes spread across
//   8 bank-groups x 2 lanes = 2-way (free) vs 8-way before.
// K-order preserved (kk ascending) -> bit-identical accumulation.
// XCD-bijective chunked swizzle, n-fastest. Output fp32 or bf16.
// ---------------------------------------------------------------------------
__global__ __launch_bounds__(256) void k_mgemm3(
    const void* A, size_t a_off, int a_kind,
    const ushort_t* __restrict__ Wt, const void* bias,
    float* __restrict__ Cf, ushort_t* __restrict__ Chi,
    int N, int K, int relu, const int* __restrict__ mf)
{
  const int mode = *mf;
  const int rawf32 = (a_kind==0) && (mode==1);
  __shared__ ushort_t Ah[128*64];
  __shared__ ushort_t Bt[128*64];
  const int tid = threadIdx.x;
  const int nbx = gridDim.x, nby = gridDim.y;
  const int total = nbx*nby;
  const int f = blockIdx.y*nbx + blockIdx.x;
  const int qq = total>>3, rr = total&7;
  const int xcd = f&7, pos = f>>3;
  const int wg = (xcd<rr ? xcd*(qq+1) : rr*(qq+1) + (xcd-rr)*qq) + pos;
  const int gm0 = (wg / nby)*128, gn0 = (wg % nby)*128;

  const int wv = tid>>6, lane = tid&63;
  const int mh = (wv&1)*64, nh = (wv>>1)*64;
  const int r16 = lane&15, kq = lane>>4;
  // staging: 32 rows x 8 segs per issue; dest = lane-linear (tid*16 B)
  const int sr = tid>>3;        // row within issue (0..31)
  const int sg = tid&7;         // LDS seg (0..7)
  // rawf32 reg-staging: 128 rows, half-row (32 cols) per thread
  const int srow = tid>>1, chalf = (tid&1)*32;
  const ushort_t* Abf = (const ushort_t*)A + a_off;
  v4f acc[4][4];
  #pragma unroll
  for (int i=0;i<4;i++)
    #pragma unroll
    for (int j=0;j<4;j++) acc[i][j] = (v4f){0.f,0.f,0.f,0.f};

  for (int k0=0; k0<K; k0+=64){
    if (k0) __syncthreads();
    #pragma unroll
    for (int i=0;i<4;i++){
      const int r = i*32 + sr;
      const int gs = (sg ^ (r&7))*8;     // pre-swizzled global segment
      gload_lds16(Wt + (size_t)(gn0+r)*K + k0 + gs, &Bt[r*64 + sg*8]);
    }
    if (!rawf32){
      #pragma unroll
      for (int i=0;i<4;i++){
        const int r = i*32 + sr;
        const int gs = (sg ^ (r&7))*8;
        gload_lds16(Abf + (size_t)(gm0+r)*K + k0 + gs, &Ah[r*64 + sg*8]);
      }
    } else {
      const float* src = (const float*)A + a_off + (size_t)(gm0+srow)*K + k0 + chalf;
      #pragma unroll
      for (int v=0;v<8;v++){
        float4 fq = ((const float4*)src)[v];
        float xs[4] = {fq.x, fq.y, fq.z, fq.w};
        #pragma unroll
        for (int e=0;e<4;e++){
          const int c = chalf + v*4 + e;
          const int idx = srow*64 + (((c>>3) ^ (srow&7))<<3) + (c&7);
          Ah[idx] = f2bfbits(xs[e]);
        }
      }
    }
    __syncthreads();
    #pragma unroll
    for (int kk=0;kk<2;kk++){
      const int seg = kk*4 + kq;         // k-seg this quad consumes
      v8s af[4], bfr[4];
      #pragma unroll
      for (int mt=0;mt<4;mt++){
        const int row = mh + mt*16 + r16;
        af[mt] = *(const v8s*)&Ah[row*64 + ((seg ^ (row&7))<<3)];
      }
      #pragma unroll
      for (int nt=0;nt<4;nt++){
        const int row = nh + nt*16 + r16;
        bfr[nt] = *(const v8s*)&Bt[row*64 + ((seg ^ (row&7))<<3)];
      }
      #pragma unroll
      for (int mt=0;mt<4;mt++){
        #pragma unroll
        for (int nt=0;nt<4;nt++)
          acc[mt][nt] = __builtin_amdgcn_mfma_f32_16x16x32_bf16(af[mt], bfr[nt], acc[mt][nt], 0, 0, 0);
      }
    }
  }
  const int rq = kq*4;
  float bv[4];
  #pragma unroll
  for (int nt=0;nt<4;nt++) bv[nt] = ldin(bias, gn0 + nh + nt*16 + r16, mode);
  const int outf = (Cf != nullptr);
  #pragma unroll
  for (int mt=0;mt<4;mt++){
    #pragma unroll
    for (int r=0;r<4;r++){
      const size_t ro = (size_t)(gm0 + mh + mt*16 + rq + r)*N + gn0 + nh + r16;
      #pragma unroll
      for (int nt=0;nt<4;nt++){
        float v = acc[mt][nt][r] + bv[nt];
        if (relu) v = fmaxf(v, 0.f);
        if (outf) Cf[ro + nt*16] = v;
        else      Chi[ro + nt*16] = f2bfbits(v);
      }
    }
  }
}

// ---------------------------------------------------------------------------
// GEMM + residual + LayerNorm fused — o-proj only (K=256). 64 rows x 256
// cols, 256 thr = 4 waves (unchanged from R12 — measured OK).
// ---------------------------------------------------------------------------
__global__ __launch_bounds__(256) void k_mgemm_ln(
    const ushort_t* __restrict__ A,
    const ushort_t* __restrict__ Wt, const void* bias,
    const void* RES, size_t res_off, int res_bf16,
    void* OUT, size_t out_off, int out_bf16,
    const void* g, const void* be,
    int K, const int* __restrict__ mf)
{
  const int mode = *mf;
  __shared__ ushort_t Ah[64*32];
  __shared__ ushort_t Bt[256*32];
  __shared__ float rsum[4][64];
  __shared__ float rsq[4][64];
  const int tid = threadIdx.x;
  const int gm0 = blockIdx.x*64;
  const int wv = tid>>6, lane = tid&63;
  const int nh = wv*64;
  const int r16 = lane&15, kq = lane>>4, q8 = kq*8;
  const int grow = tid>>2, gcol = (tid&3)*8;
  v4f acc[4][4];
  #pragma unroll
  for (int i=0;i<4;i++)
    #pragma unroll
    for (int j=0;j<4;j++) acc[i][j] = (v4f){0.f,0.f,0.f,0.f};

  for (int k0=0; k0<K; k0+=32){
    if (k0) __syncthreads();
    gload_lds16(A  + (size_t)(gm0+grow)*K  + k0 + gcol, &Ah[grow*32 + gcol]);
    gload_lds16(Wt + (size_t)grow*K        + k0 + gcol, &Bt[grow*32 + gcol]);
    gload_lds16(Wt + (size_t)(64+grow)*K   + k0 + gcol, &Bt[(64+grow)*32 + gcol]);
    gload_lds16(Wt + (size_t)(128+grow)*K  + k0 + gcol, &Bt[(128+grow)*32 + gcol]);
    gload_lds16(Wt + (size_t)(192+grow)*K  + k0 + gcol, &Bt[(192+grow)*32 + gcol]);
    __syncthreads();
    v8s af[4], bfr[4];
    #pragma unroll
    for (int mt=0;mt<4;mt++)
      af[mt] = *(const v8s*)&Ah[(mt*16 + r16)*32 + q8];
    #pragma unroll
    for (int nt=0;nt<4;nt++)
      bfr[nt] = *(const v8s*)&Bt[(nh + nt*16 + r16)*32 + q8];
    #pragma unroll
    for (int mt=0;mt<4;mt++){
      #pragma unroll
      for (int nt=0;nt<4;nt++)
        acc[mt][nt] = __builtin_amdgcn_mfma_f32_16x16x32_bf16(af[mt], bfr[nt], acc[mt][nt], 0, 0, 0);
    }
  }
  // ---- z = acc + bias + residual (in place) ----
  float bv[4];
  #pragma unroll
  for (int nt=0;nt<4;nt++) bv[nt] = ldin(bias, nh + nt*16 + r16, mode);
  #pragma unroll
  for (int mt=0;mt<4;mt++){
    #pragma unroll
    for (int r=0;r<4;r++){
      const int row_l = mt*16 + kq*4 + r;
      const size_t rbase = (size_t)(gm0 + row_l)*256;
      #pragma unroll
      for (int nt=0;nt<4;nt++){
        const int col = nh + nt*16 + r16;
        const float rv = res_bf16 ? bf2f(((const ushort_t*)RES)[res_off + rbase + col])
                                  : ldin(RES, res_off + rbase + col, mode);
        acc[mt][nt][r] = acc[mt][nt][r] + bv[nt] + rv;
      }
    }
  }
  // ---- pass 1: row sums -> mean ----
  #pragma unroll
  for (int mt=0;mt<4;mt++){
    #pragma unroll
    for (int r=0;r<4;r++){
      float s = acc[mt][0][r] + acc[mt][1][r] + acc[mt][2][r] + acc[mt][3][r];
      #pragma unroll
      for (int o=1;o<16;o<<=1) s += __shfl_xor(s, o);
      if (r16==0) rsum[wv][mt*16 + kq*4 + r] = s;
    }
  }
  __syncthreads();
  float mean[4][4];
  #pragma unroll
  for (int mt=0;mt<4;mt++){
    #pragma unroll
    for (int r=0;r<4;r++){
      const int row_l = mt*16 + kq*4 + r;
      mean[mt][r] = (rsum[0][row_l]+rsum[1][row_l]+rsum[2][row_l]+rsum[3][row_l]) * (1.f/256.f);
    }
  }
  // ---- pass 2: row sumsq of (z-mean) -> var ----
  #pragma unroll
  for (int mt=0;mt<4;mt++){
    #pragma unroll
    for (int r=0;r<4;r++){
      const float m = mean[mt][r];
      float s2 = 0.f;
      #pragma unroll
      for (int nt=0;nt<4;nt++){ const float d = acc[mt][nt][r]-m; s2 += d*d; }
      #pragma unroll
      for (int o=1;o<16;o<<=1) s2 += __shfl_xor(s2, o);
      if (r16==0) rsq[wv][mt*16 + kq*4 + r] = s2;
    }
  }
  __syncthreads();
  // ---- normalize + affine + write ----
  float gv[4], bev[4];
  #pragma unroll
  for (int nt=0;nt<4;nt++){
    gv[nt]  = ldin(g,  nh + nt*16 + r16, mode);
    bev[nt] = ldin(be, nh + nt*16 + r16, mode);
  }
  #pragma unroll
  for (int mt=0;mt<4;mt++){
    #pragma unroll
    for (int r=0;r<4;r++){
      const int row_l = mt*16 + kq*4 + r;
      const float var = (rsq[0][row_l]+rsq[1][row_l]+rsq[2][row_l]+rsq[3][row_l]) * (1.f/256.f);
      const float inv = rsqrtf(var + 1e-5f);
      const float m = mean[mt][r];
      const size_t obase = (size_t)(gm0 + row_l)*256;
      #pragma unroll
      for (int nt=0;nt<4;nt++){
        const int col = nh + nt*16 + r16;
        const float o = (acc[mt][nt][r]-m)*inv*gv[nt] + bev[nt];
        if (out_bf16) ((ushort_t*)OUT)[obase + col] = f2bfbits(o);
        else          stout(OUT, out_off + obase + col, mode, o);
      }
    }
  }
}

// ---------------------------------------------------------------------------
// KV split/transpose prep (unchanged)
// ---------------------------------------------------------------------------
__global__ __launch_bounds__(256) void k_kvsplit(
    const float* __restrict__ kws, const float* __restrict__ vws,
    ushort_t* __restrict__ khi, ushort_t* __restrict__ klo,
    ushort_t* __restrict__ vthi, ushort_t* __restrict__ vtlo)
{
  const int row = blockIdx.x;        // 0..255 = b*32 + key
  const int b = row >> 5, key = row & 31;
  const int t = threadIdx.x;         // dim 0..255
  const float f = kws[(size_t)row*256 + t];
  const ushort_t fh = f2bfbits(f);
  khi[(size_t)row*256 + t] = fh;
  klo[(size_t)row*256 + t] = f2bfbits(f - bf2f(fh));
  const float g = vws[(size_t)row*256 + t];
  const ushort_t gh = f2bfbits(g);
  const size_t vt = ((size_t)b*256 + t)*32 + key;
  vthi[vt] = gh;
  vtlo[vt] = f2bfbits(g - bf2f(gh));
}

// ---------------------------------------------------------------------------
// A2: MFMA MHA (unchanged)
// ---------------------------------------------------------------------------
__global__ __launch_bounds__(256) void k_attn2(
    const ushort_t* __restrict__ qcH,
    ushort_t* __restrict__ aoh,
    const ushort_t* __restrict__ khi, const ushort_t* __restrict__ klo,
    const ushort_t* __restrict__ vthi, const ushort_t* __restrict__ vtlo,
    const char* __restrict__ tmask, int r0)
{
  __shared__ float P[4][16][36];
  const int tid = threadIdx.x;
  const int wv = tid>>6, lane = tid&63;
  const int lrow0 = blockIdx.x*64 + wv*16;
  const int b = (r0 + lrow0)/NVTOK;
  const int m16 = lane&15;
  const int kq = lane>>4;
  const int q8 = kq*8;
  const int key0 = m16, key1 = m16+16;
  const bool msk0 = tmask[b*LT + key0] != 0;
  const bool msk1 = tmask[b*LT + key1] != 0;
  const float scale = 0.17677669529663687f;

  for (int h=0; h<8; ++h){
    const size_t qoff = (size_t)(lrow0 + m16)*256 + h*32 + q8;
    const v8s qh = *(const v8s*)&qcH[qoff];
    const size_t kb0 = ((size_t)(b*32+key0)*256) + h*32 + q8;
    const size_t kb1 = ((size_t)(b*32+key1)*256) + h*32 + q8;
    const v8s kh0 = *(const v8s*)&khi[kb0];
    const v8s kl0 = *(const v8s*)&klo[kb0];
    const v8s kh1 = *(const v8s*)&khi[kb1];
    const v8s kl1 = *(const v8s*)&klo[kb1];
    v4f s0 = (v4f){0.f,0.f,0.f,0.f}, s1 = (v4f){0.f,0.f,0.f,0.f};
    s0 = __builtin_amdgcn_mfma_f32_16x16x32_bf16(qh, kh0, s0, 0,0,0);
    s0 = __builtin_amdgcn_mfma_f32_16x16x32_bf16(qh, kl0, s0, 0,0,0);
    s1 = __builtin_amdgcn_mfma_f32_16x16x32_bf16(qh, kh1, s1, 0,0,0);
    s1 = __builtin_amdgcn_mfma_f32_16x16x32_bf16(qh, kl1, s1, 0,0,0);
    float e0[4], e1[4], inv[4];
    #pragma unroll
    for (int r=0;r<4;r++){
      const float a0 = msk0 ? -1e9f : s0[r]*scale;
      const float a1 = msk1 ? -1e9f : s1[r]*scale;
      float mx = fmaxf(a0,a1);
      #pragma unroll
      for (int o=1;o<16;o<<=1) mx = fmaxf(mx, __shfl_xor(mx,o));
      const float x0 = __expf(a0-mx), x1 = __expf(a1-mx);
      float dn = x0+x1;
      #pragma unroll
      for (int o=1;o<16;o<<=1) dn += __shfl_xor(dn,o);
      e0[r]=x0; e1[r]=x1; inv[r] = 1.f/dn;
    }
    #pragma unroll
    for (int r=0;r<4;r++){
      P[wv][kq*4+r][key0] = e0[r];
      P[wv][kq*4+r][key1] = e1[r];
    }
    __syncthreads();
    float pv[8];
    *(float4*)&pv[0] = *(const float4*)&P[wv][m16][q8];
    *(float4*)&pv[4] = *(const float4*)&P[wv][m16][q8+4];
    v8s ph;
    #pragma unroll
    for (int j=0;j<8;j++) ph[j] = (short)f2bfbits(pv[j]);
    const size_t vb0 = ((size_t)(b*256 + h*32 + m16)*32) + q8;
    const size_t vb1 = ((size_t)(b*256 + h*32 + 16 + m16)*32) + q8;
    const v8s vh0 = *(const v8s*)&vthi[vb0];
    const v8s vl0 = *(const v8s*)&vtlo[vb0];
    const v8s vh1 = *(const v8s*)&vthi[vb1];
    const v8s vl1 = *(const v8s*)&vtlo[vb1];
    v4f o0 = (v4f){0.f,0.f,0.f,0.f}, o1 = (v4f){0.f,0.f,0.f,0.f};
    o0 = __builtin_amdgcn_mfma_f32_16x16x32_bf16(ph, vh0, o0, 0,0,0);
    o0 = __builtin_amdgcn_mfma_f32_16x16x32_bf16(ph, vl0, o0, 0,0,0);
    o1 = __builtin_amdgcn_mfma_f32_16x16x32_bf16(ph, vh1, o1, 0,0,0);
    o1 = __builtin_amdgcn_mfma_f32_16x16x32_bf16(ph, vl1, o1, 0,0,0);
    __syncthreads();
    #pragma unroll
    for (int r=0;r<4;r++){
      const size_t ro = (size_t)(lrow0 + kq*4 + r)*256 + h*32;
      aoh[ro + m16]      = f2bfbits(o0[r]*inv[r]);
      aoh[ro + 16 + m16] = f2bfbits(o1[r]*inv[r]);
    }
  }
}

// ---------------------------------------------------------------------------
// residual + two-pass LayerNorm (text side, unchanged)
// ---------------------------------------------------------------------------
__global__ __launch_bounds__(256) void k_add_ln(
    const float* __restrict__ X, const void* R, size_t r_off, int r_f32,
    void* OUT, size_t o_off, int o_f32,
    void* OUT2, size_t o2_off,
    const void* g, const void* be, const int* __restrict__ mf)
{
  const int mode = *mf;
  const int row = blockIdx.x; const int t = threadIdx.x;
  const size_t idx = (size_t)row*256 + t;
  __shared__ float red[4];
  const float rv = r_f32 ? ((const float*)R)[r_off+idx] : ldin(R, r_off+idx, mode);
  const float v = X[idx] + rv;
  const float m = block_sum(v, red) * (1.f/256.f);
  __syncthreads();
  const float d = v - m;
  const float var = block_sum(d*d, red) * (1.f/256.f);
  const float o = d*rsqrtf(var+1e-5f)*ldin(g,t,mode) + ldin(be,t,mode);
  if (o_f32) ((float*)OUT)[o_off+idx] = o;
  else       stout(OUT, o_off+idx, mode, o);
  if (OUT2)  stout(OUT2, o2_off+idx, mode, o);
}

// ---------------------------------------------------------------------------
// LN2 (vis): v = X + RH ; out = mode-typed at offset
// ---------------------------------------------------------------------------
__global__ __launch_bounds__(256) void k_add_ln_pres(
    const float* __restrict__ X,
    const ushort_t* __restrict__ RH,
    void* OUT, size_t o_off,
    const void* g, const void* be, const int* __restrict__ mf)
{
  const int mode = *mf;
  const int row = blockIdx.x; const int t = threadIdx.x;
  const size_t idx = (size_t)row*256 + t;
  __shared__ float red[4];
  const float rv = bf2f(RH[idx]);
  const float v = X[idx] + rv;
  const float m = block_sum(v, red) * (1.f/256.f);
  __syncthreads();
  const float d = v - m;
  const float var = block_sum(d*d, red) * (1.f/256.f);
  const float o = d*rsqrtf(var+1e-5f)*ldin(g,t,mode) + ldin(be,t,mode);
  stout(OUT, o_off+idx, mode, o);
}

// ---------------------------------------------------------------------------
extern "C" void kernel_launch(void* const* d_in, const int* in_sizes, int n_in,
                              void* d_out, int out_size, void* d_ws, size_t ws_size,
                              hipStream_t stream)
{
  (void)n_in; (void)out_size;
  const void* vis_tokens = d_in[0];
  const void* text_tokens= d_in[1];
  const void* vis_value  = d_in[2];
  const void* ref_w = d_in[3];  const void* ref_b = d_in[4];
  const void* off_w = d_in[5];  const void* off_b = d_in[6];
  const void* aw_w  = d_in[7];  const void* aw_b  = d_in[8];
  const void* vproj_w = d_in[9];  const void* vproj_b = d_in[10];
  const void* oproj_w = d_in[11]; const void* oproj_b = d_in[12];
  const void* lvi_out_w = d_in[13]; const void* lvi_out_b = d_in[14];
  const void* lvi_n1_s = d_in[15];  const void* lvi_n1_b = d_in[16];
  const void* lvi_f1_w = d_in[17];  const void* lvi_f1_b = d_in[18];
  const void* lvi_f2_w = d_in[19];  const void* lvi_f2_b = d_in[20];
  const void* lvi_n2_s = d_in[21];  const void* lvi_n2_b = d_in[22];
  const void* mha_qw = d_in[23]; const void* mha_qb = d_in[24];
  const void* mha_kw = d_in[25]; const void* mha_kb = d_in[26];
  const void* mha_vw = d_in[27]; const void* mha_vb = d_in[28];
  const void* mha_ow = d_in[29]; const void* mha_ob = d_in[30];
  const void* vli_out_w = d_in[31]; const void* vli_out_b = d_in[32];
  const void* vli_n1_s = d_in[33];  const void* vli_n1_b = d_in[34];
  const void* vli_f1_w = d_in[35];  const void* vli_f1_b = d_in[36];
  const void* vli_f2_w = d_in[37];  const void* vli_f2_b = d_in[38];
  const void* vli_n2_s = d_in[39];  const void* vli_n2_b = d_in[40];
  const char* tmask = (const char*)d_in[43];
  const char* vmask = (const char*)d_in[44];

  // ---- workspace layout ----
  char* ws = (char*)d_ws;
  int*   flag    = (int*)  (ws + 0);               // 256 B
  float* loc_ws  = (float*)(ws + 256);             // 196608
  float* aw_ws   = (float*)(ws + 196864);          //  98304
  float* ctxt_ws = (float*)(ws + 295168);          // 262144
  float* t_ws    = (float*)(ws + 557312);          // 262144
  float* tout_ws = (float*)(ws + 819456);          // 262144
  float* k_ws    = (float*)(ws + 1081600);         // 262144
  float* v_ws    = (float*)(ws + 1343744);         // 262144
  ushort_t* wtq  = (ushort_t*)(ws + 1605888ull);   // 131072 B
  ushort_t* wto  = (ushort_t*)(ws + 1736960ull);   // 131072 B
  ushort_t* wtf1 = (ushort_t*)(ws + 1868032ull);   // 524288 B
  ushort_t* wtf2 = (ushort_t*)(ws + 2392320ull);   // 524288 B
  ushort_t* wtk   = (ushort_t*)(ws + 2916608ull);  // 131072 B (mha_kw^T)
  ushort_t* wtv   = (ushort_t*)(ws + 3047680ull);  // 131072 B (mha_vw^T)
  ushort_t* wtop  = (ushort_t*)(ws + 3178752ull);  // 131072 B (oproj_w^T)
  ushort_t* wtlo  = (ushort_t*)(ws + 3309824ull);  // 131072 B (lvi_out_w^T)
  ushort_t* wtlf1 = (ushort_t*)(ws + 3440896ull);  // 524288 B (lvi_f1_w^T)
  ushort_t* wtlf2 = (ushort_t*)(ws + 3965184ull);  // 524288 B (lvi_f2_w^T)
  float* hbuf_t   = (float*)(ws + 4489472ull);     // 1048576 B (256x1024)
  float* ybuf     = (float*)(ws + 5538048ull);     // 262144 B
  float* fbuf     = (float*)(ws + 5800192ull);     // 262144 B
  ushort_t* khi   = (ushort_t*)(ws + 6062336ull);  // 131072 B
  ushort_t* klo   = (ushort_t*)(ws + 6193408ull);  // 131072 B
  ushort_t* vthi  = (ushort_t*)(ws + 6324480ull);  // 131072 B
  ushort_t* vtlo  = (ushort_t*)(ws + 6455552ull);  // 131072 B
  const size_t fe = 6586624ull;                    // chunk region start

  // per-row chunk bytes (3584 B/row):
  //   region0 (1024 B): ubuf fp32 (f2 out); first 512 B alias qc bf16
  //   region1 ( 512 B): v1 bf16
  //   region2 (2048 B): hb bf16; first 512 B alias ao bf16 (dead pre-f1)
  long long R_ll = 128;
  if (ws_size > fe) R_ll = (long long)((ws_size - fe) / 3584ull);
  if (R_ll > (long long)MVIS) R_ll = MVIS;
  R_ll &= ~127LL;
  if (R_ll < 128) R_ll = 128;
  const int R = (int)R_ll;
  ushort_t* qcH  = (ushort_t*)(ws + fe);                      // region0 alias
  float*    ubuf = (float*)   (ws + fe);                      // region0
  ushort_t* v1H  = (ushort_t*)(ws + fe + (size_t)R*1024ull);  // region1
  ushort_t* hbH  = (ushort_t*)(ws + fe + (size_t)R*1536ull);  // region2
  ushort_t* aoH  = hbH;                                       // alias (dead pre-f1)

  // ---- dtype detect ----
  int ndw = in_sizes[1]/2; if (ndw < 1) ndw = 1;
  k_detect<<<1,256,0,stream>>>((const uint_t*)text_tokens, ndw, flag);

  // ---- weight transposes for MFMA GEMMs ----
  k_transpose<<<dim3(8,8),  256,0,stream>>>(mha_qw,    wtq,   256, 256,  flag);
  k_transpose<<<dim3(8,8),  256,0,stream>>>(mha_ow,    wto,   256, 256,  flag);
  k_transpose<<<dim3(8,32), 256,0,stream>>>(vli_f1_w,  wtf1,  256, 1024, flag);
  k_transpose<<<dim3(32,8), 256,0,stream>>>(vli_f2_w,  wtf2,  1024, 256, flag);
  k_transpose<<<dim3(8,8),  256,0,stream>>>(mha_kw,    wtk,   256, 256,  flag);
  k_transpose<<<dim3(8,8),  256,0,stream>>>(mha_vw,    wtv,   256, 256,  flag);
  k_transpose<<<dim3(8,8),  256,0,stream>>>(oproj_w,   wtop,  256, 256,  flag);
  k_transpose<<<dim3(8,8),  256,0,stream>>>(lvi_out_w, wtlo,  256, 256,  flag);
  k_transpose<<<dim3(8,32), 256,0,stream>>>(lvi_f1_w,  wtlf1, 256, 1024, flag);
  k_transpose<<<dim3(32,8), 256,0,stream>>>(lvi_f2_w,  wtlf2, 1024, 256, flag);

  // ---- text side ----
  k_text_prep<<<MTEXT,256,0,stream>>>(text_tokens, ref_w, ref_b, off_w, off_b,
                                      aw_w, aw_b, loc_ws, aw_ws, flag);
  k_deform<<<MTEXT*NHEAD,64,0,stream>>>(vis_value, vmask, vproj_w, vproj_b,
                                        loc_ws, aw_ws, ctxt_ws, flag);

  // attn-out path: y = ctx@oproj + b ; z = y@lvi_out + b ; t = LN(text + z)
  {
    dim3 g22(2,2);
    k_mgemm<<<g22,256,0,stream>>>(ctxt_ws, 0, 1, wtop, oproj_b, ybuf, 256, 256, 0, flag);
    k_mgemm<<<g22,256,0,stream>>>(ybuf,    0, 1, wtlo, lvi_out_b, fbuf, 256, 256, 0, flag);
    k_add_ln<<<MTEXT,256,0,stream>>>(fbuf, text_tokens, 0, 0,
                                     t_ws, 0, 1, nullptr, 0, lvi_n1_s, lvi_n1_b, flag);
  }
  // ffn path: h = relu(t@f1+b1) ; f = h@f2+b2 ; tout = LN(t + f)
  {
    dim3 g28(2,8), g22(2,2);
    k_mgemm<<<g28,256,0,stream>>>(t_ws,   0, 1, wtlf1, lvi_f1_b, hbuf_t, 1024, 256, 1, flag);
    k_mgemm<<<g22,256,0,stream>>>(hbuf_t, 0, 1, wtlf2, lvi_f2_b, fbuf,   256, 1024, 0, flag);
    k_add_ln<<<MTEXT,256,0,stream>>>(fbuf, t_ws, 0, 1,
                                     tout_ws, 0, 1, d_out, VISSZ, lvi_n2_s, lvi_n2_b, flag);
  }
  // k/v projection of text_out + bf16 hi/lo split (+ V transpose)
  {
    dim3 g22(2,2);
    k_mgemm<<<g22,256,0,stream>>>(tout_ws, 0, 1, wtk, mha_kb, k_ws, 256, 256, 0, flag);
    k_mgemm<<<g22,256,0,stream>>>(tout_ws, 0, 1, wtv, mha_vb, v_ws, 256, 256, 0, flag);
    k_kvsplit<<<256,256,0,stream>>>(k_ws, v_ws, khi, klo, vthi, vtlo);
  }

  // ---- vis side, chunked by R rows ----
  for (int r0 = 0; r0 < MVIS; r0 += R){
    const int nr = (MVIS - r0 < R) ? (MVIS - r0) : R;   // multiple of 128
    dim3 g2(nr/128, 2), g8(nr/128, 8);
    k_mgemm3<<<g2,256,0,stream>>>(vis_tokens, (size_t)r0*256, 0,
                                  wtq, mha_qb, nullptr, qcH, 256, 256, 0, flag);
    k_attn2<<<nr/64,256,0,stream>>>(qcH, aoH, khi, klo, vthi, vtlo, tmask, r0);
    // o-proj + residual(vis_tokens) + LN1 -> v1H (bf16)  [K=256: fused OK]
    k_mgemm_ln<<<nr/64,256,0,stream>>>(aoH, wto, mha_ob,
                                       vis_tokens, (size_t)r0*256, 0,
                                       v1H, 0, 1,
                                       vli_n1_s, vli_n1_b, 256, flag);
    k_mgemm3<<<g8,256,0,stream>>>(v1H, 0, 2,
                                  wtf1, vli_f1_b, nullptr, hbH, 1024, 256, 1, flag);
    // f2 unfused (proven 128x128 N-split path) -> ubuf fp32
    k_mgemm3<<<g2,256,0,stream>>>(hbH, 0, 2,
                                  wtf2, vli_f2_b, ubuf, nullptr, 256, 1024, 0, flag);
    // LN2: ubuf + v1H -> d_out
    k_add_ln_pres<<<nr,256,0,stream>>>(ubuf, v1H,
                                       d_out, (size_t)r0*256, vli_n2_s, vli_n2_b, flag);
  }
}

// Round 14
// 860.957 us; speedup vs baseline: 1.3190x; 1.0086x over previous
//
#include <hip/hip_runtime.h>
#include <hip/hip_bf16.h>
#include <math.h>

typedef __hip_bfloat16 bf16;
typedef unsigned short ushort_t;
typedef unsigned int uint_t;
typedef short v8s __attribute__((ext_vector_type(8)));
typedef float v4f __attribute__((ext_vector_type(4)));

#define NVTOK 9072
#define BATCH 8
#define LT 32
#define DMODEL 256
#define NHEAD 8
#define DHEAD 32
#define MVIS (BATCH*NVTOK)   /* 72576 */
#define MTEXT (BATCH*LT)     /* 256 */
#define VISSZ 18579456ull    /* MVIS*256 elements */

__device__ __forceinline__ float bf2f(ushort_t u){ return __uint_as_float(((uint_t)u)<<16); }
__device__ __forceinline__ ushort_t f2bfbits(float f){
  __hip_bfloat16 h = __float2bfloat16(f);
  union { __hip_bfloat16 h; ushort_t u; } c; c.h = h; return c.u;
}
// mode: 0 = buffers hold bf16, 1 = buffers hold fp32
__device__ __forceinline__ float ldin(const void* p, size_t i, int mode){
  return mode ? ((const float*)p)[i] : bf2f(((const ushort_t*)p)[i]);
}
__device__ __forceinline__ void stout(void* p, size_t i, int mode, float v){
  if (mode) ((float*)p)[i] = v; else ((ushort_t*)p)[i] = f2bfbits(v);
}

// async global->LDS, 16 B per lane (LDS dest = wave-uniform base + lane*16).
__device__ __forceinline__ void gload_lds16(const void* g, void* l){
  __builtin_amdgcn_global_load_lds(
      (const __attribute__((address_space(1))) unsigned int*)g,
      (__attribute__((address_space(3))) unsigned int*)l, 16, 0, 0);
}

// ---------------------------------------------------------------------------
// D0: dtype detector (unchanged)
// ---------------------------------------------------------------------------
__global__ void k_detect(const uint_t* __restrict__ buf, int n_avail, int* __restrict__ flag){
  __shared__ int zc, bc;
  if (threadIdx.x==0){ zc=0; bc=0; }
  __syncthreads();
  int stride = n_avail/2048; if (stride < 1) stride = 1;
  int nz=0, nb=0;
  for (int i=threadIdx.x; i<2048; i+=256){
    long long idx = (long long)i*stride;
    if (idx >= n_avail) break;
    uint_t d = buf[idx];
    uint_t lo = d & 0xFFFFu;
    int e = (int)((lo >> 7) & 0xFF);
    if (lo == 0) nz++;
    else if (e >= 90 && e <= 160) nb++;
  }
  atomicAdd(&zc, nz); atomicAdd(&bc, nb);
  __syncthreads();
  if (threadIdx.x==0){
    int mode;
    if (zc > 1024) mode = 1;
    else if (bc > 1228) mode = 0;
    else mode = 1;
    *flag = mode;
  }
}

// ---------------------------------------------------------------------------
// W-transpose (unchanged)
// ---------------------------------------------------------------------------
__global__ __launch_bounds__(256) void k_transpose(
    const void* W, ushort_t* __restrict__ Wt, int K, int N,
    const int* __restrict__ mf)
{
  const int mode = *mf;
  __shared__ float tile[32][33];
  const int k0 = blockIdx.x*32, n0 = blockIdx.y*32;
  const int c = threadIdx.x & 31, r8 = threadIdx.x >> 5;
  #pragma unroll
  for (int i=0;i<4;i++){
    const int kk = r8 + i*8;
    tile[kk][c] = ldin(W, (size_t)(k0+kk)*N + n0 + c, mode);
  }
  __syncthreads();
  #pragma unroll
  for (int i=0;i<4;i++){
    const int nn = r8 + i*8;
    Wt[(size_t)(n0+nn)*K + k0 + c] = f2bfbits(tile[c][nn]);
  }
}

// ---------------------------------------------------------------------------
// T1: text prep (unchanged)
// ---------------------------------------------------------------------------
__global__ __launch_bounds__(256) void k_text_prep(
    const void* text,
    const void* ref_w, const void* ref_b,
    const void* off_w, const void* off_b,
    const void* aw_w,  const void* aw_b,
    float* __restrict__ loc_out, float* __restrict__ aw_out,
    const int* __restrict__ mf)
{
  const int mode = *mf;
  const int r = blockIdx.x;
  const int t = threadIdx.x;
  __shared__ float x[256];
  __shared__ float refv[6];
  __shared__ float offv[192];
  __shared__ float logit[96];
  x[t] = ldin(text, (size_t)r*256 + t, mode);
  __syncthreads();
  if (t < 192) {
    float s = 0.f;
    for (int k=0;k<256;k++) s += x[k]*ldin(off_w, (size_t)k*192+t, mode);
    offv[t] = s + ldin(off_b, t, mode);
  } else if (t < 198) {
    int j = t-192;
    float s = 0.f;
    for (int k=0;k<256;k++) s += x[k]*ldin(ref_w, (size_t)k*6+j, mode);
    s += ldin(ref_b, j, mode);
    refv[j] = 1.f/(1.f+expf(-s));
  }
  if (t < 96) {
    float s = 0.f;
    for (int k=0;k<256;k++) s += x[k]*ldin(aw_w, (size_t)k*96+t, mode);
    logit[t] = s + ldin(aw_b, t, mode);
  }
  __syncthreads();
  if (t < 8) {
    float mx = -1e30f;
    for (int j=0;j<12;j++) mx = fmaxf(mx, logit[t*12+j]);
    float e[12]; float den = 0.f;
    for (int j=0;j<12;j++){ e[j] = expf(logit[t*12+j]-mx); den += e[j]; }
    float inv = 1.f/den;
    for (int j=0;j<12;j++) aw_out[(size_t)r*96 + t*12 + j] = e[j]*inv;
  }
  if (t < 192) {
    int rem = t % 24;
    int l = rem >> 3;
    int c = t & 1;
    const float normW[3] = {96.f,48.f,24.f};
    const float normH[3] = {72.f,36.f,18.f};
    float nrm = (c==0) ? normW[l] : normH[l];
    loc_out[(size_t)r*192 + t] = refv[l*2+c] + offv[t]/nrm;
  }
}

// ---------------------------------------------------------------------------
// T2: deformable sampling, lazy vproj (unchanged)
// ---------------------------------------------------------------------------
__global__ __launch_bounds__(64) void k_deform(
    const void* vis_value, const char* __restrict__ vmask,
    const void* vproj_w, const void* vproj_b,
    const float* __restrict__ loc, const float* __restrict__ aw,
    float* __restrict__ ctx_out, const int* __restrict__ mf)
{
  const int mode = *mf;
  const int blk = blockIdx.x;      // r*8 + h
  const int r = blk >> 3;
  const int h = blk & 7;
  const int b = r >> 5;
  const int t = threadIdx.x;
  const int Hs[3] = {72,36,18};
  const int Wsz[3] = {96,48,24};
  const int stl[3] = {0,6912,8640};
  float s0=0.f,s1=0.f,s2=0.f,s3=0.f, wsum=0.f;
  for (int l=0;l<3;l++){
    for (int p=0;p<4;p++){
      const int sIdx = blk*12 + l*4 + p;
      const float a  = aw[sIdx];
      const float X = loc[sIdx*2+0]*(float)Wsz[l] - 0.5f;
      const float Y = loc[sIdx*2+1]*(float)Hs[l] - 0.5f;
      const float x0f = floorf(X), y0f = floorf(Y);
      const int x0 = (int)x0f, y0 = (int)y0f;
      const float wx = X-x0f, wy = Y-y0f;
      const float cw[4] = {(1.f-wx)*(1.f-wy), wx*(1.f-wy), (1.f-wx)*wy, wx*wy};
      const int cx[4] = {x0,x0+1,x0,x0+1};
      const int cy[4] = {y0,y0,y0+1,y0+1};
      for (int c=0;c<4;c++){
        if (cx[c]>=0 && cx[c]<Wsz[l] && cy[c]>=0 && cy[c]<Hs[l]){
          const size_t pos = (size_t)b*NVTOK + stl[l] + cy[c]*Wsz[l] + cx[c];
          if (vmask[pos]) continue;
          const float w = a*cw[c];
          wsum += w;
          const size_t base = pos*256 + t*4;
          s0 += w*ldin(vis_value, base+0, mode);
          s1 += w*ldin(vis_value, base+1, mode);
          s2 += w*ldin(vis_value, base+2, mode);
          s3 += w*ldin(vis_value, base+3, mode);
        }
      }
    }
  }
  __shared__ float sh[256];
  sh[t*4+0]=s0; sh[t*4+1]=s1; sh[t*4+2]=s2; sh[t*4+3]=s3;
  __syncthreads();
  if (t < 32) {
    const int col = h*32 + t;
    float acc = wsum * ldin(vproj_b, col, mode);
    for (int k=0;k<256;k++) acc += sh[k]*ldin(vproj_w, (size_t)k*256+col, mode);
    ctx_out[(size_t)r*256 + col] = acc;
  }
}

__device__ __forceinline__ float block_sum(float v, float* red){
  float sm = v;
  #pragma unroll
  for (int o=32;o>0;o>>=1) sm += __shfl_down(sm,o);
  const int t = threadIdx.x;
  __syncthreads();
  if ((t&63)==0) red[t>>6] = sm;
  __syncthreads();
  return red[0]+red[1]+red[2]+red[3];
}

// ---------------------------------------------------------------------------
// MFMA GEMM (text side, unchanged — tiny M, full hi/lo precision)
// ---------------------------------------------------------------------------
__global__ __launch_bounds__(256) void k_mgemm(
    const void* A, size_t a_off, int a_kind,
    const ushort_t* __restrict__ Wt, const void* bias, float* __restrict__ C,
    int N, int K, int relu, const int* __restrict__ mf)
{
  const int mode = *mf;
  const int split = (a_kind==1) || (mode==1);
  __shared__ ushort_t Ah[128*32];
  __shared__ ushort_t Al[128*32];
  __shared__ ushort_t Bt[128*32];
  const int tid = threadIdx.x;
  const int gm0 = blockIdx.x*128, gn0 = blockIdx.y*128;
  const int wv = tid>>6, lane = tid&63;
  const int mh = (wv&1)*64, nh = (wv>>1)*64;
  const int r16 = lane&15, q8 = (lane>>4)*8;
  const int srow = tid>>1, sseg = (tid&1)*16;
  v4f acc[4][4];
  #pragma unroll
  for (int i=0;i<4;i++)
    #pragma unroll
    for (int j=0;j<4;j++) acc[i][j] = (v4f){0.f,0.f,0.f,0.f};

  for (int k0=0; k0<K; k0+=32){
    if (k0) __syncthreads();
    {
      const ushort_t* src = Wt + (size_t)(gn0+srow)*K + k0 + sseg;
      ((uint4*)&Bt[srow*32+sseg])[0]   = ((const uint4*)src)[0];
      ((uint4*)&Bt[srow*32+sseg+8])[0] = ((const uint4*)src)[1];
    }
    if (!split){
      const ushort_t* src = (const ushort_t*)A + a_off + (size_t)(gm0+srow)*K + k0 + sseg;
      ((uint4*)&Ah[srow*32+sseg])[0]   = ((const uint4*)src)[0];
      ((uint4*)&Ah[srow*32+sseg+8])[0] = ((const uint4*)src)[1];
    } else {
      const float* src = (const float*)A + a_off + (size_t)(gm0+srow)*K + k0 + sseg;
      #pragma unroll
      for (int v=0;v<4;v++){
        float4 f = ((const float4*)src)[v];
        float xs[4] = {f.x, f.y, f.z, f.w};
        #pragma unroll
        for (int e=0;e<4;e++){
          const int idx = srow*32 + sseg + v*4 + e;
          const ushort_t h = f2bfbits(xs[e]);
          Ah[idx] = h;
          Al[idx] = f2bfbits(xs[e] - bf2f(h));
        }
      }
    }
    __syncthreads();
    v8s af[4], bfr[4], al[4];
    #pragma unroll
    for (int mt=0;mt<4;mt++){
      af[mt] = *(const v8s*)&Ah[(mh + mt*16 + r16)*32 + q8];
      if (split) al[mt] = *(const v8s*)&Al[(mh + mt*16 + r16)*32 + q8];
    }
    #pragma unroll
    for (int nt=0;nt<4;nt++)
      bfr[nt] = *(const v8s*)&Bt[(nh + nt*16 + r16)*32 + q8];
    #pragma unroll
    for (int mt=0;mt<4;mt++){
      #pragma unroll
      for (int nt=0;nt<4;nt++){
        acc[mt][nt] = __builtin_amdgcn_mfma_f32_16x16x32_bf16(af[mt], bfr[nt], acc[mt][nt], 0, 0, 0);
        if (split)
          acc[mt][nt] = __builtin_amdgcn_mfma_f32_16x16x32_bf16(al[mt], bfr[nt], acc[mt][nt], 0, 0, 0);
      }
    }
  }
  const int rq = (lane>>4)*4;
  float bv[4];
  #pragma unroll
  for (int nt=0;nt<4;nt++) bv[nt] = ldin(bias, gn0 + nh + nt*16 + r16, mode);
  #pragma unroll
  for (int mt=0;mt<4;mt++){
    #pragma unroll
    for (int r=0;r<4;r++){
      const size_t ro = (size_t)(gm0 + mh + mt*16 + rq + r)*N + gn0 + nh + r16;
      #pragma unroll
      for (int nt=0;nt<4;nt++){
        float v = acc[mt][nt][r] + bv[nt];
        if (relu) v = fmaxf(v, 0.f);
        C[ro + nt*16] = v;
      }
    }
  }
}

// ---------------------------------------------------------------------------
// V5 MFMA GEMM (vis q-proj / f1 / f2): 128x128 tile, BK=64, seg-XOR LDS
// swizzle (R13: bank conflicts -> 0). Unchanged from R13.
// ---------------------------------------------------------------------------
__global__ __launch_bounds__(256) void k_mgemm3(
    const void* A, size_t a_off, int a_kind,
    const ushort_t* __restrict__ Wt, const void* bias,
    float* __restrict__ Cf, ushort_t* __restrict__ Chi,
    int N, int K, int relu, const int* __restrict__ mf)
{
  const int mode = *mf;
  const int rawf32 = (a_kind==0) && (mode==1);
  __shared__ ushort_t Ah[128*64];
  __shared__ ushort_t Bt[128*64];
  const int tid = threadIdx.x;
  const int nbx = gridDim.x, nby = gridDim.y;
  const int total = nbx*nby;
  const int f = blockIdx.y*nbx + blockIdx.x;
  const int qq = total>>3, rr = total&7;
  const int xcd = f&7, pos = f>>3;
  const int wg = (xcd<rr ? xcd*(qq+1) : rr*(qq+1) + (xcd-rr)*qq) + pos;
  const int gm0 = (wg / nby)*128, gn0 = (wg % nby)*128;

  const int wv = tid>>6, lane = tid&63;
  const int mh = (wv&1)*64, nh = (wv>>1)*64;
  const int r16 = lane&15, kq = lane>>4;
  const int sr = tid>>3;        // row within issue (0..31)
  const int sg = tid&7;         // LDS seg (0..7)
  const int srow = tid>>1, chalf = (tid&1)*32;
  const ushort_t* Abf = (const ushort_t*)A + a_off;
  v4f acc[4][4];
  #pragma unroll
  for (int i=0;i<4;i++)
    #pragma unroll
    for (int j=0;j<4;j++) acc[i][j] = (v4f){0.f,0.f,0.f,0.f};

  for (int k0=0; k0<K; k0+=64){
    if (k0) __syncthreads();
    #pragma unroll
    for (int i=0;i<4;i++){
      const int r = i*32 + sr;
      const int gs = (sg ^ (r&7))*8;     // pre-swizzled global segment
      gload_lds16(Wt + (size_t)(gn0+r)*K + k0 + gs, &Bt[r*64 + sg*8]);
    }
    if (!rawf32){
      #pragma unroll
      for (int i=0;i<4;i++){
        const int r = i*32 + sr;
        const int gs = (sg ^ (r&7))*8;
        gload_lds16(Abf + (size_t)(gm0+r)*K + k0 + gs, &Ah[r*64 + sg*8]);
      }
    } else {
      const float* src = (const float*)A + a_off + (size_t)(gm0+srow)*K + k0 + chalf;
      #pragma unroll
      for (int v=0;v<8;v++){
        float4 fq = ((const float4*)src)[v];
        float xs[4] = {fq.x, fq.y, fq.z, fq.w};
        #pragma unroll
        for (int e=0;e<4;e++){
          const int c = chalf + v*4 + e;
          const int idx = srow*64 + (((c>>3) ^ (srow&7))<<3) + (c&7);
          Ah[idx] = f2bfbits(xs[e]);
        }
      }
    }
    __syncthreads();
    #pragma unroll
    for (int kk=0;kk<2;kk++){
      const int seg = kk*4 + kq;         // k-seg this quad consumes
      v8s af[4], bfr[4];
      #pragma unroll
      for (int mt=0;mt<4;mt++){
        const int row = mh + mt*16 + r16;
        af[mt] = *(const v8s*)&Ah[row*64 + ((seg ^ (row&7))<<3)];
      }
      #pragma unroll
      for (int nt=0;nt<4;nt++){
        const int row = nh + nt*16 + r16;
        bfr[nt] = *(const v8s*)&Bt[row*64 + ((seg ^ (row&7))<<3)];
      }
      #pragma unroll
      for (int mt=0;mt<4;mt++){
        #pragma unroll
        for (int nt=0;nt<4;nt++)
          acc[mt][nt] = __builtin_amdgcn_mfma_f32_16x16x32_bf16(af[mt], bfr[nt], acc[mt][nt], 0, 0, 0);
      }
    }
  }
  const int rq = kq*4;
  float bv[4];
  #pragma unroll
  for (int nt=0;nt<4;nt++) bv[nt] = ldin(bias, gn0 + nh + nt*16 + r16, mode);
  const int outf = (Cf != nullptr);
  #pragma unroll
  for (int mt=0;mt<4;mt++){
    #pragma unroll
    for (int r=0;r<4;r++){
      const size_t ro = (size_t)(gm0 + mh + mt*16 + rq + r)*N + gn0 + nh + r16;
      #pragma unroll
      for (int nt=0;nt<4;nt++){
        float v = acc[mt][nt][r] + bv[nt];
        if (relu) v = fmaxf(v, 0.f);
        if (outf) Cf[ro + nt*16] = v;
        else      Chi[ro + nt*16] = f2bfbits(v);
      }
    }
  }
}

// ---------------------------------------------------------------------------
// GEMM + residual + LayerNorm fused — o-proj only (K=256). 64 rows x 256
// cols, 256 thr = 4 waves. NOW: BK=64 + seg-XOR swizzle (R13 recipe ported:
// 4 K-steps instead of 8, LDS reads conflict-free vs 8-way before).
// K-order preserved (seg = kk*4+kq ascending) -> bit-identical numerics.
// ---------------------------------------------------------------------------
__global__ __launch_bounds__(256) void k_mgemm_ln(
    const ushort_t* __restrict__ A,
    const ushort_t* __restrict__ Wt, const void* bias,
    const void* RES, size_t res_off, int res_bf16,
    void* OUT, size_t out_off, int out_bf16,
    const void* g, const void* be,
    int K, const int* __restrict__ mf)
{
  const int mode = *mf;
  __shared__ ushort_t Ah[64*64];
  __shared__ ushort_t Bt[256*64];
  __shared__ float rsum[4][64];
  __shared__ float rsq[4][64];
  const int tid = threadIdx.x;
  const int gm0 = blockIdx.x*64;
  const int wv = tid>>6, lane = tid&63;
  const int nh = wv*64;
  const int r16 = lane&15, kq = lane>>4;
  const int sr = tid>>3;        // row within issue (0..31)
  const int sg = tid&7;         // LDS seg (0..7)
  v4f acc[4][4];
  #pragma unroll
  for (int i=0;i<4;i++)
    #pragma unroll
    for (int j=0;j<4;j++) acc[i][j] = (v4f){0.f,0.f,0.f,0.f};

  for (int k0=0; k0<K; k0+=64){
    if (k0) __syncthreads();
    // A: 64 rows -> 2 issues
    #pragma unroll
    for (int i=0;i<2;i++){
      const int r = i*32 + sr;
      const int gs = (sg ^ (r&7))*8;
      gload_lds16(A + (size_t)(gm0+r)*K + k0 + gs, &Ah[r*64 + sg*8]);
    }
    // B: 256 rows -> 8 issues
    #pragma unroll
    for (int i=0;i<8;i++){
      const int r = i*32 + sr;
      const int gs = (sg ^ (r&7))*8;
      gload_lds16(Wt + (size_t)r*K + k0 + gs, &Bt[r*64 + sg*8]);
    }
    __syncthreads();
    #pragma unroll
    for (int kk=0;kk<2;kk++){
      const int seg = kk*4 + kq;
      v8s af[4], bfr[4];
      #pragma unroll
      for (int mt=0;mt<4;mt++){
        const int row = mt*16 + r16;
        af[mt] = *(const v8s*)&Ah[row*64 + ((seg ^ (row&7))<<3)];
      }
      #pragma unroll
      for (int nt=0;nt<4;nt++){
        const int row = nh + nt*16 + r16;
        bfr[nt] = *(const v8s*)&Bt[row*64 + ((seg ^ (row&7))<<3)];
      }
      #pragma unroll
      for (int mt=0;mt<4;mt++){
        #pragma unroll
        for (int nt=0;nt<4;nt++)
          acc[mt][nt] = __builtin_amdgcn_mfma_f32_16x16x32_bf16(af[mt], bfr[nt], acc[mt][nt], 0, 0, 0);
      }
    }
  }
  // ---- z = acc + bias + residual (in place) ----
  float bv[4];
  #pragma unroll
  for (int nt=0;nt<4;nt++) bv[nt] = ldin(bias, nh + nt*16 + r16, mode);
  #pragma unroll
  for (int mt=0;mt<4;mt++){
    #pragma unroll
    for (int r=0;r<4;r++){
      const int row_l = mt*16 + kq*4 + r;
      const size_t rbase = (size_t)(gm0 + row_l)*256;
      #pragma unroll
      for (int nt=0;nt<4;nt++){
        const int col = nh + nt*16 + r16;
        const float rv = res_bf16 ? bf2f(((const ushort_t*)RES)[res_off + rbase + col])
                                  : ldin(RES, res_off + rbase + col, mode);
        acc[mt][nt][r] = acc[mt][nt][r] + bv[nt] + rv;
      }
    }
  }
  // ---- pass 1: row sums -> mean ----
  #pragma unroll
  for (int mt=0;mt<4;mt++){
    #pragma unroll
    for (int r=0;r<4;r++){
      float s = acc[mt][0][r] + acc[mt][1][r] + acc[mt][2][r] + acc[mt][3][r];
      #pragma unroll
      for (int o=1;o<16;o<<=1) s += __shfl_xor(s, o);
      if (r16==0) rsum[wv][mt*16 + kq*4 + r] = s;
    }
  }
  __syncthreads();
  float mean[4][4];
  #pragma unroll
  for (int mt=0;mt<4;mt++){
    #pragma unroll
    for (int r=0;r<4;r++){
      const int row_l = mt*16 + kq*4 + r;
      mean[mt][r] = (rsum[0][row_l]+rsum[1][row_l]+rsum[2][row_l]+rsum[3][row_l]) * (1.f/256.f);
    }
  }
  // ---- pass 2: row sumsq of (z-mean) -> var ----
  #pragma unroll
  for (int mt=0;mt<4;mt++){
    #pragma unroll
    for (int r=0;r<4;r++){
      const float m = mean[mt][r];
      float s2 = 0.f;
      #pragma unroll
      for (int nt=0;nt<4;nt++){ const float d = acc[mt][nt][r]-m; s2 += d*d; }
      #pragma unroll
      for (int o=1;o<16;o<<=1) s2 += __shfl_xor(s2, o);
      if (r16==0) rsq[wv][mt*16 + kq*4 + r] = s2;
    }
  }
  __syncthreads();
  // ---- normalize + affine + write ----
  float gv[4], bev[4];
  #pragma unroll
  for (int nt=0;nt<4;nt++){
    gv[nt]  = ldin(g,  nh + nt*16 + r16, mode);
    bev[nt] = ldin(be, nh + nt*16 + r16, mode);
  }
  #pragma unroll
  for (int mt=0;mt<4;mt++){
    #pragma unroll
    for (int r=0;r<4;r++){
      const int row_l = mt*16 + kq*4 + r;
      const float var = (rsq[0][row_l]+rsq[1][row_l]+rsq[2][row_l]+rsq[3][row_l]) * (1.f/256.f);
      const float inv = rsqrtf(var + 1e-5f);
      const float m = mean[mt][r];
      const size_t obase = (size_t)(gm0 + row_l)*256;
      #pragma unroll
      for (int nt=0;nt<4;nt++){
        const int col = nh + nt*16 + r16;
        const float o = (acc[mt][nt][r]-m)*inv*gv[nt] + bev[nt];
        if (out_bf16) ((ushort_t*)OUT)[obase + col] = f2bfbits(o);
        else          stout(OUT, out_off + obase + col, mode, o);
      }
    }
  }
}

// ---------------------------------------------------------------------------
// KV split/transpose prep (unchanged)
// ---------------------------------------------------------------------------
__global__ __launch_bounds__(256) void k_kvsplit(
    const float* __restrict__ kws, const float* __restrict__ vws,
    ushort_t* __restrict__ khi, ushort_t* __restrict__ klo,
    ushort_t* __restrict__ vthi, ushort_t* __restrict__ vtlo)
{
  const int row = blockIdx.x;        // 0..255 = b*32 + key
  const int b = row >> 5, key = row & 31;
  const int t = threadIdx.x;         // dim 0..255
  const float f = kws[(size_t)row*256 + t];
  const ushort_t fh = f2bfbits(f);
  khi[(size_t)row*256 + t] = fh;
  klo[(size_t)row*256 + t] = f2bfbits(f - bf2f(fh));
  const float g = vws[(size_t)row*256 + t];
  const ushort_t gh = f2bfbits(g);
  const size_t vt = ((size_t)b*256 + t)*32 + key;
  vthi[vt] = gh;
  vtlo[vt] = f2bfbits(g - bf2f(gh));
}

// ---------------------------------------------------------------------------
// A2: MFMA MHA. P tile is WAVE-PRIVATE (P[wv] only touched by wave wv), so
// no block-wide barriers are needed in the head loop — within-wave LDS
// write->read ordering is enforced by compiler-inserted lgkmcnt waits.
// (Removes 16 __syncthreads per block vs R13.)
// ---------------------------------------------------------------------------
__global__ __launch_bounds__(256) void k_attn2(
    const ushort_t* __restrict__ qcH,
    ushort_t* __restrict__ aoh,
    const ushort_t* __restrict__ khi, const ushort_t* __restrict__ klo,
    const ushort_t* __restrict__ vthi, const ushort_t* __restrict__ vtlo,
    const char* __restrict__ tmask, int r0)
{
  __shared__ float P[4][16][36];
  const int tid = threadIdx.x;
  const int wv = tid>>6, lane = tid&63;
  const int lrow0 = blockIdx.x*64 + wv*16;
  const int b = (r0 + lrow0)/NVTOK;
  const int m16 = lane&15;
  const int kq = lane>>4;
  const int q8 = kq*8;
  const int key0 = m16, key1 = m16+16;
  const bool msk0 = tmask[b*LT + key0] != 0;
  const bool msk1 = tmask[b*LT + key1] != 0;
  const float scale = 0.17677669529663687f;

  for (int h=0; h<8; ++h){
    const size_t qoff = (size_t)(lrow0 + m16)*256 + h*32 + q8;
    const v8s qh = *(const v8s*)&qcH[qoff];
    const size_t kb0 = ((size_t)(b*32+key0)*256) + h*32 + q8;
    const size_t kb1 = ((size_t)(b*32+key1)*256) + h*32 + q8;
    const v8s kh0 = *(const v8s*)&khi[kb0];
    const v8s kl0 = *(const v8s*)&klo[kb0];
    const v8s kh1 = *(const v8s*)&khi[kb1];
    const v8s kl1 = *(const v8s*)&klo[kb1];
    v4f s0 = (v4f){0.f,0.f,0.f,0.f}, s1 = (v4f){0.f,0.f,0.f,0.f};
    s0 = __builtin_amdgcn_mfma_f32_16x16x32_bf16(qh, kh0, s0, 0,0,0);
    s0 = __builtin_amdgcn_mfma_f32_16x16x32_bf16(qh, kl0, s0, 0,0,0);
    s1 = __builtin_amdgcn_mfma_f32_16x16x32_bf16(qh, kh1, s1, 0,0,0);
    s1 = __builtin_amdgcn_mfma_f32_16x16x32_bf16(qh, kl1, s1, 0,0,0);
    float e0[4], e1[4], inv[4];
    #pragma unroll
    for (int r=0;r<4;r++){
      const float a0 = msk0 ? -1e9f : s0[r]*scale;
      const float a1 = msk1 ? -1e9f : s1[r]*scale;
      float mx = fmaxf(a0,a1);
      #pragma unroll
      for (int o=1;o<16;o<<=1) mx = fmaxf(mx, __shfl_xor(mx,o));
      const float x0 = __expf(a0-mx), x1 = __expf(a1-mx);
      float dn = x0+x1;
      #pragma unroll
      for (int o=1;o<16;o<<=1) dn += __shfl_xor(dn,o);
      e0[r]=x0; e1[r]=x1; inv[r] = 1.f/dn;
    }
    #pragma unroll
    for (int r=0;r<4;r++){
      P[wv][kq*4+r][key0] = e0[r];
      P[wv][kq*4+r][key1] = e1[r];
    }
    // no __syncthreads: P[wv] is wave-private; lgkmcnt orders within wave
    float pv[8];
    *(float4*)&pv[0] = *(const float4*)&P[wv][m16][q8];
    *(float4*)&pv[4] = *(const float4*)&P[wv][m16][q8+4];
    v8s ph;
    #pragma unroll
    for (int j=0;j<8;j++) ph[j] = (short)f2bfbits(pv[j]);
    const size_t vb0 = ((size_t)(b*256 + h*32 + m16)*32) + q8;
    const size_t vb1 = ((size_t)(b*256 + h*32 + 16 + m16)*32) + q8;
    const v8s vh0 = *(const v8s*)&vthi[vb0];
    const v8s vl0 = *(const v8s*)&vtlo[vb0];
    const v8s vh1 = *(const v8s*)&vthi[vb1];
    const v8s vl1 = *(const v8s*)&vtlo[vb1];
    v4f o0 = (v4f){0.f,0.f,0.f,0.f}, o1 = (v4f){0.f,0.f,0.f,0.f};
    o0 = __builtin_amdgcn_mfma_f32_16x16x32_bf16(ph, vh0, o0, 0,0,0);
    o0 = __builtin_amdgcn_mfma_f32_16x16x32_bf16(ph, vl0, o0, 0,0,0);
    o1 = __builtin_amdgcn_mfma_f32_16x16x32_bf16(ph, vh1, o1, 0,0,0);
    o1 = __builtin_amdgcn_mfma_f32_16x16x32_bf16(ph, vl1, o1, 0,0,0);
    // no __syncthreads: next head's P writes are same-wave, ordered by lgkmcnt
    #pragma unroll
    for (int r=0;r<4;r++){
      const size_t ro = (size_t)(lrow0 + kq*4 + r)*256 + h*32;
      aoh[ro + m16]      = f2bfbits(o0[r]*inv[r]);
      aoh[ro + 16 + m16] = f2bfbits(o1[r]*inv[r]);
    }
  }
}

// ---------------------------------------------------------------------------
// residual + two-pass LayerNorm (text side, unchanged)
// ---------------------------------------------------------------------------
__global__ __launch_bounds__(256) void k_add_ln(
    const float* __restrict__ X, const void* R, size_t r_off, int r_f32,
    void* OUT, size_t o_off, int o_f32,
    void* OUT2, size_t o2_off,
    const void* g, const void* be, const int* __restrict__ mf)
{
  const int mode = *mf;
  const int row = blockIdx.x; const int t = threadIdx.x;
  const size_t idx = (size_t)row*256 + t;
  __shared__ float red[4];
  const float rv = r_f32 ? ((const float*)R)[r_off+idx] : ldin(R, r_off+idx, mode);
  const float v = X[idx] + rv;
  const float m = block_sum(v, red) * (1.f/256.f);
  __syncthreads();
  const float d = v - m;
  const float var = block_sum(d*d, red) * (1.f/256.f);
  const float o = d*rsqrtf(var+1e-5f)*ldin(g,t,mode) + ldin(be,t,mode);
  if (o_f32) ((float*)OUT)[o_off+idx] = o;
  else       stout(OUT, o_off+idx, mode, o);
  if (OUT2)  stout(OUT2, o2_off+idx, mode, o);
}

// ---------------------------------------------------------------------------
// LN2 (vis): v = X + RH ; out = mode-typed at offset
// ---------------------------------------------------------------------------
__global__ __launch_bounds__(256) void k_add_ln_pres(
    const float* __restrict__ X,
    const ushort_t* __restrict__ RH,
    void* OUT, size_t o_off,
    const void* g, const void* be, const int* __restrict__ mf)
{
  const int mode = *mf;
  const int row = blockIdx.x; const int t = threadIdx.x;
  const size_t idx = (size_t)row*256 + t;
  __shared__ float red[4];
  const float rv = bf2f(RH[idx]);
  const float v = X[idx] + rv;
  const float m = block_sum(v, red) * (1.f/256.f);
  __syncthreads();
  const float d = v - m;
  const float var = block_sum(d*d, red) * (1.f/256.f);
  const float o = d*rsqrtf(var+1e-5f)*ldin(g,t,mode) + ldin(be,t,mode);
  stout(OUT, o_off+idx, mode, o);
}

// ---------------------------------------------------------------------------
extern "C" void kernel_launch(void* const* d_in, const int* in_sizes, int n_in,
                              void* d_out, int out_size, void* d_ws, size_t ws_size,
                              hipStream_t stream)
{
  (void)n_in; (void)out_size;
  const void* vis_tokens = d_in[0];
  const void* text_tokens= d_in[1];
  const void* vis_value  = d_in[2];
  const void* ref_w = d_in[3];  const void* ref_b = d_in[4];
  const void* off_w = d_in[5];  const void* off_b = d_in[6];
  const void* aw_w  = d_in[7];  const void* aw_b  = d_in[8];
  const void* vproj_w = d_in[9];  const void* vproj_b = d_in[10];
  const void* oproj_w = d_in[11]; const void* oproj_b = d_in[12];
  const void* lvi_out_w = d_in[13]; const void* lvi_out_b = d_in[14];
  const void* lvi_n1_s = d_in[15];  const void* lvi_n1_b = d_in[16];
  const void* lvi_f1_w = d_in[17];  const void* lvi_f1_b = d_in[18];
  const void* lvi_f2_w = d_in[19];  const void* lvi_f2_b = d_in[20];
  const void* lvi_n2_s = d_in[21];  const void* lvi_n2_b = d_in[22];
  const void* mha_qw = d_in[23]; const void* mha_qb = d_in[24];
  const void* mha_kw = d_in[25]; const void* mha_kb = d_in[26];
  const void* mha_vw = d_in[27]; const void* mha_vb = d_in[28];
  const void* mha_ow = d_in[29]; const void* mha_ob = d_in[30];
  const void* vli_out_w = d_in[31]; const void* vli_out_b = d_in[32];
  const void* vli_n1_s = d_in[33];  const void* vli_n1_b = d_in[34];
  const void* vli_f1_w = d_in[35];  const void* vli_f1_b = d_in[36];
  const void* vli_f2_w = d_in[37];  const void* vli_f2_b = d_in[38];
  const void* vli_n2_s = d_in[39];  const void* vli_n2_b = d_in[40];
  const char* tmask = (const char*)d_in[43];
  const char* vmask = (const char*)d_in[44];

  // ---- workspace layout ----
  char* ws = (char*)d_ws;
  int*   flag    = (int*)  (ws + 0);               // 256 B
  float* loc_ws  = (float*)(ws + 256);             // 196608
  float* aw_ws   = (float*)(ws + 196864);          //  98304
  float* ctxt_ws = (float*)(ws + 295168);          // 262144
  float* t_ws    = (float*)(ws + 557312);          // 262144
  float* tout_ws = (float*)(ws + 819456);          // 262144
  float* k_ws    = (float*)(ws + 1081600);         // 262144
  float* v_ws    = (float*)(ws + 1343744);         // 262144
  ushort_t* wtq  = (ushort_t*)(ws + 1605888ull);   // 131072 B
  ushort_t* wto  = (ushort_t*)(ws + 1736960ull);   // 131072 B
  ushort_t* wtf1 = (ushort_t*)(ws + 1868032ull);   // 524288 B
  ushort_t* wtf2 = (ushort_t*)(ws + 2392320ull);   // 524288 B
  ushort_t* wtk   = (ushort_t*)(ws + 2916608ull);  // 131072 B (mha_kw^T)
  ushort_t* wtv   = (ushort_t*)(ws + 3047680ull);  // 131072 B (mha_vw^T)
  ushort_t* wtop  = (ushort_t*)(ws + 3178752ull);  // 131072 B (oproj_w^T)
  ushort_t* wtlo  = (ushort_t*)(ws + 3309824ull);  // 131072 B (lvi_out_w^T)
  ushort_t* wtlf1 = (ushort_t*)(ws + 3440896ull);  // 524288 B (lvi_f1_w^T)
  ushort_t* wtlf2 = (ushort_t*)(ws + 3965184ull);  // 524288 B (lvi_f2_w^T)
  float* hbuf_t   = (float*)(ws + 4489472ull);     // 1048576 B (256x1024)
  float* ybuf     = (float*)(ws + 5538048ull);     // 262144 B
  float* fbuf     = (float*)(ws + 5800192ull);     // 262144 B
  ushort_t* khi   = (ushort_t*)(ws + 6062336ull);  // 131072 B
  ushort_t* klo   = (ushort_t*)(ws + 6193408ull);  // 131072 B
  ushort_t* vthi  = (ushort_t*)(ws + 6324480ull);  // 131072 B
  ushort_t* vtlo  = (ushort_t*)(ws + 6455552ull);  // 131072 B
  const size_t fe = 6586624ull;                    // chunk region start

  // per-row chunk bytes (3584 B/row):
  //   region0 (1024 B): ubuf fp32 (f2 out); first 512 B alias qc bf16
  //   region1 ( 512 B): v1 bf16
  //   region2 (2048 B): hb bf16; first 512 B alias ao bf16 (dead pre-f1)
  long long R_ll = 128;
  if (ws_size > fe) R_ll = (long long)((ws_size - fe) / 3584ull);
  if (R_ll > (long long)MVIS) R_ll = MVIS;
  R_ll &= ~127LL;
  if (R_ll < 128) R_ll = 128;
  const int R = (int)R_ll;
  ushort_t* qcH  = (ushort_t*)(ws + fe);                      // region0 alias
  float*    ubuf = (float*)   (ws + fe);                      // region0
  ushort_t* v1H  = (ushort_t*)(ws + fe + (size_t)R*1024ull);  // region1
  ushort_t* hbH  = (ushort_t*)(ws + fe + (size_t)R*1536ull);  // region2
  ushort_t* aoH  = hbH;                                       // alias (dead pre-f1)

  // ---- dtype detect ----
  int ndw = in_sizes[1]/2; if (ndw < 1) ndw = 1;
  k_detect<<<1,256,0,stream>>>((const uint_t*)text_tokens, ndw, flag);

  // ---- weight transposes for MFMA GEMMs ----
  k_transpose<<<dim3(8,8),  256,0,stream>>>(mha_qw,    wtq,   256, 256,  flag);
  k_transpose<<<dim3(8,8),  256,0,stream>>>(mha_ow,    wto,   256, 256,  flag);
  k_transpose<<<dim3(8,32), 256,0,stream>>>(vli_f1_w,  wtf1,  256, 1024, flag);
  k_transpose<<<dim3(32,8), 256,0,stream>>>(vli_f2_w,  wtf2,  1024, 256, flag);
  k_transpose<<<dim3(8,8),  256,0,stream>>>(mha_kw,    wtk,   256, 256,  flag);
  k_transpose<<<dim3(8,8),  256,0,stream>>>(mha_vw,    wtv,   256, 256,  flag);
  k_transpose<<<dim3(8,8),  256,0,stream>>>(oproj_w,   wtop,  256, 256,  flag);
  k_transpose<<<dim3(8,8),  256,0,stream>>>(lvi_out_w, wtlo,  256, 256,  flag);
  k_transpose<<<dim3(8,32), 256,0,stream>>>(lvi_f1_w,  wtlf1, 256, 1024, flag);
  k_transpose<<<dim3(32,8), 256,0,stream>>>(lvi_f2_w,  wtlf2, 1024, 256, flag);

  // ---- text side ----
  k_text_prep<<<MTEXT,256,0,stream>>>(text_tokens, ref_w, ref_b, off_w, off_b,
                                      aw_w, aw_b, loc_ws, aw_ws, flag);
  k_deform<<<MTEXT*NHEAD,64,0,stream>>>(vis_value, vmask, vproj_w, vproj_b,
                                        loc_ws, aw_ws, ctxt_ws, flag);

  // attn-out path: y = ctx@oproj + b ; z = y@lvi_out + b ; t = LN(text + z)
  {
    dim3 g22(2,2);
    k_mgemm<<<g22,256,0,stream>>>(ctxt_ws, 0, 1, wtop, oproj_b, ybuf, 256, 256, 0, flag);
    k_mgemm<<<g22,256,0,stream>>>(ybuf,    0, 1, wtlo, lvi_out_b, fbuf, 256, 256, 0, flag);
    k_add_ln<<<MTEXT,256,0,stream>>>(fbuf, text_tokens, 0, 0,
                                     t_ws, 0, 1, nullptr, 0, lvi_n1_s, lvi_n1_b, flag);
  }
  // ffn path: h = relu(t@f1+b1) ; f = h@f2+b2 ; tout = LN(t + f)
  {
    dim3 g28(2,8), g22(2,2);
    k_mgemm<<<g28,256,0,stream>>>(t_ws,   0, 1, wtlf1, lvi_f1_b, hbuf_t, 1024, 256, 1, flag);
    k_mgemm<<<g22,256,0,stream>>>(hbuf_t, 0, 1, wtlf2, lvi_f2_b, fbuf,   256, 1024, 0, flag);
    k_add_ln<<<MTEXT,256,0,stream>>>(fbuf, t_ws, 0, 1,
                                     tout_ws, 0, 1, d_out, VISSZ, lvi_n2_s, lvi_n2_b, flag);
  }
  // k/v projection of text_out + bf16 hi/lo split (+ V transpose)
  {
    dim3 g22(2,2);
    k_mgemm<<<g22,256,0,stream>>>(tout_ws, 0, 1, wtk, mha_kb, k_ws, 256, 256, 0, flag);
    k_mgemm<<<g22,256,0,stream>>>(tout_ws, 0, 1, wtv, mha_vb, v_ws, 256, 256, 0, flag);
    k_kvsplit<<<256,256,0,stream>>>(k_ws, v_ws, khi, klo, vthi, vtlo);
  }

  // ---- vis side, chunked by R rows ----
  for (int r0 = 0; r0 < MVIS; r0 += R){
    const int nr = (MVIS - r0 < R) ? (MVIS - r0) : R;   // multiple of 128
    dim3 g2(nr/128, 2), g8(nr/128, 8);
    k_mgemm3<<<g2,256,0,stream>>>(vis_tokens, (size_t)r0*256, 0,
                                  wtq, mha_qb, nullptr, qcH, 256, 256, 0, flag);
    k_attn2<<<nr/64,256,0,stream>>>(qcH, aoH, khi, klo, vthi, vtlo, tmask, r0);
    // o-proj + residual(vis_tokens) + LN1 -> v1H (bf16)  [K=256: fused OK]
    k_mgemm_ln<<<nr/64,256,0,stream>>>(aoH, wto, mha_ob,
                                       vis_tokens, (size_t)r0*256, 0,
                                       v1H, 0, 1,
                                       vli_n1_s, vli_n1_b, 256, flag);
    k_mgemm3<<<g8,256,0,stream>>>(v1H, 0, 2,
                                  wtf1, vli_f1_b, nullptr, hbH, 1024, 256, 1, flag);
    // f2 unfused (proven 128x128 N-split path) -> ubuf fp32
    k_mgemm3<<<g2,256,0,stream>>>(hbH, 0, 2,
                                  wtf2, vli_f2_b, ubuf, nullptr, 256, 1024, 0, flag);
    // LN2: ubuf + v1H -> d_out
    k_add_ln_pres<<<nr,256,0,stream>>>(ubuf, v1H,
                                       d_out, (size_t)r0*256, vli_n2_s, vli_n2_b, flag);
  }
}

// Round 15
// 859.857 us; speedup vs baseline: 1.3207x; 1.0013x over previous
//
#include <hip/hip_runtime.h>
#include <hip/hip_bf16.h>
#include <math.h>

typedef __hip_bfloat16 bf16;
typedef unsigned short ushort_t;
typedef unsigned int uint_t;
typedef short v8s __attribute__((ext_vector_type(8)));
typedef float v4f __attribute__((ext_vector_type(4)));

#define NVTOK 9072
#define BATCH 8
#define LT 32
#define DMODEL 256
#define NHEAD 8
#define DHEAD 32
#define MVIS (BATCH*NVTOK)   /* 72576 */
#define MTEXT (BATCH*LT)     /* 256 */
#define VISSZ 18579456ull    /* MVIS*256 elements */

__device__ __forceinline__ float bf2f(ushort_t u){ return __uint_as_float(((uint_t)u)<<16); }
__device__ __forceinline__ ushort_t f2bfbits(float f){
  __hip_bfloat16 h = __float2bfloat16(f);
  union { __hip_bfloat16 h; ushort_t u; } c; c.h = h; return c.u;
}
// mode: 0 = buffers hold bf16, 1 = buffers hold fp32
__device__ __forceinline__ float ldin(const void* p, size_t i, int mode){
  return mode ? ((const float*)p)[i] : bf2f(((const ushort_t*)p)[i]);
}
__device__ __forceinline__ void stout(void* p, size_t i, int mode, float v){
  if (mode) ((float*)p)[i] = v; else ((ushort_t*)p)[i] = f2bfbits(v);
}

// async global->LDS, 16 B per lane (LDS dest = wave-uniform base + lane*16).
__device__ __forceinline__ void gload_lds16(const void* g, void* l){
  __builtin_amdgcn_global_load_lds(
      (const __attribute__((address_space(1))) unsigned int*)g,
      (__attribute__((address_space(3))) unsigned int*)l, 16, 0, 0);
}

// ---------------------------------------------------------------------------
// D0: dtype detector (unchanged)
// ---------------------------------------------------------------------------
__global__ void k_detect(const uint_t* __restrict__ buf, int n_avail, int* __restrict__ flag){
  __shared__ int zc, bc;
  if (threadIdx.x==0){ zc=0; bc=0; }
  __syncthreads();
  int stride = n_avail/2048; if (stride < 1) stride = 1;
  int nz=0, nb=0;
  for (int i=threadIdx.x; i<2048; i+=256){
    long long idx = (long long)i*stride;
    if (idx >= n_avail) break;
    uint_t d = buf[idx];
    uint_t lo = d & 0xFFFFu;
    int e = (int)((lo >> 7) & 0xFF);
    if (lo == 0) nz++;
    else if (e >= 90 && e <= 160) nb++;
  }
  atomicAdd(&zc, nz); atomicAdd(&bc, nb);
  __syncthreads();
  if (threadIdx.x==0){
    int mode;
    if (zc > 1024) mode = 1;
    else if (bc > 1228) mode = 0;
    else mode = 1;
    *flag = mode;
  }
}

// ---------------------------------------------------------------------------
// W-transpose (unchanged)
// ---------------------------------------------------------------------------
__global__ __launch_bounds__(256) void k_transpose(
    const void* W, ushort_t* __restrict__ Wt, int K, int N,
    const int* __restrict__ mf)
{
  const int mode = *mf;
  __shared__ float tile[32][33];
  const int k0 = blockIdx.x*32, n0 = blockIdx.y*32;
  const int c = threadIdx.x & 31, r8 = threadIdx.x >> 5;
  #pragma unroll
  for (int i=0;i<4;i++){
    const int kk = r8 + i*8;
    tile[kk][c] = ldin(W, (size_t)(k0+kk)*N + n0 + c, mode);
  }
  __syncthreads();
  #pragma unroll
  for (int i=0;i<4;i++){
    const int nn = r8 + i*8;
    Wt[(size_t)(n0+nn)*K + k0 + c] = f2bfbits(tile[c][nn]);
  }
}

// ---------------------------------------------------------------------------
// T1: text prep (unchanged)
// ---------------------------------------------------------------------------
__global__ __launch_bounds__(256) void k_text_prep(
    const void* text,
    const void* ref_w, const void* ref_b,
    const void* off_w, const void* off_b,
    const void* aw_w,  const void* aw_b,
    float* __restrict__ loc_out, float* __restrict__ aw_out,
    const int* __restrict__ mf)
{
  const int mode = *mf;
  const int r = blockIdx.x;
  const int t = threadIdx.x;
  __shared__ float x[256];
  __shared__ float refv[6];
  __shared__ float offv[192];
  __shared__ float logit[96];
  x[t] = ldin(text, (size_t)r*256 + t, mode);
  __syncthreads();
  if (t < 192) {
    float s = 0.f;
    for (int k=0;k<256;k++) s += x[k]*ldin(off_w, (size_t)k*192+t, mode);
    offv[t] = s + ldin(off_b, t, mode);
  } else if (t < 198) {
    int j = t-192;
    float s = 0.f;
    for (int k=0;k<256;k++) s += x[k]*ldin(ref_w, (size_t)k*6+j, mode);
    s += ldin(ref_b, j, mode);
    refv[j] = 1.f/(1.f+expf(-s));
  }
  if (t < 96) {
    float s = 0.f;
    for (int k=0;k<256;k++) s += x[k]*ldin(aw_w, (size_t)k*96+t, mode);
    logit[t] = s + ldin(aw_b, t, mode);
  }
  __syncthreads();
  if (t < 8) {
    float mx = -1e30f;
    for (int j=0;j<12;j++) mx = fmaxf(mx, logit[t*12+j]);
    float e[12]; float den = 0.f;
    for (int j=0;j<12;j++){ e[j] = expf(logit[t*12+j]-mx); den += e[j]; }
    float inv = 1.f/den;
    for (int j=0;j<12;j++) aw_out[(size_t)r*96 + t*12 + j] = e[j]*inv;
  }
  if (t < 192) {
    int rem = t % 24;
    int l = rem >> 3;
    int c = t & 1;
    const float normW[3] = {96.f,48.f,24.f};
    const float normH[3] = {72.f,36.f,18.f};
    float nrm = (c==0) ? normW[l] : normH[l];
    loc_out[(size_t)r*192 + t] = refv[l*2+c] + offv[t]/nrm;
  }
}

// ---------------------------------------------------------------------------
// T2: deformable sampling, lazy vproj (unchanged)
// ---------------------------------------------------------------------------
__global__ __launch_bounds__(64) void k_deform(
    const void* vis_value, const char* __restrict__ vmask,
    const void* vproj_w, const void* vproj_b,
    const float* __restrict__ loc, const float* __restrict__ aw,
    float* __restrict__ ctx_out, const int* __restrict__ mf)
{
  const int mode = *mf;
  const int blk = blockIdx.x;      // r*8 + h
  const int r = blk >> 3;
  const int h = blk & 7;
  const int b = r >> 5;
  const int t = threadIdx.x;
  const int Hs[3] = {72,36,18};
  const int Wsz[3] = {96,48,24};
  const int stl[3] = {0,6912,8640};
  float s0=0.f,s1=0.f,s2=0.f,s3=0.f, wsum=0.f;
  for (int l=0;l<3;l++){
    for (int p=0;p<4;p++){
      const int sIdx = blk*12 + l*4 + p;
      const float a  = aw[sIdx];
      const float X = loc[sIdx*2+0]*(float)Wsz[l] - 0.5f;
      const float Y = loc[sIdx*2+1]*(float)Hs[l] - 0.5f;
      const float x0f = floorf(X), y0f = floorf(Y);
      const int x0 = (int)x0f, y0 = (int)y0f;
      const float wx = X-x0f, wy = Y-y0f;
      const float cw[4] = {(1.f-wx)*(1.f-wy), wx*(1.f-wy), (1.f-wx)*wy, wx*wy};
      const int cx[4] = {x0,x0+1,x0,x0+1};
      const int cy[4] = {y0,y0,y0+1,y0+1};
      for (int c=0;c<4;c++){
        if (cx[c]>=0 && cx[c]<Wsz[l] && cy[c]>=0 && cy[c]<Hs[l]){
          const size_t pos = (size_t)b*NVTOK + stl[l] + cy[c]*Wsz[l] + cx[c];
          if (vmask[pos]) continue;
          const float w = a*cw[c];
          wsum += w;
          const size_t base = pos*256 + t*4;
          s0 += w*ldin(vis_value, base+0, mode);
          s1 += w*ldin(vis_value, base+1, mode);
          s2 += w*ldin(vis_value, base+2, mode);
          s3 += w*ldin(vis_value, base+3, mode);
        }
      }
    }
  }
  __shared__ float sh[256];
  sh[t*4+0]=s0; sh[t*4+1]=s1; sh[t*4+2]=s2; sh[t*4+3]=s3;
  __syncthreads();
  if (t < 32) {
    const int col = h*32 + t;
    float acc = wsum * ldin(vproj_b, col, mode);
    for (int k=0;k<256;k++) acc += sh[k]*ldin(vproj_w, (size_t)k*256+col, mode);
    ctx_out[(size_t)r*256 + col] = acc;
  }
}

__device__ __forceinline__ float block_sum(float v, float* red){
  float sm = v;
  #pragma unroll
  for (int o=32;o>0;o>>=1) sm += __shfl_down(sm,o);
  const int t = threadIdx.x;
  __syncthreads();
  if ((t&63)==0) red[t>>6] = sm;
  __syncthreads();
  return red[0]+red[1]+red[2]+red[3];
}

// ---------------------------------------------------------------------------
// MFMA GEMM (text side, unchanged — tiny M, full hi/lo precision)
// ---------------------------------------------------------------------------
__global__ __launch_bounds__(256) void k_mgemm(
    const void* A, size_t a_off, int a_kind,
    const ushort_t* __restrict__ Wt, const void* bias, float* __restrict__ C,
    int N, int K, int relu, const int* __restrict__ mf)
{
  const int mode = *mf;
  const int split = (a_kind==1) || (mode==1);
  __shared__ ushort_t Ah[128*32];
  __shared__ ushort_t Al[128*32];
  __shared__ ushort_t Bt[128*32];
  const int tid = threadIdx.x;
  const int gm0 = blockIdx.x*128, gn0 = blockIdx.y*128;
  const int wv = tid>>6, lane = tid&63;
  const int mh = (wv&1)*64, nh = (wv>>1)*64;
  const int r16 = lane&15, q8 = (lane>>4)*8;
  const int srow = tid>>1, sseg = (tid&1)*16;
  v4f acc[4][4];
  #pragma unroll
  for (int i=0;i<4;i++)
    #pragma unroll
    for (int j=0;j<4;j++) acc[i][j] = (v4f){0.f,0.f,0.f,0.f};

  for (int k0=0; k0<K; k0+=32){
    if (k0) __syncthreads();
    {
      const ushort_t* src = Wt + (size_t)(gn0+srow)*K + k0 + sseg;
      ((uint4*)&Bt[srow*32+sseg])[0]   = ((const uint4*)src)[0];
      ((uint4*)&Bt[srow*32+sseg+8])[0] = ((const uint4*)src)[1];
    }
    if (!split){
      const ushort_t* src = (const ushort_t*)A + a_off + (size_t)(gm0+srow)*K + k0 + sseg;
      ((uint4*)&Ah[srow*32+sseg])[0]   = ((const uint4*)src)[0];
      ((uint4*)&Ah[srow*32+sseg+8])[0] = ((const uint4*)src)[1];
    } else {
      const float* src = (const float*)A + a_off + (size_t)(gm0+srow)*K + k0 + sseg;
      #pragma unroll
      for (int v=0;v<4;v++){
        float4 f = ((const float4*)src)[v];
        float xs[4] = {f.x, f.y, f.z, f.w};
        #pragma unroll
        for (int e=0;e<4;e++){
          const int idx = srow*32 + sseg + v*4 + e;
          const ushort_t h = f2bfbits(xs[e]);
          Ah[idx] = h;
          Al[idx] = f2bfbits(xs[e] - bf2f(h));
        }
      }
    }
    __syncthreads();
    v8s af[4], bfr[4], al[4];
    #pragma unroll
    for (int mt=0;mt<4;mt++){
      af[mt] = *(const v8s*)&Ah[(mh + mt*16 + r16)*32 + q8];
      if (split) al[mt] = *(const v8s*)&Al[(mh + mt*16 + r16)*32 + q8];
    }
    #pragma unroll
    for (int nt=0;nt<4;nt++)
      bfr[nt] = *(const v8s*)&Bt[(nh + nt*16 + r16)*32 + q8];
    #pragma unroll
    for (int mt=0;mt<4;mt++){
      #pragma unroll
      for (int nt=0;nt<4;nt++){
        acc[mt][nt] = __builtin_amdgcn_mfma_f32_16x16x32_bf16(af[mt], bfr[nt], acc[mt][nt], 0, 0, 0);
        if (split)
          acc[mt][nt] = __builtin_amdgcn_mfma_f32_16x16x32_bf16(al[mt], bfr[nt], acc[mt][nt], 0, 0, 0);
      }
    }
  }
  const int rq = (lane>>4)*4;
  float bv[4];
  #pragma unroll
  for (int nt=0;nt<4;nt++) bv[nt] = ldin(bias, gn0 + nh + nt*16 + r16, mode);
  #pragma unroll
  for (int mt=0;mt<4;mt++){
    #pragma unroll
    for (int r=0;r<4;r++){
      const size_t ro = (size_t)(gm0 + mh + mt*16 + rq + r)*N + gn0 + nh + r16;
      #pragma unroll
      for (int nt=0;nt<4;nt++){
        float v = acc[mt][nt][r] + bv[nt];
        if (relu) v = fmaxf(v, 0.f);
        C[ro + nt*16] = v;
      }
    }
  }
}

// ---------------------------------------------------------------------------
// V5 MFMA GEMM (vis q-proj / f1 / f2): 128x128 tile, BK=64, seg-XOR LDS
// swizzle (R13: bank conflicts -> 0). Unchanged from R14.
// ---------------------------------------------------------------------------
__global__ __launch_bounds__(256) void k_mgemm3(
    const void* A, size_t a_off, int a_kind,
    const ushort_t* __restrict__ Wt, const void* bias,
    float* __restrict__ Cf, ushort_t* __restrict__ Chi,
    int N, int K, int relu, const int* __restrict__ mf)
{
  const int mode = *mf;
  const int rawf32 = (a_kind==0) && (mode==1);
  __shared__ ushort_t Ah[128*64];
  __shared__ ushort_t Bt[128*64];
  const int tid = threadIdx.x;
  const int nbx = gridDim.x, nby = gridDim.y;
  const int total = nbx*nby;
  const int f = blockIdx.y*nbx + blockIdx.x;
  const int qq = total>>3, rr = total&7;
  const int xcd = f&7, pos = f>>3;
  const int wg = (xcd<rr ? xcd*(qq+1) : rr*(qq+1) + (xcd-rr)*qq) + pos;
  const int gm0 = (wg / nby)*128, gn0 = (wg % nby)*128;

  const int wv = tid>>6, lane = tid&63;
  const int mh = (wv&1)*64, nh = (wv>>1)*64;
  const int r16 = lane&15, kq = lane>>4;
  const int sr = tid>>3;        // row within issue (0..31)
  const int sg = tid&7;         // LDS seg (0..7)
  const int srow = tid>>1, chalf = (tid&1)*32;
  const ushort_t* Abf = (const ushort_t*)A + a_off;
  v4f acc[4][4];
  #pragma unroll
  for (int i=0;i<4;i++)
    #pragma unroll
    for (int j=0;j<4;j++) acc[i][j] = (v4f){0.f,0.f,0.f,0.f};

  for (int k0=0; k0<K; k0+=64){
    if (k0) __syncthreads();
    #pragma unroll
    for (int i=0;i<4;i++){
      const int r = i*32 + sr;
      const int gs = (sg ^ (r&7))*8;     // pre-swizzled global segment
      gload_lds16(Wt + (size_t)(gn0+r)*K + k0 + gs, &Bt[r*64 + sg*8]);
    }
    if (!rawf32){
      #pragma unroll
      for (int i=0;i<4;i++){
        const int r = i*32 + sr;
        const int gs = (sg ^ (r&7))*8;
        gload_lds16(Abf + (size_t)(gm0+r)*K + k0 + gs, &Ah[r*64 + sg*8]);
      }
    } else {
      const float* src = (const float*)A + a_off + (size_t)(gm0+srow)*K + k0 + chalf;
      #pragma unroll
      for (int v=0;v<8;v++){
        float4 fq = ((const float4*)src)[v];
        float xs[4] = {fq.x, fq.y, fq.z, fq.w};
        #pragma unroll
        for (int e=0;e<4;e++){
          const int c = chalf + v*4 + e;
          const int idx = srow*64 + (((c>>3) ^ (srow&7))<<3) + (c&7);
          Ah[idx] = f2bfbits(xs[e]);
        }
      }
    }
    __syncthreads();
    #pragma unroll
    for (int kk=0;kk<2;kk++){
      const int seg = kk*4 + kq;         // k-seg this quad consumes
      v8s af[4], bfr[4];
      #pragma unroll
      for (int mt=0;mt<4;mt++){
        const int row = mh + mt*16 + r16;
        af[mt] = *(const v8s*)&Ah[row*64 + ((seg ^ (row&7))<<3)];
      }
      #pragma unroll
      for (int nt=0;nt<4;nt++){
        const int row = nh + nt*16 + r16;
        bfr[nt] = *(const v8s*)&Bt[row*64 + ((seg ^ (row&7))<<3)];
      }
      #pragma unroll
      for (int mt=0;mt<4;mt++){
        #pragma unroll
        for (int nt=0;nt<4;nt++)
          acc[mt][nt] = __builtin_amdgcn_mfma_f32_16x16x32_bf16(af[mt], bfr[nt], acc[mt][nt], 0, 0, 0);
      }
    }
  }
  const int rq = kq*4;
  float bv[4];
  #pragma unroll
  for (int nt=0;nt<4;nt++) bv[nt] = ldin(bias, gn0 + nh + nt*16 + r16, mode);
  const int outf = (Cf != nullptr);
  #pragma unroll
  for (int mt=0;mt<4;mt++){
    #pragma unroll
    for (int r=0;r<4;r++){
      const size_t ro = (size_t)(gm0 + mh + mt*16 + rq + r)*N + gn0 + nh + r16;
      #pragma unroll
      for (int nt=0;nt<4;nt++){
        float v = acc[mt][nt][r] + bv[nt];
        if (relu) v = fmaxf(v, 0.f);
        if (outf) Cf[ro + nt*16] = v;
        else      Chi[ro + nt*16] = f2bfbits(v);
      }
    }
  }
}

// ---------------------------------------------------------------------------
// GEMM + residual + LayerNorm fused — o-proj only (K=256). 64 rows x 256
// cols, 256 thr = 4 waves. BK=64 + seg-XOR swizzle (unchanged from R14).
// ---------------------------------------------------------------------------
__global__ __launch_bounds__(256) void k_mgemm_ln(
    const ushort_t* __restrict__ A,
    const ushort_t* __restrict__ Wt, const void* bias,
    const void* RES, size_t res_off, int res_bf16,
    void* OUT, size_t out_off, int out_bf16,
    const void* g, const void* be,
    int K, const int* __restrict__ mf)
{
  const int mode = *mf;
  __shared__ ushort_t Ah[64*64];
  __shared__ ushort_t Bt[256*64];
  __shared__ float rsum[4][64];
  __shared__ float rsq[4][64];
  const int tid = threadIdx.x;
  const int gm0 = blockIdx.x*64;
  const int wv = tid>>6, lane = tid&63;
  const int nh = wv*64;
  const int r16 = lane&15, kq = lane>>4;
  const int sr = tid>>3;        // row within issue (0..31)
  const int sg = tid&7;         // LDS seg (0..7)
  v4f acc[4][4];
  #pragma unroll
  for (int i=0;i<4;i++)
    #pragma unroll
    for (int j=0;j<4;j++) acc[i][j] = (v4f){0.f,0.f,0.f,0.f};

  for (int k0=0; k0<K; k0+=64){
    if (k0) __syncthreads();
    // A: 64 rows -> 2 issues
    #pragma unroll
    for (int i=0;i<2;i++){
      const int r = i*32 + sr;
      const int gs = (sg ^ (r&7))*8;
      gload_lds16(A + (size_t)(gm0+r)*K + k0 + gs, &Ah[r*64 + sg*8]);
    }
    // B: 256 rows -> 8 issues
    #pragma unroll
    for (int i=0;i<8;i++){
      const int r = i*32 + sr;
      const int gs = (sg ^ (r&7))*8;
      gload_lds16(Wt + (size_t)r*K + k0 + gs, &Bt[r*64 + sg*8]);
    }
    __syncthreads();
    #pragma unroll
    for (int kk=0;kk<2;kk++){
      const int seg = kk*4 + kq;
      v8s af[4], bfr[4];
      #pragma unroll
      for (int mt=0;mt<4;mt++){
        const int row = mt*16 + r16;
        af[mt] = *(const v8s*)&Ah[row*64 + ((seg ^ (row&7))<<3)];
      }
      #pragma unroll
      for (int nt=0;nt<4;nt++){
        const int row = nh + nt*16 + r16;
        bfr[nt] = *(const v8s*)&Bt[row*64 + ((seg ^ (row&7))<<3)];
      }
      #pragma unroll
      for (int mt=0;mt<4;mt++){
        #pragma unroll
        for (int nt=0;nt<4;nt++)
          acc[mt][nt] = __builtin_amdgcn_mfma_f32_16x16x32_bf16(af[mt], bfr[nt], acc[mt][nt], 0, 0, 0);
      }
    }
  }
  // ---- z = acc + bias + residual (in place) ----
  float bv[4];
  #pragma unroll
  for (int nt=0;nt<4;nt++) bv[nt] = ldin(bias, nh + nt*16 + r16, mode);
  #pragma unroll
  for (int mt=0;mt<4;mt++){
    #pragma unroll
    for (int r=0;r<4;r++){
      const int row_l = mt*16 + kq*4 + r;
      const size_t rbase = (size_t)(gm0 + row_l)*256;
      #pragma unroll
      for (int nt=0;nt<4;nt++){
        const int col = nh + nt*16 + r16;
        const float rv = res_bf16 ? bf2f(((const ushort_t*)RES)[res_off + rbase + col])
                                  : ldin(RES, res_off + rbase + col, mode);
        acc[mt][nt][r] = acc[mt][nt][r] + bv[nt] + rv;
      }
    }
  }
  // ---- pass 1: row sums -> mean ----
  #pragma unroll
  for (int mt=0;mt<4;mt++){
    #pragma unroll
    for (int r=0;r<4;r++){
      float s = acc[mt][0][r] + acc[mt][1][r] + acc[mt][2][r] + acc[mt][3][r];
      #pragma unroll
      for (int o=1;o<16;o<<=1) s += __shfl_xor(s, o);
      if (r16==0) rsum[wv][mt*16 + kq*4 + r] = s;
    }
  }
  __syncthreads();
  float mean[4][4];
  #pragma unroll
  for (int mt=0;mt<4;mt++){
    #pragma unroll
    for (int r=0;r<4;r++){
      const int row_l = mt*16 + kq*4 + r;
      mean[mt][r] = (rsum[0][row_l]+rsum[1][row_l]+rsum[2][row_l]+rsum[3][row_l]) * (1.f/256.f);
    }
  }
  // ---- pass 2: row sumsq of (z-mean) -> var ----
  #pragma unroll
  for (int mt=0;mt<4;mt++){
    #pragma unroll
    for (int r=0;r<4;r++){
      const float m = mean[mt][r];
      float s2 = 0.f;
      #pragma unroll
      for (int nt=0;nt<4;nt++){ const float d = acc[mt][nt][r]-m; s2 += d*d; }
      #pragma unroll
      for (int o=1;o<16;o<<=1) s2 += __shfl_xor(s2, o);
      if (r16==0) rsq[wv][mt*16 + kq*4 + r] = s2;
    }
  }
  __syncthreads();
  // ---- normalize + affine + write ----
  float gv[4], bev[4];
  #pragma unroll
  for (int nt=0;nt<4;nt++){
    gv[nt]  = ldin(g,  nh + nt*16 + r16, mode);
    bev[nt] = ldin(be, nh + nt*16 + r16, mode);
  }
  #pragma unroll
  for (int mt=0;mt<4;mt++){
    #pragma unroll
    for (int r=0;r<4;r++){
      const int row_l = mt*16 + kq*4 + r;
      const float var = (rsq[0][row_l]+rsq[1][row_l]+rsq[2][row_l]+rsq[3][row_l]) * (1.f/256.f);
      const float inv = rsqrtf(var + 1e-5f);
      const float m = mean[mt][r];
      const size_t obase = (size_t)(gm0 + row_l)*256;
      #pragma unroll
      for (int nt=0;nt<4;nt++){
        const int col = nh + nt*16 + r16;
        const float o = (acc[mt][nt][r]-m)*inv*gv[nt] + bev[nt];
        if (out_bf16) ((ushort_t*)OUT)[obase + col] = f2bfbits(o);
        else          stout(OUT, out_off + obase + col, mode, o);
      }
    }
  }
}

// ---------------------------------------------------------------------------
// KV split/transpose prep (unchanged)
// ---------------------------------------------------------------------------
__global__ __launch_bounds__(256) void k_kvsplit(
    const float* __restrict__ kws, const float* __restrict__ vws,
    ushort_t* __restrict__ khi, ushort_t* __restrict__ klo,
    ushort_t* __restrict__ vthi, ushort_t* __restrict__ vtlo)
{
  const int row = blockIdx.x;        // 0..255 = b*32 + key
  const int b = row >> 5, key = row & 31;
  const int t = threadIdx.x;         // dim 0..255
  const float f = kws[(size_t)row*256 + t];
  const ushort_t fh = f2bfbits(f);
  khi[(size_t)row*256 + t] = fh;
  klo[(size_t)row*256 + t] = f2bfbits(f - bf2f(fh));
  const float g = vws[(size_t)row*256 + t];
  const ushort_t gh = f2bfbits(g);
  const size_t vt = ((size_t)b*256 + t)*32 + key;
  vthi[vt] = gh;
  vtlo[vt] = f2bfbits(g - bf2f(gh));
}

// ---------------------------------------------------------------------------
// A2: MFMA MHA (unchanged from R14 — wave-private P, no block barriers)
// ---------------------------------------------------------------------------
__global__ __launch_bounds__(256) void k_attn2(
    const ushort_t* __restrict__ qcH,
    ushort_t* __restrict__ aoh,
    const ushort_t* __restrict__ khi, const ushort_t* __restrict__ klo,
    const ushort_t* __restrict__ vthi, const ushort_t* __restrict__ vtlo,
    const char* __restrict__ tmask, int r0)
{
  __shared__ float P[4][16][36];
  const int tid = threadIdx.x;
  const int wv = tid>>6, lane = tid&63;
  const int lrow0 = blockIdx.x*64 + wv*16;
  const int b = (r0 + lrow0)/NVTOK;
  const int m16 = lane&15;
  const int kq = lane>>4;
  const int q8 = kq*8;
  const int key0 = m16, key1 = m16+16;
  const bool msk0 = tmask[b*LT + key0] != 0;
  const bool msk1 = tmask[b*LT + key1] != 0;
  const float scale = 0.17677669529663687f;

  for (int h=0; h<8; ++h){
    const size_t qoff = (size_t)(lrow0 + m16)*256 + h*32 + q8;
    const v8s qh = *(const v8s*)&qcH[qoff];
    const size_t kb0 = ((size_t)(b*32+key0)*256) + h*32 + q8;
    const size_t kb1 = ((size_t)(b*32+key1)*256) + h*32 + q8;
    const v8s kh0 = *(const v8s*)&khi[kb0];
    const v8s kl0 = *(const v8s*)&klo[kb0];
    const v8s kh1 = *(const v8s*)&khi[kb1];
    const v8s kl1 = *(const v8s*)&klo[kb1];
    v4f s0 = (v4f){0.f,0.f,0.f,0.f}, s1 = (v4f){0.f,0.f,0.f,0.f};
    s0 = __builtin_amdgcn_mfma_f32_16x16x32_bf16(qh, kh0, s0, 0,0,0);
    s0 = __builtin_amdgcn_mfma_f32_16x16x32_bf16(qh, kl0, s0, 0,0,0);
    s1 = __builtin_amdgcn_mfma_f32_16x16x32_bf16(qh, kh1, s1, 0,0,0);
    s1 = __builtin_amdgcn_mfma_f32_16x16x32_bf16(qh, kl1, s1, 0,0,0);
    float e0[4], e1[4], inv[4];
    #pragma unroll
    for (int r=0;r<4;r++){
      const float a0 = msk0 ? -1e9f : s0[r]*scale;
      const float a1 = msk1 ? -1e9f : s1[r]*scale;
      float mx = fmaxf(a0,a1);
      #pragma unroll
      for (int o=1;o<16;o<<=1) mx = fmaxf(mx, __shfl_xor(mx,o));
      const float x0 = __expf(a0-mx), x1 = __expf(a1-mx);
      float dn = x0+x1;
      #pragma unroll
      for (int o=1;o<16;o<<=1) dn += __shfl_xor(dn,o);
      e0[r]=x0; e1[r]=x1; inv[r] = 1.f/dn;
    }
    #pragma unroll
    for (int r=0;r<4;r++){
      P[wv][kq*4+r][key0] = e0[r];
      P[wv][kq*4+r][key1] = e1[r];
    }
    // no __syncthreads: P[wv] is wave-private; lgkmcnt orders within wave
    float pv[8];
    *(float4*)&pv[0] = *(const float4*)&P[wv][m16][q8];
    *(float4*)&pv[4] = *(const float4*)&P[wv][m16][q8+4];
    v8s ph;
    #pragma unroll
    for (int j=0;j<8;j++) ph[j] = (short)f2bfbits(pv[j]);
    const size_t vb0 = ((size_t)(b*256 + h*32 + m16)*32) + q8;
    const size_t vb1 = ((size_t)(b*256 + h*32 + 16 + m16)*32) + q8;
    const v8s vh0 = *(const v8s*)&vthi[vb0];
    const v8s vl0 = *(const v8s*)&vtlo[vb0];
    const v8s vh1 = *(const v8s*)&vthi[vb1];
    const v8s vl1 = *(const v8s*)&vtlo[vb1];
    v4f o0 = (v4f){0.f,0.f,0.f,0.f}, o1 = (v4f){0.f,0.f,0.f,0.f};
    o0 = __builtin_amdgcn_mfma_f32_16x16x32_bf16(ph, vh0, o0, 0,0,0);
    o0 = __builtin_amdgcn_mfma_f32_16x16x32_bf16(ph, vl0, o0, 0,0,0);
    o1 = __builtin_amdgcn_mfma_f32_16x16x32_bf16(ph, vh1, o1, 0,0,0);
    o1 = __builtin_amdgcn_mfma_f32_16x16x32_bf16(ph, vl1, o1, 0,0,0);
    // no __syncthreads: next head's P writes are same-wave, ordered by lgkmcnt
    #pragma unroll
    for (int r=0;r<4;r++){
      const size_t ro = (size_t)(lrow0 + kq*4 + r)*256 + h*32;
      aoh[ro + m16]      = f2bfbits(o0[r]*inv[r]);
      aoh[ro + 16 + m16] = f2bfbits(o1[r]*inv[r]);
    }
  }
}

// ---------------------------------------------------------------------------
// residual + two-pass LayerNorm (text side, unchanged)
// ---------------------------------------------------------------------------
__global__ __launch_bounds__(256) void k_add_ln(
    const float* __restrict__ X, const void* R, size_t r_off, int r_f32,
    void* OUT, size_t o_off, int o_f32,
    void* OUT2, size_t o2_off,
    const void* g, const void* be, const int* __restrict__ mf)
{
  const int mode = *mf;
  const int row = blockIdx.x; const int t = threadIdx.x;
  const size_t idx = (size_t)row*256 + t;
  __shared__ float red[4];
  const float rv = r_f32 ? ((const float*)R)[r_off+idx] : ldin(R, r_off+idx, mode);
  const float v = X[idx] + rv;
  const float m = block_sum(v, red) * (1.f/256.f);
  __syncthreads();
  const float d = v - m;
  const float var = block_sum(d*d, red) * (1.f/256.f);
  const float o = d*rsqrtf(var+1e-5f)*ldin(g,t,mode) + ldin(be,t,mode);
  if (o_f32) ((float*)OUT)[o_off+idx] = o;
  else       stout(OUT, o_off+idx, mode, o);
  if (OUT2)  stout(OUT2, o2_off+idx, mode, o);
}

// ---------------------------------------------------------------------------
// LN2 (vis): v = bf16(X) + bf16(RH) ; out = mode-typed at offset.
// X is now bf16 (f2 output rounded) — halves f2-write + LN2-read traffic.
// ---------------------------------------------------------------------------
__global__ __launch_bounds__(256) void k_add_ln_pres(
    const ushort_t* __restrict__ X,
    const ushort_t* __restrict__ RH,
    void* OUT, size_t o_off,
    const void* g, const void* be, const int* __restrict__ mf)
{
  const int mode = *mf;
  const int row = blockIdx.x; const int t = threadIdx.x;
  const size_t idx = (size_t)row*256 + t;
  __shared__ float red[4];
  const float rv = bf2f(RH[idx]);
  const float v = bf2f(X[idx]) + rv;
  const float m = block_sum(v, red) * (1.f/256.f);
  __syncthreads();
  const float d = v - m;
  const float var = block_sum(d*d, red) * (1.f/256.f);
  const float o = d*rsqrtf(var+1e-5f)*ldin(g,t,mode) + ldin(be,t,mode);
  stout(OUT, o_off+idx, mode, o);
}

// ---------------------------------------------------------------------------
extern "C" void kernel_launch(void* const* d_in, const int* in_sizes, int n_in,
                              void* d_out, int out_size, void* d_ws, size_t ws_size,
                              hipStream_t stream)
{
  (void)n_in; (void)out_size;
  const void* vis_tokens = d_in[0];
  const void* text_tokens= d_in[1];
  const void* vis_value  = d_in[2];
  const void* ref_w = d_in[3];  const void* ref_b = d_in[4];
  const void* off_w = d_in[5];  const void* off_b = d_in[6];
  const void* aw_w  = d_in[7];  const void* aw_b  = d_in[8];
  const void* vproj_w = d_in[9];  const void* vproj_b = d_in[10];
  const void* oproj_w = d_in[11]; const void* oproj_b = d_in[12];
  const void* lvi_out_w = d_in[13]; const void* lvi_out_b = d_in[14];
  const void* lvi_n1_s = d_in[15];  const void* lvi_n1_b = d_in[16];
  const void* lvi_f1_w = d_in[17];  const void* lvi_f1_b = d_in[18];
  const void* lvi_f2_w = d_in[19];  const void* lvi_f2_b = d_in[20];
  const void* lvi_n2_s = d_in[21];  const void* lvi_n2_b = d_in[22];
  const void* mha_qw = d_in[23]; const void* mha_qb = d_in[24];
  const void* mha_kw = d_in[25]; const void* mha_kb = d_in[26];
  const void* mha_vw = d_in[27]; const void* mha_vb = d_in[28];
  const void* mha_ow = d_in[29]; const void* mha_ob = d_in[30];
  const void* vli_out_w = d_in[31]; const void* vli_out_b = d_in[32];
  const void* vli_n1_s = d_in[33];  const void* vli_n1_b = d_in[34];
  const void* vli_f1_w = d_in[35];  const void* vli_f1_b = d_in[36];
  const void* vli_f2_w = d_in[37];  const void* vli_f2_b = d_in[38];
  const void* vli_n2_s = d_in[39];  const void* vli_n2_b = d_in[40];
  const char* tmask = (const char*)d_in[43];
  const char* vmask = (const char*)d_in[44];

  // ---- workspace layout ----
  char* ws = (char*)d_ws;
  int*   flag    = (int*)  (ws + 0);               // 256 B
  float* loc_ws  = (float*)(ws + 256);             // 196608
  float* aw_ws   = (float*)(ws + 196864);          //  98304
  float* ctxt_ws = (float*)(ws + 295168);          // 262144
  float* t_ws    = (float*)(ws + 557312);          // 262144
  float* tout_ws = (float*)(ws + 819456);          // 262144
  float* k_ws    = (float*)(ws + 1081600);         // 262144
  float* v_ws    = (float*)(ws + 1343744);         // 262144
  ushort_t* wtq  = (ushort_t*)(ws + 1605888ull);   // 131072 B
  ushort_t* wto  = (ushort_t*)(ws + 1736960ull);   // 131072 B
  ushort_t* wtf1 = (ushort_t*)(ws + 1868032ull);   // 524288 B
  ushort_t* wtf2 = (ushort_t*)(ws + 2392320ull);   // 524288 B
  ushort_t* wtk   = (ushort_t*)(ws + 2916608ull);  // 131072 B (mha_kw^T)
  ushort_t* wtv   = (ushort_t*)(ws + 3047680ull);  // 131072 B (mha_vw^T)
  ushort_t* wtop  = (ushort_t*)(ws + 3178752ull);  // 131072 B (oproj_w^T)
  ushort_t* wtlo  = (ushort_t*)(ws + 3309824ull);  // 131072 B (lvi_out_w^T)
  ushort_t* wtlf1 = (ushort_t*)(ws + 3440896ull);  // 524288 B (lvi_f1_w^T)
  ushort_t* wtlf2 = (ushort_t*)(ws + 3965184ull);  // 524288 B (lvi_f2_w^T)
  float* hbuf_t   = (float*)(ws + 4489472ull);     // 1048576 B (256x1024)
  float* ybuf     = (float*)(ws + 5538048ull);     // 262144 B
  float* fbuf     = (float*)(ws + 5800192ull);     // 262144 B
  ushort_t* khi   = (ushort_t*)(ws + 6062336ull);  // 131072 B
  ushort_t* klo   = (ushort_t*)(ws + 6193408ull);  // 131072 B
  ushort_t* vthi  = (ushort_t*)(ws + 6324480ull);  // 131072 B
  ushort_t* vtlo  = (ushort_t*)(ws + 6455552ull);  // 131072 B
  const size_t fe = 6586624ull;                    // chunk region start

  // per-row chunk bytes (3072 B/row), f2-out now bf16:
  //   region0 ( 512 B): qc bf16 (dead after attn2) <-> f2out bf16 (born at f2)
  //   region1 ( 512 B): v1 bf16
  //   region2 (2048 B): hb bf16; first 512 B alias ao bf16 (dead pre-f1)
  long long R_ll = 128;
  if (ws_size > fe) R_ll = (long long)((ws_size - fe) / 3072ull);
  if (R_ll > (long long)MVIS) R_ll = MVIS;
  R_ll &= ~127LL;
  if (R_ll < 128) R_ll = 128;
  const int R = (int)R_ll;
  ushort_t* qcH  = (ushort_t*)(ws + fe);                      // region0
  ushort_t* f2H  = qcH;                                       // alias (qc dead)
  ushort_t* v1H  = (ushort_t*)(ws + fe + (size_t)R*512ull);   // region1
  ushort_t* hbH  = (ushort_t*)(ws + fe + (size_t)R*1024ull);  // region2
  ushort_t* aoH  = hbH;                                       // alias (dead pre-f1)

  // ---- dtype detect ----
  int ndw = in_sizes[1]/2; if (ndw < 1) ndw = 1;
  k_detect<<<1,256,0,stream>>>((const uint_t*)text_tokens, ndw, flag);

  // ---- weight transposes for MFMA GEMMs ----
  k_transpose<<<dim3(8,8),  256,0,stream>>>(mha_qw,    wtq,   256, 256,  flag);
  k_transpose<<<dim3(8,8),  256,0,stream>>>(mha_ow,    wto,   256, 256,  flag);
  k_transpose<<<dim3(8,32), 256,0,stream>>>(vli_f1_w,  wtf1,  256, 1024, flag);
  k_transpose<<<dim3(32,8), 256,0,stream>>>(vli_f2_w,  wtf2,  1024, 256, flag);
  k_transpose<<<dim3(8,8),  256,0,stream>>>(mha_kw,    wtk,   256, 256,  flag);
  k_transpose<<<dim3(8,8),  256,0,stream>>>(mha_vw,    wtv,   256, 256,  flag);
  k_transpose<<<dim3(8,8),  256,0,stream>>>(oproj_w,   wtop,  256, 256,  flag);
  k_transpose<<<dim3(8,8),  256,0,stream>>>(lvi_out_w, wtlo,  256, 256,  flag);
  k_transpose<<<dim3(8,32), 256,0,stream>>>(lvi_f1_w,  wtlf1, 256, 1024, flag);
  k_transpose<<<dim3(32,8), 256,0,stream>>>(lvi_f2_w,  wtlf2, 1024, 256, flag);

  // ---- text side ----
  k_text_prep<<<MTEXT,256,0,stream>>>(text_tokens, ref_w, ref_b, off_w, off_b,
                                      aw_w, aw_b, loc_ws, aw_ws, flag);
  k_deform<<<MTEXT*NHEAD,64,0,stream>>>(vis_value, vmask, vproj_w, vproj_b,
                                        loc_ws, aw_ws, ctxt_ws, flag);

  // attn-out path: y = ctx@oproj + b ; z = y@lvi_out + b ; t = LN(text + z)
  {
    dim3 g22(2,2);
    k_mgemm<<<g22,256,0,stream>>>(ctxt_ws, 0, 1, wtop, oproj_b, ybuf, 256, 256, 0, flag);
    k_mgemm<<<g22,256,0,stream>>>(ybuf,    0, 1, wtlo, lvi_out_b, fbuf, 256, 256, 0, flag);
    k_add_ln<<<MTEXT,256,0,stream>>>(fbuf, text_tokens, 0, 0,
                                     t_ws, 0, 1, nullptr, 0, lvi_n1_s, lvi_n1_b, flag);
  }
  // ffn path: h = relu(t@f1+b1) ; f = h@f2+b2 ; tout = LN(t + f)
  {
    dim3 g28(2,8), g22(2,2);
    k_mgemm<<<g28,256,0,stream>>>(t_ws,   0, 1, wtlf1, lvi_f1_b, hbuf_t, 1024, 256, 1, flag);
    k_mgemm<<<g22,256,0,stream>>>(hbuf_t, 0, 1, wtlf2, lvi_f2_b, fbuf,   256, 1024, 0, flag);
    k_add_ln<<<MTEXT,256,0,stream>>>(fbuf, t_ws, 0, 1,
                                     tout_ws, 0, 1, d_out, VISSZ, lvi_n2_s, lvi_n2_b, flag);
  }
  // k/v projection of text_out + bf16 hi/lo split (+ V transpose)
  {
    dim3 g22(2,2);
    k_mgemm<<<g22,256,0,stream>>>(tout_ws, 0, 1, wtk, mha_kb, k_ws, 256, 256, 0, flag);
    k_mgemm<<<g22,256,0,stream>>>(tout_ws, 0, 1, wtv, mha_vb, v_ws, 256, 256, 0, flag);
    k_kvsplit<<<256,256,0,stream>>>(k_ws, v_ws, khi, klo, vthi, vtlo);
  }

  // ---- vis side, chunked by R rows ----
  for (int r0 = 0; r0 < MVIS; r0 += R){
    const int nr = (MVIS - r0 < R) ? (MVIS - r0) : R;   // multiple of 128
    dim3 g2(nr/128, 2), g8(nr/128, 8);
    k_mgemm3<<<g2,256,0,stream>>>(vis_tokens, (size_t)r0*256, 0,
                                  wtq, mha_qb, nullptr, qcH, 256, 256, 0, flag);
    k_attn2<<<nr/64,256,0,stream>>>(qcH, aoH, khi, klo, vthi, vtlo, tmask, r0);
    // o-proj + residual(vis_tokens) + LN1 -> v1H (bf16)  [K=256: fused OK]
    k_mgemm_ln<<<nr/64,256,0,stream>>>(aoH, wto, mha_ob,
                                       vis_tokens, (size_t)r0*256, 0,
                                       v1H, 0, 1,
                                       vli_n1_s, vli_n1_b, 256, flag);
    k_mgemm3<<<g8,256,0,stream>>>(v1H, 0, 2,
                                  wtf1, vli_f1_b, nullptr, hbH, 1024, 256, 1, flag);
    // f2 -> bf16 (halves write traffic; qc region is dead, alias as f2H)
    k_mgemm3<<<g2,256,0,stream>>>(hbH, 0, 2,
                                  wtf2, vli_f2_b, nullptr, f2H, 256, 1024, 0, flag);
    // LN2: bf16 f2H + v1H -> d_out
    k_add_ln_pres<<<nr,256,0,stream>>>(f2H, v1H,
                                       d_out, (size_t)r0*256, vli_n2_s, vli_n2_b, flag);
  }
}